// Round 4
// baseline (1954.684 us; speedup 1.0000x reference)
//
#include <hip/hip_runtime.h>
#include <hip/hip_bf16.h>

typedef __hip_bfloat16 bf16;

#define B_ 8
#define C_ 256
#define L_ 128
#define MB 1048576UL

__device__ inline float b2f(bf16 v){ return __bfloat162float(v); }
__device__ inline bf16 f2b(float v){ return __float2bfloat16(v); }
__device__ inline float siluf(float x){ return x / (1.f + expf(-x)); }
__device__ inline float softplusf(float x){ return (x > 20.f) ? x : log1pf(expf(x)); }
__device__ inline float vclamp(float v){ return fmaxf(v, 0.f) + 1e-5f; }

// block = 256 threads. red must hold 512 floats.
__device__ inline void bred2(float& a, float& b, float* red){
  int t = threadIdx.x;
  __syncthreads();
  red[t] = a; red[256 + t] = b;
  __syncthreads();
  for (int off = 128; off > 0; off >>= 1){
    if (t < off){ red[t] += red[t + off]; red[256 + t] += red[256 + t + off]; }
    __syncthreads();
  }
  a = red[0]; b = red[256];
}
__device__ inline float bred1(float a, float* red){
  int t = threadIdx.x;
  __syncthreads();
  red[t] = a; __syncthreads();
  for (int off = 128; off > 0; off >>= 1){
    if (t < off) red[t] += red[t + off];
    __syncthreads();
  }
  return red[0];
}

// ---------------- pooling step 1: row/col max/min + argmax + pos-embed -------------
// grid (C, B), block 64
__global__ __launch_bounds__(64) void pool1_kernel(const float* __restrict__ x, const float* __restrict__ pos,
    float* __restrict__ pcolmax, float* __restrict__ pcolmin,
    float* __restrict__ prowmax, float* __restrict__ prowmin)
{
  int c = blockIdx.x, b = blockIdx.y, t = threadIdx.x;
  __shared__ float xs[64][65];
  const float* xp = x + ((long)(b*C_ + c))*4096;
  for (int i = 0; i < 64; i++) xs[i][t] = xp[i*64 + t];
  __syncthreads();
  // jax.image.resize 'linear' 16->64: half-pixel coords, edge clamp
  float tt = 0.25f*(float)t - 0.375f;
  const float* pp = pos + c*16;
  float pe;
  if (tt <= 0.f) pe = pp[0];
  else if (tt >= 15.f) pe = pp[15];
  else { int f = (int)floorf(tt); float w = tt - (float)f; pe = pp[f]*(1.f - w) + pp[f+1]*w; }
  float vmax = -1e30f, vmin = 1e30f; int amax = 0, amin = 0;
  for (int j = 0; j < 64; j++){
    float v = xs[t][j];
    if (v > vmax){ vmax = v; amax = j; }
    if (v < vmin){ vmin = v; amin = j; }
  }
  long o = (long)(b*64 + t)*C_ + c;
  prowmax[o] = vmax + pe + (float)amax;
  prowmin[o] = vmin + pe + (float)amin;
  vmax = -1e30f; vmin = 1e30f; amax = 0; amin = 0;
  for (int i = 0; i < 64; i++){
    float v = xs[i][t];
    if (v > vmax){ vmax = v; amax = i; }
    if (v < vmin){ vmin = v; amin = i; }
  }
  pcolmax[o] = vmax + pe + (float)amax;
  pcolmin[o] = vmin + pe + (float)amin;
}

// ---------------- pooling step 2: LN over channels, write 4 mamba inputs -----------
// grid (128, B), block 256
__global__ __launch_bounds__(256) void pool2_kernel(const float* __restrict__ pcolmax, const float* __restrict__ pcolmin,
    const float* __restrict__ prowmax, const float* __restrict__ prowmin,
    const float* __restrict__ lnw, const float* __restrict__ lnb, float* __restrict__ hbuf)
{
  int r = blockIdx.x, b = blockIdx.y, c = threadIdx.x;
  __shared__ float red[512];
  int p = r & 63;
  long src = (long)(b*64 + p)*C_ + c;
  float vmax = (r < 64) ? pcolmax[src] : prowmax[src];
  float vmin = (r < 64) ? pcolmin[src] : prowmin[src];
  float gw = lnw[c], gb = lnb[c];
  long row = (long)b*L_ + r, frow = (long)b*L_ + (127 - r);
  float s = vmax, s2 = vmax*vmax;
  bred2(s, s2, red);
  float m = s*(1.f/256.f), var = s2*(1.f/256.f) - m*m;
  float o = (vmax - m)*rsqrtf(vclamp(var))*gw + gb;
  hbuf[0*262144 + row*C_ + c]  = o;
  hbuf[2*262144 + frow*C_ + c] = o;
  s = vmin; s2 = vmin*vmin;
  bred2(s, s2, red);
  m = s*(1.f/256.f); var = s2*(1.f/256.f) - m*m;
  o = (vmin - m)*rsqrtf(vclamp(var))*gw + gb;
  hbuf[1*262144 + row*C_ + c]  = o;
  hbuf[3*262144 + frow*C_ + c] = o;
}

// ---------------- dwconvT on-the-fly helper ----------------------------------------
__device__ inline float dwconvT_at(const float* __restrict__ xp, const float* __restrict__ w, int i, int j)
{
  float acc = 0.f;
  #pragma unroll
  for (int ki = 0; ki < 3; ki++){
    int pi = i + ki - 1;
    if (pi < 0 || (pi & 1)) continue;
    int xi = pi >> 1;
    if (xi >= 64) continue;
    #pragma unroll
    for (int kj = 0; kj < 3; kj++){
      int pj = j + kj - 1;
      if (pj < 0 || (pj & 1)) continue;
      int xj = pj >> 1;
      if (xj >= 64) continue;
      acc += w[(2-ki)*3 + (2-kj)] * xp[xi*64 + xj];
    }
  }
  return acc;
}

// ---------------- bn1 stats of dwconvT(x), no store --------------------------------
// grid (B*C), block 256
__global__ __launch_bounds__(256) void dwstats_kernel(const float* __restrict__ x, const float* __restrict__ dw,
    float* __restrict__ bn1sum, float* __restrict__ bn1sq)
{
  int bc = blockIdx.x; int c = bc & 255;
  const float* xp = x + (long)bc*4096;
  float w[9];
  #pragma unroll
  for (int q = 0; q < 9; q++) w[q] = dw[c*9 + q];
  float s = 0.f, s2 = 0.f;
  int tid = threadIdx.x;
  for (int it = 0; it < 64; it++){
    int p = it*256 + tid; int i = p >> 7, j = p & 127;
    float acc = dwconvT_at(xp, w, i, j);
    s += acc; s2 += acc*acc;
  }
  __shared__ float red[512];
  bred2(s, s2, red);
  if (tid == 0){ atomicAdd(&bn1sum[c], s); atomicAdd(&bn1sq[c], s2); }
}

// ---------------- bn finalize: per-channel affine ----------------------------------
__global__ void fin_bn_kernel(const float* __restrict__ sum, const float* __restrict__ sq,
                              const float* __restrict__ g, const float* __restrict__ b,
                              float cnt_inv, float* __restrict__ a, float* __restrict__ d)
{
  int c = threadIdx.x;
  float m = sum[c]*cnt_inv;
  float v = sq[c]*cnt_inv - m*m;
  float aa = g[c] * rsqrtf(vclamp(v));
  a[c] = aa;
  d[c] = b[c] - m*aa;
}

// ---------------- up-pw GEMM with fused dwconvT+bn1+relu B-load --------------------
// z2[b,o,p] = sum_c W[o,c] * relu(bn1(dwconvT(x)[b,c,p])),  p in 0..16383
// grid (256, 4, B), block 256
__global__ __launch_bounds__(256) void pwz_gemm_kernel(const float* __restrict__ x,
    const float* __restrict__ dw, const float* __restrict__ W,
    const float* __restrict__ fa, const float* __restrict__ fd,
    bf16* __restrict__ z2)
{
  int b = blockIdx.z;
  int n0 = blockIdx.x*64, m0 = blockIdx.y*64;
  __shared__ __align__(16) float As[16][68];
  __shared__ __align__(16) float Bs[16][68];
  int tid = threadIdx.x, tx = tid & 15, ty = tid >> 4;
  float acc[4][4] = {};
  int pi0 = n0 >> 7, pj0 = n0 & 127;   // pixel row (fixed within block), col base
  for (int c0 = 0; c0 < C_; c0 += 16){
    #pragma unroll
    for (int q = 0; q < 4; q++){
      int e = tid + q*256; int mm = e >> 4, kk = e & 15;
      As[kk][mm] = W[(m0 + mm)*C_ + c0 + kk];
    }
    #pragma unroll
    for (int q = 0; q < 4; q++){
      int e = tid + q*256; int kk = e >> 6, nn = e & 63;
      int c = c0 + kk;
      const float* xp = x + ((long)(b*C_ + c))*4096;
      float w[9];
      #pragma unroll
      for (int t9 = 0; t9 < 9; t9++) w[t9] = dw[c*9 + t9];
      float zv = dwconvT_at(xp, w, pi0, pj0 + nn);
      Bs[kk][nn] = fmaxf(zv*fa[c] + fd[c], 0.f);
    }
    __syncthreads();
    #pragma unroll
    for (int kk = 0; kk < 16; kk++){
      float4 a4 = *(const float4*)&As[kk][ty*4];
      float4 b4 = *(const float4*)&Bs[kk][tx*4];
      float av[4] = {a4.x, a4.y, a4.z, a4.w};
      float bv[4] = {b4.x, b4.y, b4.z, b4.w};
      #pragma unroll
      for (int mm = 0; mm < 4; mm++)
        #pragma unroll
        for (int nn = 0; nn < 4; nn++) acc[mm][nn] += av[mm]*bv[nn];
    }
    __syncthreads();
  }
  #pragma unroll
  for (int mm = 0; mm < 4; mm++){
    int o = m0 + ty*4 + mm;
    #pragma unroll
    for (int nn = 0; nn < 4; nn++)
      z2[((long)(b*C_ + o))*16384 + n0 + tx*4 + nn] = f2b(acc[mm][nn]);
  }
}

// ---------------- per-channel stats of bf16 tensor (B,C,16384) ---------------------
// grid (C, B), block 256
__global__ __launch_bounds__(256) void chstats_kernel(const bf16* __restrict__ t,
                                                      float* __restrict__ sum, float* __restrict__ sq)
{
  int c = blockIdx.x, b = blockIdx.y, tid = threadIdx.x;
  const bf16* p = t + ((long)(b*C_ + c))*16384;
  float s = 0.f, s2 = 0.f;
  for (int it = 0; it < 64; it++){ float v = b2f(p[it*256 + tid]); s += v; s2 += v*v; }
  __shared__ float red[512];
  bred2(s, s2, red);
  if (tid == 0){ atomicAdd(&sum[c], s); atomicAdd(&sq[c], s2); }
}

// ---------------- generic GEMM: C[m,n] = act(sum_k A[m,k] W[n,k] + bias[n]) --------
// A fp32 (lda, batch stride sA), W fp32 (N,K) row-major, batched over grid.z.
// grid ((N+63)/64, (M+63)/64, nbatch), block 256
__global__ __launch_bounds__(256) void gemm_kernel(
  const float* __restrict__ Abase, long sA, int lda,
  const float* __restrict__ W0, const float* __restrict__ W1,
  const float* __restrict__ bias0, const float* __restrict__ bias1, int wsplit,
  float* __restrict__ Cbase, long sC, int ldc,
  int M, int N, int K, int act)
{
  int z = blockIdx.z;
  const float* A = Abase + (long)z*sA;
  float* Cp = Cbase + (long)z*sC;
  const float* W = (z >= wsplit) ? W1 : W0;
  const float* bias = (z >= wsplit) ? bias1 : bias0;
  int m0 = blockIdx.y*64, n0 = blockIdx.x*64;
  __shared__ __align__(16) float As[16][68];
  __shared__ __align__(16) float Ws[16][68];
  int tid = threadIdx.x, tx = tid & 15, ty = tid >> 4;
  float acc[4][4] = {};
  for (int k0 = 0; k0 < K; k0 += 16){
    #pragma unroll
    for (int q = 0; q < 4; q++){
      int e = tid + q*256; int r = e >> 4, kk = e & 15;
      int mi = m0 + r, ki = k0 + kk;
      As[kk][r] = (mi < M && ki < K) ? A[(long)mi*lda + ki] : 0.f;
    }
    #pragma unroll
    for (int q = 0; q < 4; q++){
      int e = tid + q*256; int n = e >> 4, kk = e & 15;
      int ni = n0 + n, ki = k0 + kk;
      Ws[kk][n] = (ni < N && ki < K) ? W[(long)ni*K + ki] : 0.f;
    }
    __syncthreads();
    #pragma unroll
    for (int kk = 0; kk < 16; kk++){
      float4 a4 = *(const float4*)&As[kk][ty*4];
      float4 b4 = *(const float4*)&Ws[kk][tx*4];
      float av[4] = {a4.x, a4.y, a4.z, a4.w};
      float bv[4] = {b4.x, b4.y, b4.z, b4.w};
      #pragma unroll
      for (int mm = 0; mm < 4; mm++)
        #pragma unroll
        for (int nn = 0; nn < 4; nn++) acc[mm][nn] += av[mm]*bv[nn];
    }
    __syncthreads();
  }
  #pragma unroll
  for (int mm = 0; mm < 4; mm++){
    int mi = m0 + ty*4 + mm;
    if (mi >= M) continue;
    #pragma unroll
    for (int nn = 0; nn < 4; nn++){
      int ni = n0 + tx*4 + nn;
      if (ni >= N) continue;
      float v = acc[mm][nn];
      if (bias) v += bias[ni];
      if (act == 2) v = softplusf(v);
      Cp[(long)mi*ldc + ni] = v;
    }
  }
}

// ---------------- depthwise causal conv1d (k=4) + silu -----------------------------
// grid (L, B, 4), block 512
__global__ __launch_bounds__(512) void conv1d_kernel(const float* __restrict__ xzb,
    const float* __restrict__ fw, const float* __restrict__ fb,
    const float* __restrict__ bw, const float* __restrict__ bb,
    float* __restrict__ ub)
{
  int l = blockIdx.x, b = blockIdx.y, v = blockIdx.z, d = threadIdx.x;
  const float* xm = xzb + (long)v*1024*1024;
  const float* w  = (v < 2) ? fw : bw;
  const float* cb = (v < 2) ? fb : bb;
  float acc = cb[d];
  #pragma unroll
  for (int k = 0; k < 4; k++){
    int ll = l - 3 + k;
    if (ll >= 0) acc += xm[(long)(b*L_ + ll)*1024 + d] * w[d*4 + k];
  }
  ub[(long)v*1024*512 + (long)(b*L_ + l)*512 + d] = siluf(acc);
}

// ---------------- selective scan ---------------------------------------------------
// grid (2, B, 4), block 256 : thread = one (b,d)
__global__ __launch_bounds__(256) void scan_kernel(const float* __restrict__ dtb, const float* __restrict__ ub,
    const float* __restrict__ dblb, const float* __restrict__ xzb,
    const float* __restrict__ fAlog, const float* __restrict__ fD,
    const float* __restrict__ bAlog, const float* __restrict__ bD,
    float* __restrict__ yb)
{
  int v = blockIdx.z, b = blockIdx.y;
  int d = blockIdx.x*256 + threadIdx.x;
  const float* dt  = dtb  + (long)v*1024*512;
  const float* u   = ub   + (long)v*1024*512;
  const float* dbl = dblb + (long)v*1024*48;
  const float* zg  = xzb  + (long)v*1024*1024 + 512;
  const float* Alog = (v < 2) ? fAlog : bAlog;
  const float* Dp   = (v < 2) ? fD : bD;
  float a[16];
  #pragma unroll
  for (int n = 0; n < 16; n++) a[n] = -expf(Alog[d*16 + n]);
  float Dv = Dp[d];
  float h[16];
  #pragma unroll
  for (int n = 0; n < 16; n++) h[n] = 0.f;
  __shared__ float bc[2][32];
  float* yo = yb + (long)v*1024*512;
  for (int l = 0; l < L_; l++){
    int row = b*L_ + l;
    if (threadIdx.x < 32) bc[l & 1][threadIdx.x] = dbl[row*48 + 16 + threadIdx.x];
    __syncthreads();
    float dtv = dt[(long)row*512 + d];
    float uv  = u [(long)row*512 + d];
    float zgv = zg[(long)row*1024 + d];
    float dtu = dtv*uv;
    float acc = 0.f;
    const float* Bm = bc[l & 1];
    #pragma unroll
    for (int n = 0; n < 16; n++){
      float dA = expf(dtv*a[n]);
      h[n] = dA*h[n] + dtu*Bm[n];
      acc += h[n]*Bm[16 + n];
    }
    float yv = acc + Dv*uv;
    yo[(long)row*512 + d] = yv * siluf(zgv);
  }
}

// ---------------- LayerNorm over C, two output modes -------------------------------
// grid (128, B, NV), block 256
__global__ __launch_bounds__(256) void ln_kernel(const float* __restrict__ inb, float* __restrict__ out0,
    float* __restrict__ out1, const float* __restrict__ lnw, const float* __restrict__ lnb, int mode)
{
  int r = blockIdx.x, b = blockIdx.y, v = blockIdx.z, c = threadIdx.x;
  long row = (long)b*L_ + r;
  float val = inb[((long)v*1024 + row)*C_ + c];
  __shared__ float red[512];
  float s = val, s2 = val*val;
  bred2(s, s2, red);
  float m = s*(1.f/256.f), var = s2*(1.f/256.f) - m*m;
  float o = (val - m)*rsqrtf(vclamp(var))*lnw[c] + lnb[c];
  if (mode == 1){
    long frow = (long)b*L_ + (127 - r);
    if (v == 0)      out0[row*512 + c] = o;
    else if (v == 1) out1[row*512 + c] = o;
    else if (v == 2) out0[frow*512 + 256 + c] = o;
    else             out1[frow*512 + 256 + c] = o;
  } else {
    out0[((long)v*1024 + row)*C_ + c] = o;
  }
}

// ---------------- hsig(rm+rn)*clip(bn2(z2)) + gn stats; resq IN-PLACE in z2 --------
// Race-free: group g reads p in [g*1024,(g+1)*1024); after a barrier it writes
// q in [g*256,(g+1)*256) — every write index < every future read index.
// grid (C, B), block 256
__global__ __launch_bounds__(256) void hsig_kernel(bf16* __restrict__ z2, const float* __restrict__ rm,
    const float* __restrict__ rn, const float* __restrict__ a2, const float* __restrict__ d2,
    float* __restrict__ gnsum, float* __restrict__ gnsq)
{
  int c = blockIdx.x, b = blockIdx.y, tid = threadIdx.x;
  __shared__ float rms[128], rns[128];
  if (tid < 128){
    rms[tid] = rm[(long)(b*L_ + tid)*C_ + c];
    rns[tid] = rn[(long)(b*L_ + tid)*C_ + c];
  }
  __syncthreads();
  float aa = a2[c], dd = d2[c];
  bf16* zp = z2 + ((long)(b*C_ + c))*16384;
  float s = 0.f, s2 = 0.f;
  for (int g = 0; g < 16; g++){
    float tv[4]; int wq[4];
    #pragma unroll
    for (int q = 0; q < 4; q++){
      int p = g*1024 + q*256 + tid; int i = p >> 7, j = p & 127;
      float zv = b2f(zp[p])*aa + dd;
      zv = fminf(fmaxf(zv, 0.f), 6.f);
      float gate = rms[i] + rns[j];
      gate = fminf(fmaxf(gate + 3.f, 0.f), 6.f) * (1.f/6.f);
      float t = gate*zv;
      s += t; s2 += t*t;
      tv[q] = t;
      wq[q] = (((i | j) & 1) == 0) ? ((i >> 1)*64 + (j >> 1)) : -1;
    }
    __syncthreads();
    #pragma unroll
    for (int q = 0; q < 4; q++)
      if (wq[q] >= 0) zp[wq[q]] = f2b(tv[q]);
  }
  __shared__ float red[512];
  bred2(s, s2, red);
  if (tid == 0){ atomicAdd(&gnsum[b*32 + (c >> 3)], s); atomicAdd(&gnsq[b*32 + (c >> 3)], s2); }
}

// ---------------- gn finalize to per-(b,c) affine ----------------------------------
// grid (B), block 256
__global__ void fin_gn_kernel(const float* __restrict__ gnsum, const float* __restrict__ gnsq,
                              const float* __restrict__ g, const float* __restrict__ bb,
                              float* __restrict__ gnA, float* __restrict__ gnD)
{
  int b = blockIdx.x, c = threadIdx.x, gr = c >> 3;
  float inv_cnt = 1.f/131072.f;
  float m = gnsum[b*32 + gr]*inv_cnt;
  float v = gnsq[b*32 + gr]*inv_cnt - m*m;
  float inv = rsqrtf(vclamp(v));
  float A = inv*g[c];
  gnA[b*C_ + c] = A;
  gnD[b*C_ + c] = bb[c] - m*A;
}

// ---------------- down-pw GEMM: d[b,o,s] = sum_c W[o,c]*(resq[b,c,s]*gnA+gnD) ------
// resq rows strided 16384 (in-place inside z2); out fp32 (d_out), stride 4096.
// grid (64, 4, B), block 256
__global__ __launch_bounds__(256) void pwdown_gemm_kernel(const bf16* __restrict__ in,
    const float* __restrict__ W, const float* __restrict__ fa, const float* __restrict__ fd,
    float* __restrict__ out)
{
  int b = blockIdx.z;
  int n0 = blockIdx.x*64, m0 = blockIdx.y*64;
  __shared__ __align__(16) float As[16][68];
  __shared__ __align__(16) float Bs[16][68];
  int tid = threadIdx.x, tx = tid & 15, ty = tid >> 4;
  float acc[4][4] = {};
  for (int c0 = 0; c0 < C_; c0 += 16){
    #pragma unroll
    for (int q = 0; q < 4; q++){
      int e = tid + q*256; int mm = e >> 4, kk = e & 15;
      As[kk][mm] = W[(m0 + mm)*C_ + c0 + kk];
    }
    #pragma unroll
    for (int q = 0; q < 4; q++){
      int e = tid + q*256; int kk = e >> 6, nn = e & 63;
      int c = c0 + kk;
      int ai = b*C_ + c;
      float v = b2f(in[((long)(b*C_ + c))*16384 + n0 + nn]);
      Bs[kk][nn] = v*fa[ai] + fd[ai];
    }
    __syncthreads();
    #pragma unroll
    for (int kk = 0; kk < 16; kk++){
      float4 a4 = *(const float4*)&As[kk][ty*4];
      float4 b4 = *(const float4*)&Bs[kk][tx*4];
      float av[4] = {a4.x, a4.y, a4.z, a4.w};
      float bv[4] = {b4.x, b4.y, b4.z, b4.w};
      #pragma unroll
      for (int mm = 0; mm < 4; mm++)
        #pragma unroll
        for (int nn = 0; nn < 4; nn++) acc[mm][nn] += av[mm]*bv[nn];
    }
    __syncthreads();
  }
  #pragma unroll
  for (int mm = 0; mm < 4; mm++){
    int o = m0 + ty*4 + mm;
    #pragma unroll
    for (int nn = 0; nn < 4; nn++)
      out[((long)(b*C_ + o))*4096 + n0 + tx*4 + nn] = acc[mm][nn];
  }
}

// ---------------- 5 moments per (b,c): sum d, d^2, x, x^2, dx ----------------------
// grid (C, B), block 256
__global__ __launch_bounds__(256) void stat5_kernel(const float* __restrict__ dbuf, const float* __restrict__ x,
                                                    float* __restrict__ s5)
{
  int c = blockIdx.x, b = blockIdx.y, tid = threadIdx.x;
  const float* dp = dbuf + ((long)(b*C_ + c))*4096;
  const float* xp = x + ((long)(b*C_ + c))*4096;
  float sd = 0, sd2 = 0, sx = 0, sx2 = 0, sdx = 0;
  for (int it = 0; it < 16; it++){
    float d = dp[it*256 + tid];
    float xv = xp[it*256 + tid];
    sd += d; sd2 += d*d; sx += xv; sx2 += xv*xv; sdx += d*xv;
  }
  __shared__ float red[256];
  float r0 = bred1(sd, red); float r1 = bred1(sd2, red); float r2 = bred1(sx, red);
  float r3 = bred1(sx2, red); float r4 = bred1(sdx, red);
  if (tid == 0){
    float* o = s5 + (long)(b*C_ + c)*5;
    o[0] = r0; o[1] = r1; o[2] = r2; o[3] = r3; o[4] = r4;
  }
}

// ---------------- collapse bn -> gn -> (+x) -> gn into out = P*d + Q*x + R ---------
// grid (B), block 256
__global__ void coeff_kernel(const float* __restrict__ s5, const float* __restrict__ dbn_g, const float* __restrict__ dbn_b,
                             const float* __restrict__ gn_g, const float* __restrict__ gn_b, float* __restrict__ pqr)
{
  int b = blockIdx.x, c = threadIdx.x, g = c >> 3;
  float sd = 0, sd2 = 0;
  for (int bb = 0; bb < 8; bb++){ sd += s5[(long)(bb*C_ + c)*5 + 0]; sd2 += s5[(long)(bb*C_ + c)*5 + 1]; }
  float inv_cnt = 1.f/32768.f;
  float mB = sd*inv_cnt;
  float vB = sd2*inv_cnt - mB*mB;
  float ab = dbn_g[c] * rsqrtf(vclamp(vB));
  float db = dbn_b[c] - mB*ab;
  const float* s = s5 + (long)(b*C_ + c)*5;
  float inv_n = 1.f/4096.f;
  float m = s[0]*inv_n, Ed2 = s[1]*inv_n, mx = s[2]*inv_n, Ex2 = s[3]*inv_n, Edx = s[4]*inv_n;
  float Ev = ab*m + db;
  float Ev2 = ab*ab*Ed2 + 2.f*ab*db*m + db*db;
  __shared__ float e1[256], e2[256];
  e1[c] = Ev; e2[c] = Ev2;
  __syncthreads();
  float m1 = 0, q1 = 0;
  for (int k = 0; k < 8; k++){ m1 += e1[(g << 3) + k]; q1 += e2[(g << 3) + k]; }
  m1 *= 0.125f; q1 *= 0.125f;
  float inv1 = rsqrtf(vclamp(q1 - m1*m1));
  float gg = gn_g[c];
  float A1 = inv1*gg;
  float D1 = gn_b[c] - m1*A1;
  float al = A1*ab;
  float be = A1*db + D1;
  float Et = al*m + be + mx;
  float Et2 = al*al*Ed2 + 2.f*al*be*m + be*be + 2.f*al*Edx + 2.f*be*mx + Ex2;
  __syncthreads();
  e1[c] = Et; e2[c] = Et2;
  __syncthreads();
  float m2 = 0, q2 = 0;
  for (int k = 0; k < 8; k++){ m2 += e1[(g << 3) + k]; q2 += e2[(g << 3) + k]; }
  m2 *= 0.125f; q2 *= 0.125f;
  float inv2 = rsqrtf(vclamp(q2 - m2*m2));
  float G = inv2*gg;
  float* o = pqr + (long)(b*C_ + c)*3;
  o[0] = G*al;
  o[1] = G;
  o[2] = G*(be - m2) + gn_b[c];
}

// ---------------- final elementwise: out = P*out + Q*x + R (in-place on d_out) -----
// grid (C, B), block 256
__global__ __launch_bounds__(256) void final_kernel(const float* __restrict__ x,
    const float* __restrict__ pqr, float* __restrict__ out)
{
  int c = blockIdx.x, b = blockIdx.y, tid = threadIdx.x;
  const float* o = pqr + (long)(b*C_ + c)*3;
  float P = o[0], Q = o[1], R = o[2];
  long base = ((long)(b*C_ + c))*4096;
  for (int it = 0; it < 16; it++){
    long idx = base + it*256 + tid;
    out[idx] = P*out[idx] + Q*x[idx] + R;
  }
}

extern "C" void kernel_launch(void* const* d_in, const int* in_sizes, int n_in,
                              void* d_out, int out_size, void* d_ws, size_t ws_size,
                              hipStream_t stream)
{
  (void)in_sizes; (void)n_in; (void)out_size; (void)ws_size;
  // ALL inputs/outputs are float32 (reference setup_inputs uses jnp.float32;
  // threshold policy confirms _any_bf16 == False).
  const float* x         = (const float*)d_in[0];
  const float* pos       = (const float*)d_in[1];
  const float* ln_w      = (const float*)d_in[2];
  const float* ln_b      = (const float*)d_in[3];
  const float* proj_w    = (const float*)d_in[4];
  const float* proj_b    = (const float*)d_in[5];
  const float* up_dw_w   = (const float*)d_in[6];
  const float* up_bn1_g  = (const float*)d_in[7];
  const float* up_bn1_b  = (const float*)d_in[8];
  const float* up_pw_w   = (const float*)d_in[9];
  const float* up_bn2_g  = (const float*)d_in[10];
  const float* up_bn2_b  = (const float*)d_in[11];
  const float* down_pw_w = (const float*)d_in[12];
  const float* down_bn_g = (const float*)d_in[13];
  const float* down_bn_b = (const float*)d_in[14];
  const float* gn_g      = (const float*)d_in[15];
  const float* gn_b      = (const float*)d_in[16];
  const float* f_in_w    = (const float*)d_in[17];
  const float* f_conv_w  = (const float*)d_in[18];
  const float* f_conv_b  = (const float*)d_in[19];
  const float* f_xproj_w = (const float*)d_in[20];
  const float* f_dt_w    = (const float*)d_in[21];
  const float* f_dt_b    = (const float*)d_in[22];
  const float* f_Alog    = (const float*)d_in[23];
  const float* f_D       = (const float*)d_in[24];
  const float* f_out_w   = (const float*)d_in[25];
  const float* b_in_w    = (const float*)d_in[26];
  const float* b_conv_w  = (const float*)d_in[27];
  const float* b_conv_b  = (const float*)d_in[28];
  const float* b_xproj_w = (const float*)d_in[29];
  const float* b_dt_w    = (const float*)d_in[30];
  const float* b_dt_b    = (const float*)d_in[31];
  const float* b_Alog    = (const float*)d_in[32];
  const float* b_D       = (const float*)d_in[33];
  const float* b_out_w   = (const float*)d_in[34];

  // ======== workspace layout, PEAK = 4MB + 64MB = 68MB ========
  // [0, 4MB): small stats + rmrn (live across all phases)
  // [4MB, 68MB): "big" region — phase 1: mamba intermediates (57MB);
  //              phase 2/3: z2buf 64MB bf16 (resq written in-place inside it)
  // dbuf (B,C,64,64 fp32, 32MB) lives in d_out; final updates d_out in-place.
  char* sb = (char*)d_ws;
  float* statz = (float*)(sb);               // 1536 f (zeroed each launch)
  float* abn   = (float*)(sb + 8192);        // 1024 f
  float* gnAD  = (float*)(sb + 16384);       // 4096 f
  float* stat5 = (float*)(sb + 65536);       // 10240 f
  float* pqr   = (float*)(sb + 131072);      // 6144 f
  float* rmrn  = (float*)(sb + 1*MB);        // 2MB: 2 x (1024,256)
  char* big = sb + 4*MB;
  float* pool4  = (float*)(big + 0*MB);      // 2 MB
  float* hbuf   = (float*)(big + 2*MB);      // 4 MB
  float* xzbuf  = (float*)(big + 6*MB);      // 16 MB
  float* ubuf   = (float*)(big + 22*MB);     // 8 MB
  float* dblbuf = (float*)(big + 30*MB);     // 768 KB
  float* dtbuf  = (float*)(big + 31*MB);     // 8 MB
  float* ybuf   = (float*)(big + 39*MB);     // 8 MB
  float* mout   = (float*)(big + 47*MB);     // 4 MB
  float* cbuf   = (float*)(big + 51*MB);     // 4 MB
  float* respre = (float*)(big + 55*MB);     // 2 MB  (ends at 57MB < 64MB)
  bf16*  z2buf  = (bf16*)(big);              // 64 MB bf16 (phase 2/3)
  float* dbuf   = (float*)d_out;             // 32 MB fp32 (phase 3)

  float* bn1sum = statz;        float* bn1sq = statz + 256;
  float* bn2sum = statz + 512;  float* bn2sq = statz + 768;
  float* gnsum  = statz + 1024; float* gnsq  = statz + 1280;
  float* abn1 = abn;       float* dbn1 = abn + 256;
  float* abn2 = abn + 512; float* dbn2 = abn + 768;
  float* gnA = gnAD;       float* gnD = gnAD + 2048;
  float* pcolmax = pool4;
  float* pcolmin = pool4 + 131072;
  float* prowmax = pool4 + 262144;
  float* prowmin = pool4 + 393216;

  hipMemsetAsync(statz, 0, 1536*sizeof(float), stream);

  // ---- phase 1: pooling + LN + mamba x4 (f/b x max/min) -> rmrn ----
  pool1_kernel<<<dim3(256, 8), 64, 0, stream>>>(x, pos, pcolmax, pcolmin, prowmax, prowmin);
  pool2_kernel<<<dim3(128, 8), 256, 0, stream>>>(pcolmax, pcolmin, prowmax, prowmin, ln_w, ln_b, hbuf);
  gemm_kernel<<<dim3(16, 16, 4), 256, 0, stream>>>(hbuf, 262144, 256, f_in_w, b_in_w, nullptr, nullptr, 2,
                                                   xzbuf, 1048576, 1024, 1024, 1024, 256, 0);
  conv1d_kernel<<<dim3(128, 8, 4), 512, 0, stream>>>(xzbuf, f_conv_w, f_conv_b, b_conv_w, b_conv_b, ubuf);
  gemm_kernel<<<dim3(1, 16, 4), 256, 0, stream>>>(ubuf, 524288, 512, f_xproj_w, b_xproj_w, nullptr, nullptr, 2,
                                                  dblbuf, 49152, 48, 1024, 48, 512, 0);
  gemm_kernel<<<dim3(8, 16, 4), 256, 0, stream>>>(dblbuf, 49152, 48, f_dt_w, b_dt_w, f_dt_b, b_dt_b, 2,
                                                  dtbuf, 524288, 512, 1024, 512, 16, 2);
  scan_kernel<<<dim3(2, 8, 4), 256, 0, stream>>>(dtbuf, ubuf, dblbuf, xzbuf, f_Alog, f_D, b_Alog, b_D, ybuf);
  gemm_kernel<<<dim3(4, 16, 4), 256, 0, stream>>>(ybuf, 524288, 512, f_out_w, b_out_w, nullptr, nullptr, 2,
                                                  mout, 262144, 256, 1024, 256, 512, 0);
  ln_kernel<<<dim3(128, 8, 4), 256, 0, stream>>>(mout, cbuf, cbuf + 524288, ln_w, ln_b, 1);
  gemm_kernel<<<dim3(4, 16, 2), 256, 0, stream>>>(cbuf, 524288, 512, proj_w, proj_w, proj_b, proj_b, 2,
                                                  respre, 262144, 256, 1024, 256, 512, 0);
  ln_kernel<<<dim3(128, 8, 2), 256, 0, stream>>>(respre, rmrn, nullptr, ln_w, ln_b, 0);

  // ---- phase 2: z path (mamba buffers dead; big region becomes z2buf) ----
  dwstats_kernel<<<2048, 256, 0, stream>>>(x, up_dw_w, bn1sum, bn1sq);
  fin_bn_kernel<<<1, 256, 0, stream>>>(bn1sum, bn1sq, up_bn1_g, up_bn1_b, 1.f/131072.f, abn1, dbn1);
  pwz_gemm_kernel<<<dim3(256, 4, 8), 256, 0, stream>>>(x, up_dw_w, up_pw_w, abn1, dbn1, z2buf);
  chstats_kernel<<<dim3(256, 8), 256, 0, stream>>>(z2buf, bn2sum, bn2sq);
  fin_bn_kernel<<<1, 256, 0, stream>>>(bn2sum, bn2sq, up_bn2_g, up_bn2_b, 1.f/131072.f, abn2, dbn2);

  // ---- phase 3: merge + tail ----
  hsig_kernel<<<dim3(256, 8), 256, 0, stream>>>(z2buf, rmrn, rmrn + 262144, abn2, dbn2, gnsum, gnsq);
  fin_gn_kernel<<<8, 256, 0, stream>>>(gnsum, gnsq, gn_g, gn_b, gnA, gnD);
  pwdown_gemm_kernel<<<dim3(64, 4, 8), 256, 0, stream>>>(z2buf, down_pw_w, gnA, gnD, dbuf);
  stat5_kernel<<<dim3(256, 8), 256, 0, stream>>>(dbuf, x, stat5);
  coeff_kernel<<<8, 256, 0, stream>>>(stat5, down_bn_g, down_bn_b, gn_g, gn_b, pqr);
  final_kernel<<<dim3(256, 8), 256, 0, stream>>>(x, pqr, (float*)d_out);
}

// Round 5
// 1915.658 us; speedup vs baseline: 1.0204x; 1.0204x over previous
//
#include <hip/hip_runtime.h>
#include <hip/hip_bf16.h>

typedef __hip_bfloat16 bf16;

#define B_ 8
#define C_ 256
#define L_ 128
#define MB 1048576UL

__device__ inline float b2f(bf16 v){ return __bfloat162float(v); }
__device__ inline bf16 f2b(float v){ return __float2bfloat16(v); }
__device__ inline float siluf(float x){ return x / (1.f + expf(-x)); }
__device__ inline float softplusf(float x){ return (x > 20.f) ? x : log1pf(expf(x)); }
__device__ inline float vclamp(float v){ return fmaxf(v, 0.f) + 1e-5f; }

// block = 256 threads. red must hold 512 floats.
__device__ inline void bred2(float& a, float& b, float* red){
  int t = threadIdx.x;
  __syncthreads();
  red[t] = a; red[256 + t] = b;
  __syncthreads();
  for (int off = 128; off > 0; off >>= 1){
    if (t < off){ red[t] += red[t + off]; red[256 + t] += red[256 + t + off]; }
    __syncthreads();
  }
  a = red[0]; b = red[256];
}
__device__ inline float bred1(float a, float* red){
  int t = threadIdx.x;
  __syncthreads();
  red[t] = a; __syncthreads();
  for (int off = 128; off > 0; off >>= 1){
    if (t < off) red[t] += red[t + off];
    __syncthreads();
  }
  return red[0];
}

// ---------------- pooling step 1: row/col max/min + argmax + pos-embed -------------
// grid (C, B), block 64
__global__ __launch_bounds__(64) void pool1_kernel(const float* __restrict__ x, const float* __restrict__ pos,
    float* __restrict__ pcolmax, float* __restrict__ pcolmin,
    float* __restrict__ prowmax, float* __restrict__ prowmin)
{
  int c = blockIdx.x, b = blockIdx.y, t = threadIdx.x;
  __shared__ float xs[64][65];
  const float* xp = x + ((long)(b*C_ + c))*4096;
  for (int i = 0; i < 64; i++) xs[i][t] = xp[i*64 + t];
  __syncthreads();
  // jax.image.resize 'linear' 16->64: half-pixel coords, edge clamp
  float tt = 0.25f*(float)t - 0.375f;
  const float* pp = pos + c*16;
  float pe;
  if (tt <= 0.f) pe = pp[0];
  else if (tt >= 15.f) pe = pp[15];
  else { int f = (int)floorf(tt); float w = tt - (float)f; pe = pp[f]*(1.f - w) + pp[f+1]*w; }
  float vmax = -1e30f, vmin = 1e30f; int amax = 0, amin = 0;
  for (int j = 0; j < 64; j++){
    float v = xs[t][j];
    if (v > vmax){ vmax = v; amax = j; }
    if (v < vmin){ vmin = v; amin = j; }
  }
  long o = (long)(b*64 + t)*C_ + c;
  prowmax[o] = vmax + pe + (float)amax;
  prowmin[o] = vmin + pe + (float)amin;
  vmax = -1e30f; vmin = 1e30f; amax = 0; amin = 0;
  for (int i = 0; i < 64; i++){
    float v = xs[i][t];
    if (v > vmax){ vmax = v; amax = i; }
    if (v < vmin){ vmin = v; amin = i; }
  }
  pcolmax[o] = vmax + pe + (float)amax;
  pcolmin[o] = vmin + pe + (float)amin;
}

// ---------------- pooling step 2: LN over channels, write 4 mamba inputs -----------
// grid (128, B), block 256
__global__ __launch_bounds__(256) void pool2_kernel(const float* __restrict__ pcolmax, const float* __restrict__ pcolmin,
    const float* __restrict__ prowmax, const float* __restrict__ prowmin,
    const float* __restrict__ lnw, const float* __restrict__ lnb, float* __restrict__ hbuf)
{
  int r = blockIdx.x, b = blockIdx.y, c = threadIdx.x;
  __shared__ float red[512];
  int p = r & 63;
  long src = (long)(b*64 + p)*C_ + c;
  float vmax = (r < 64) ? pcolmax[src] : prowmax[src];
  float vmin = (r < 64) ? pcolmin[src] : prowmin[src];
  float gw = lnw[c], gb = lnb[c];
  long row = (long)b*L_ + r, frow = (long)b*L_ + (127 - r);
  float s = vmax, s2 = vmax*vmax;
  bred2(s, s2, red);
  float m = s*(1.f/256.f), var = s2*(1.f/256.f) - m*m;
  float o = (vmax - m)*rsqrtf(vclamp(var))*gw + gb;
  hbuf[0*262144 + row*C_ + c]  = o;
  hbuf[2*262144 + frow*C_ + c] = o;
  s = vmin; s2 = vmin*vmin;
  bred2(s, s2, red);
  m = s*(1.f/256.f); var = s2*(1.f/256.f) - m*m;
  o = (vmin - m)*rsqrtf(vclamp(var))*gw + gb;
  hbuf[1*262144 + row*C_ + c]  = o;
  hbuf[3*262144 + frow*C_ + c] = o;
}

// ---------------- dwconvT on-the-fly helper ----------------------------------------
__device__ inline float dwconvT_at(const float* __restrict__ xp, const float* __restrict__ w, int i, int j)
{
  float acc = 0.f;
  #pragma unroll
  for (int ki = 0; ki < 3; ki++){
    int pi = i + ki - 1;
    if (pi < 0 || (pi & 1)) continue;
    int xi = pi >> 1;
    if (xi >= 64) continue;
    #pragma unroll
    for (int kj = 0; kj < 3; kj++){
      int pj = j + kj - 1;
      if (pj < 0 || (pj & 1)) continue;
      int xj = pj >> 1;
      if (xj >= 64) continue;
      acc += w[(2-ki)*3 + (2-kj)] * xp[xi*64 + xj];
    }
  }
  return acc;
}

// ---------------- bn1 stats of dwconvT(x), no store, x staged in LDS ---------------
// grid (B*C), block 256
__global__ __launch_bounds__(256) void dwstats_kernel(const float* __restrict__ x, const float* __restrict__ dw,
    float* __restrict__ bn1sum, float* __restrict__ bn1sq)
{
  int bc = blockIdx.x; int c = bc & 255;
  int tid = threadIdx.x;
  __shared__ float xs[4096];
  const float* xp = x + (long)bc*4096;
  for (int it = 0; it < 16; it++) xs[it*256 + tid] = xp[it*256 + tid];
  float w[9];
  #pragma unroll
  for (int q = 0; q < 9; q++) w[q] = dw[c*9 + q];
  __syncthreads();
  float s = 0.f, s2 = 0.f;
  for (int it = 0; it < 64; it++){
    int p = it*256 + tid; int i = p >> 7, j = p & 127;
    float acc = dwconvT_at(xs, w, i, j);
    s += acc; s2 += acc*acc;
  }
  __shared__ float red[512];
  bred2(s, s2, red);
  if (tid == 0){ atomicAdd(&bn1sum[c], s); atomicAdd(&bn1sq[c], s2); }
}

// ---------------- bn finalize: per-channel affine ----------------------------------
__global__ void fin_bn_kernel(const float* __restrict__ sum, const float* __restrict__ sq,
                              const float* __restrict__ g, const float* __restrict__ b,
                              float cnt_inv, float* __restrict__ a, float* __restrict__ d)
{
  int c = threadIdx.x;
  float m = sum[c]*cnt_inv;
  float v = sq[c]*cnt_inv - m*m;
  float aa = g[c] * rsqrtf(vclamp(v));
  a[c] = aa;
  d[c] = b[c] - m*aa;
}

// ---------------- up-pw GEMM, fused dwconvT+bn1+relu B-build -----------------------
// One block computes ALL 256 output channels for its 64 pixels: B-tile built ONCE
// (old layout rebuilt it 4x, once per m-tile), dw staged in LDS (removes 36 scalar
// global loads/thread/k-step — the latency bottleneck; VALUBusy was 18.5%).
// z2[b,o,p] = sum_c W[o,c] * relu(bn1(dwconvT(x)[b,c,p]))
// grid (256, 1, B), block 256; thread: m = ty*16+mm (ty=tid>>4), p = n0+tx*4+nn
__global__ __launch_bounds__(256) void pwz_gemm_kernel(const float* __restrict__ x,
    const float* __restrict__ dw, const float* __restrict__ W,
    const float* __restrict__ fa, const float* __restrict__ fd,
    bf16* __restrict__ z2)
{
  int b = blockIdx.z;
  int n0 = blockIdx.x*64;
  __shared__ float dws[2304];
  __shared__ __align__(16) float As[16][264];
  __shared__ __align__(16) float Bs[16][68];
  int tid = threadIdx.x, tx = tid & 15, ty = tid >> 4;
  for (int e = tid; e < 2304; e += 256) dws[e] = dw[e];
  __syncthreads();
  float acc[16][4] = {};
  int pi0 = n0 >> 7, pj0 = n0 & 127;   // pixel row (uniform per block), col base
  for (int c0 = 0; c0 < C_; c0 += 16){
    #pragma unroll
    for (int q = 0; q < 16; q++){
      int e = tid + q*256; int mm = e >> 4, kk = e & 15;
      As[kk][mm] = W[mm*C_ + c0 + kk];
    }
    #pragma unroll
    for (int q = 0; q < 4; q++){
      int e = tid + q*256; int kk = e >> 6, nn = e & 63;
      int c = c0 + kk;
      const float* xp = x + ((long)(b*C_ + c))*4096;
      float zv = dwconvT_at(xp, &dws[c*9], pi0, pj0 + nn);
      Bs[kk][nn] = fmaxf(zv*fa[c] + fd[c], 0.f);
    }
    __syncthreads();
    #pragma unroll
    for (int kk = 0; kk < 16; kk++){
      float4 b4 = *(const float4*)&Bs[kk][tx*4];
      float bv[4] = {b4.x, b4.y, b4.z, b4.w};
      #pragma unroll
      for (int g = 0; g < 4; g++){
        float4 a4 = *(const float4*)&As[kk][ty*16 + g*4];
        float av[4] = {a4.x, a4.y, a4.z, a4.w};
        #pragma unroll
        for (int u = 0; u < 4; u++){
          #pragma unroll
          for (int nn = 0; nn < 4; nn++) acc[g*4 + u][nn] += av[u]*bv[nn];
        }
      }
    }
    __syncthreads();
  }
  #pragma unroll
  for (int mm = 0; mm < 16; mm++){
    int o = ty*16 + mm;
    bf16 v[4];
    #pragma unroll
    for (int nn = 0; nn < 4; nn++) v[nn] = f2b(acc[mm][nn]);
    *(uint2*)&z2[((long)(b*C_ + o))*16384 + n0 + tx*4] = *(const uint2*)v;
  }
}

// ---------------- per-channel stats of bf16 tensor (B,C,16384) ---------------------
// grid (C, B), block 256
__global__ __launch_bounds__(256) void chstats_kernel(const bf16* __restrict__ t,
                                                      float* __restrict__ sum, float* __restrict__ sq)
{
  int c = blockIdx.x, b = blockIdx.y, tid = threadIdx.x;
  const bf16* p = t + ((long)(b*C_ + c))*16384;
  float s = 0.f, s2 = 0.f;
  for (int it = 0; it < 64; it++){ float v = b2f(p[it*256 + tid]); s += v; s2 += v*v; }
  __shared__ float red[512];
  bred2(s, s2, red);
  if (tid == 0){ atomicAdd(&sum[c], s); atomicAdd(&sq[c], s2); }
}

// ---------------- generic GEMM: C[m,n] = act(sum_k A[m,k] W[n,k] + bias[n]) --------
// A fp32 (lda, batch stride sA), W fp32 (N,K) row-major, batched over grid.z.
// grid ((N+63)/64, (M+63)/64, nbatch), block 256
__global__ __launch_bounds__(256) void gemm_kernel(
  const float* __restrict__ Abase, long sA, int lda,
  const float* __restrict__ W0, const float* __restrict__ W1,
  const float* __restrict__ bias0, const float* __restrict__ bias1, int wsplit,
  float* __restrict__ Cbase, long sC, int ldc,
  int M, int N, int K, int act)
{
  int z = blockIdx.z;
  const float* A = Abase + (long)z*sA;
  float* Cp = Cbase + (long)z*sC;
  const float* W = (z >= wsplit) ? W1 : W0;
  const float* bias = (z >= wsplit) ? bias1 : bias0;
  int m0 = blockIdx.y*64, n0 = blockIdx.x*64;
  __shared__ __align__(16) float As[16][68];
  __shared__ __align__(16) float Ws[16][68];
  int tid = threadIdx.x, tx = tid & 15, ty = tid >> 4;
  float acc[4][4] = {};
  for (int k0 = 0; k0 < K; k0 += 16){
    #pragma unroll
    for (int q = 0; q < 4; q++){
      int e = tid + q*256; int r = e >> 4, kk = e & 15;
      int mi = m0 + r, ki = k0 + kk;
      As[kk][r] = (mi < M && ki < K) ? A[(long)mi*lda + ki] : 0.f;
    }
    #pragma unroll
    for (int q = 0; q < 4; q++){
      int e = tid + q*256; int n = e >> 4, kk = e & 15;
      int ni = n0 + n, ki = k0 + kk;
      Ws[kk][n] = (ni < N && ki < K) ? W[(long)ni*K + ki] : 0.f;
    }
    __syncthreads();
    #pragma unroll
    for (int kk = 0; kk < 16; kk++){
      float4 a4 = *(const float4*)&As[kk][ty*4];
      float4 b4 = *(const float4*)&Ws[kk][tx*4];
      float av[4] = {a4.x, a4.y, a4.z, a4.w};
      float bv[4] = {b4.x, b4.y, b4.z, b4.w};
      #pragma unroll
      for (int mm = 0; mm < 4; mm++)
        #pragma unroll
        for (int nn = 0; nn < 4; nn++) acc[mm][nn] += av[mm]*bv[nn];
    }
    __syncthreads();
  }
  #pragma unroll
  for (int mm = 0; mm < 4; mm++){
    int mi = m0 + ty*4 + mm;
    if (mi >= M) continue;
    #pragma unroll
    for (int nn = 0; nn < 4; nn++){
      int ni = n0 + tx*4 + nn;
      if (ni >= N) continue;
      float v = acc[mm][nn];
      if (bias) v += bias[ni];
      if (act == 2) v = softplusf(v);
      Cp[(long)mi*ldc + ni] = v;
    }
  }
}

// ---------------- depthwise causal conv1d (k=4) + silu -----------------------------
// grid (L, B, 4), block 512
__global__ __launch_bounds__(512) void conv1d_kernel(const float* __restrict__ xzb,
    const float* __restrict__ fw, const float* __restrict__ fb,
    const float* __restrict__ bw, const float* __restrict__ bb,
    float* __restrict__ ub)
{
  int l = blockIdx.x, b = blockIdx.y, v = blockIdx.z, d = threadIdx.x;
  const float* xm = xzb + (long)v*1024*1024;
  const float* w  = (v < 2) ? fw : bw;
  const float* cb = (v < 2) ? fb : bb;
  float acc = cb[d];
  #pragma unroll
  for (int k = 0; k < 4; k++){
    int ll = l - 3 + k;
    if (ll >= 0) acc += xm[(long)(b*L_ + ll)*1024 + d] * w[d*4 + k];
  }
  ub[(long)v*1024*512 + (long)(b*L_ + l)*512 + d] = siluf(acc);
}

// ---------------- selective scan ---------------------------------------------------
// grid (2, B, 4), block 256 : thread = one (b,d)
__global__ __launch_bounds__(256) void scan_kernel(const float* __restrict__ dtb, const float* __restrict__ ub,
    const float* __restrict__ dblb, const float* __restrict__ xzb,
    const float* __restrict__ fAlog, const float* __restrict__ fD,
    const float* __restrict__ bAlog, const float* __restrict__ bD,
    float* __restrict__ yb)
{
  int v = blockIdx.z, b = blockIdx.y;
  int d = blockIdx.x*256 + threadIdx.x;
  const float* dt  = dtb  + (long)v*1024*512;
  const float* u   = ub   + (long)v*1024*512;
  const float* dbl = dblb + (long)v*1024*48;
  const float* zg  = xzb  + (long)v*1024*1024 + 512;
  const float* Alog = (v < 2) ? fAlog : bAlog;
  const float* Dp   = (v < 2) ? fD : bD;
  float a[16];
  #pragma unroll
  for (int n = 0; n < 16; n++) a[n] = -expf(Alog[d*16 + n]);
  float Dv = Dp[d];
  float h[16];
  #pragma unroll
  for (int n = 0; n < 16; n++) h[n] = 0.f;
  __shared__ float bc[2][32];
  float* yo = yb + (long)v*1024*512;
  for (int l = 0; l < L_; l++){
    int row = b*L_ + l;
    if (threadIdx.x < 32) bc[l & 1][threadIdx.x] = dbl[row*48 + 16 + threadIdx.x];
    __syncthreads();
    float dtv = dt[(long)row*512 + d];
    float uv  = u [(long)row*512 + d];
    float zgv = zg[(long)row*1024 + d];
    float dtu = dtv*uv;
    float acc = 0.f;
    const float* Bm = bc[l & 1];
    #pragma unroll
    for (int n = 0; n < 16; n++){
      float dA = expf(dtv*a[n]);
      h[n] = dA*h[n] + dtu*Bm[n];
      acc += h[n]*Bm[16 + n];
    }
    float yv = acc + Dv*uv;
    yo[(long)row*512 + d] = yv * siluf(zgv);
  }
}

// ---------------- LayerNorm over C, two output modes -------------------------------
// grid (128, B, NV), block 256
__global__ __launch_bounds__(256) void ln_kernel(const float* __restrict__ inb, float* __restrict__ out0,
    float* __restrict__ out1, const float* __restrict__ lnw, const float* __restrict__ lnb, int mode)
{
  int r = blockIdx.x, b = blockIdx.y, v = blockIdx.z, c = threadIdx.x;
  long row = (long)b*L_ + r;
  float val = inb[((long)v*1024 + row)*C_ + c];
  __shared__ float red[512];
  float s = val, s2 = val*val;
  bred2(s, s2, red);
  float m = s*(1.f/256.f), var = s2*(1.f/256.f) - m*m;
  float o = (val - m)*rsqrtf(vclamp(var))*lnw[c] + lnb[c];
  if (mode == 1){
    long frow = (long)b*L_ + (127 - r);
    if (v == 0)      out0[row*512 + c] = o;
    else if (v == 1) out1[row*512 + c] = o;
    else if (v == 2) out0[frow*512 + 256 + c] = o;
    else             out1[frow*512 + 256 + c] = o;
  } else {
    out0[((long)v*1024 + row)*C_ + c] = o;
  }
}

// ---------------- hsig(rm+rn)*clip(bn2(z2)) + gn stats; resq IN-PLACE in z2 --------
// Race-free: group g reads p in [g*1024,(g+1)*1024); after a barrier it writes
// q in [g*256,(g+1)*256) — every write index < every future read index.
// grid (C, B), block 256
__global__ __launch_bounds__(256) void hsig_kernel(bf16* __restrict__ z2, const float* __restrict__ rm,
    const float* __restrict__ rn, const float* __restrict__ a2, const float* __restrict__ d2,
    float* __restrict__ gnsum, float* __restrict__ gnsq)
{
  int c = blockIdx.x, b = blockIdx.y, tid = threadIdx.x;
  __shared__ float rms[128], rns[128];
  if (tid < 128){
    rms[tid] = rm[(long)(b*L_ + tid)*C_ + c];
    rns[tid] = rn[(long)(b*L_ + tid)*C_ + c];
  }
  __syncthreads();
  float aa = a2[c], dd = d2[c];
  bf16* zp = z2 + ((long)(b*C_ + c))*16384;
  float s = 0.f, s2 = 0.f;
  for (int g = 0; g < 16; g++){
    float tv[4]; int wq[4];
    #pragma unroll
    for (int q = 0; q < 4; q++){
      int p = g*1024 + q*256 + tid; int i = p >> 7, j = p & 127;
      float zv = b2f(zp[p])*aa + dd;
      zv = fminf(fmaxf(zv, 0.f), 6.f);
      float gate = rms[i] + rns[j];
      gate = fminf(fmaxf(gate + 3.f, 0.f), 6.f) * (1.f/6.f);
      float t = gate*zv;
      s += t; s2 += t*t;
      tv[q] = t;
      wq[q] = (((i | j) & 1) == 0) ? ((i >> 1)*64 + (j >> 1)) : -1;
    }
    __syncthreads();
    #pragma unroll
    for (int q = 0; q < 4; q++)
      if (wq[q] >= 0) zp[wq[q]] = f2b(tv[q]);
  }
  __shared__ float red[512];
  bred2(s, s2, red);
  if (tid == 0){ atomicAdd(&gnsum[b*32 + (c >> 3)], s); atomicAdd(&gnsq[b*32 + (c >> 3)], s2); }
}

// ---------------- gn finalize to per-(b,c) affine ----------------------------------
// grid (B), block 256
__global__ void fin_gn_kernel(const float* __restrict__ gnsum, const float* __restrict__ gnsq,
                              const float* __restrict__ g, const float* __restrict__ bb,
                              float* __restrict__ gnA, float* __restrict__ gnD)
{
  int b = blockIdx.x, c = threadIdx.x, gr = c >> 3;
  float inv_cnt = 1.f/131072.f;
  float m = gnsum[b*32 + gr]*inv_cnt;
  float v = gnsq[b*32 + gr]*inv_cnt - m*m;
  float inv = rsqrtf(vclamp(v));
  float A = inv*g[c];
  gnA[b*C_ + c] = A;
  gnD[b*C_ + c] = bb[c] - m*A;
}

// ---------------- down-pw GEMM: d[b,o,s] = sum_c W[o,c]*(resq[b,c,s]*gnA+gnD) ------
// resq rows strided 16384 (in-place inside z2); out fp32 (d_out), stride 4096.
// grid (64, 4, B), block 256
__global__ __launch_bounds__(256) void pwdown_gemm_kernel(const bf16* __restrict__ in,
    const float* __restrict__ W, const float* __restrict__ fa, const float* __restrict__ fd,
    float* __restrict__ out)
{
  int b = blockIdx.z;
  int n0 = blockIdx.x*64, m0 = blockIdx.y*64;
  __shared__ __align__(16) float As[16][68];
  __shared__ __align__(16) float Bs[16][68];
  int tid = threadIdx.x, tx = tid & 15, ty = tid >> 4;
  float acc[4][4] = {};
  for (int c0 = 0; c0 < C_; c0 += 16){
    #pragma unroll
    for (int q = 0; q < 4; q++){
      int e = tid + q*256; int mm = e >> 4, kk = e & 15;
      As[kk][mm] = W[(m0 + mm)*C_ + c0 + kk];
    }
    #pragma unroll
    for (int q = 0; q < 4; q++){
      int e = tid + q*256; int kk = e >> 6, nn = e & 63;
      int c = c0 + kk;
      int ai = b*C_ + c;
      float v = b2f(in[((long)(b*C_ + c))*16384 + n0 + nn]);
      Bs[kk][nn] = v*fa[ai] + fd[ai];
    }
    __syncthreads();
    #pragma unroll
    for (int kk = 0; kk < 16; kk++){
      float4 a4 = *(const float4*)&As[kk][ty*4];
      float4 b4 = *(const float4*)&Bs[kk][tx*4];
      float av[4] = {a4.x, a4.y, a4.z, a4.w};
      float bv[4] = {b4.x, b4.y, b4.z, b4.w};
      #pragma unroll
      for (int mm = 0; mm < 4; mm++)
        #pragma unroll
        for (int nn = 0; nn < 4; nn++) acc[mm][nn] += av[mm]*bv[nn];
    }
    __syncthreads();
  }
  #pragma unroll
  for (int mm = 0; mm < 4; mm++){
    int o = m0 + ty*4 + mm;
    #pragma unroll
    for (int nn = 0; nn < 4; nn++)
      out[((long)(b*C_ + o))*4096 + n0 + tx*4 + nn] = acc[mm][nn];
  }
}

// ---------------- 5 moments per (b,c): sum d, d^2, x, x^2, dx ----------------------
// grid (C, B), block 256
__global__ __launch_bounds__(256) void stat5_kernel(const float* __restrict__ dbuf, const float* __restrict__ x,
                                                    float* __restrict__ s5)
{
  int c = blockIdx.x, b = blockIdx.y, tid = threadIdx.x;
  const float* dp = dbuf + ((long)(b*C_ + c))*4096;
  const float* xp = x + ((long)(b*C_ + c))*4096;
  float sd = 0, sd2 = 0, sx = 0, sx2 = 0, sdx = 0;
  for (int it = 0; it < 16; it++){
    float d = dp[it*256 + tid];
    float xv = xp[it*256 + tid];
    sd += d; sd2 += d*d; sx += xv; sx2 += xv*xv; sdx += d*xv;
  }
  __shared__ float red[256];
  float r0 = bred1(sd, red); float r1 = bred1(sd2, red); float r2 = bred1(sx, red);
  float r3 = bred1(sx2, red); float r4 = bred1(sdx, red);
  if (tid == 0){
    float* o = s5 + (long)(b*C_ + c)*5;
    o[0] = r0; o[1] = r1; o[2] = r2; o[3] = r3; o[4] = r4;
  }
}

// ---------------- collapse bn -> gn -> (+x) -> gn into out = P*d + Q*x + R ---------
// grid (B), block 256
__global__ void coeff_kernel(const float* __restrict__ s5, const float* __restrict__ dbn_g, const float* __restrict__ dbn_b,
                             const float* __restrict__ gn_g, const float* __restrict__ gn_b, float* __restrict__ pqr)
{
  int b = blockIdx.x, c = threadIdx.x, g = c >> 3;
  float sd = 0, sd2 = 0;
  for (int bb = 0; bb < 8; bb++){ sd += s5[(long)(bb*C_ + c)*5 + 0]; sd2 += s5[(long)(bb*C_ + c)*5 + 1]; }
  float inv_cnt = 1.f/32768.f;
  float mB = sd*inv_cnt;
  float vB = sd2*inv_cnt - mB*mB;
  float ab = dbn_g[c] * rsqrtf(vclamp(vB));
  float db = dbn_b[c] - mB*ab;
  const float* s = s5 + (long)(b*C_ + c)*5;
  float inv_n = 1.f/4096.f;
  float m = s[0]*inv_n, Ed2 = s[1]*inv_n, mx = s[2]*inv_n, Ex2 = s[3]*inv_n, Edx = s[4]*inv_n;
  float Ev = ab*m + db;
  float Ev2 = ab*ab*Ed2 + 2.f*ab*db*m + db*db;
  __shared__ float e1[256], e2[256];
  e1[c] = Ev; e2[c] = Ev2;
  __syncthreads();
  float m1 = 0, q1 = 0;
  for (int k = 0; k < 8; k++){ m1 += e1[(g << 3) + k]; q1 += e2[(g << 3) + k]; }
  m1 *= 0.125f; q1 *= 0.125f;
  float inv1 = rsqrtf(vclamp(q1 - m1*m1));
  float gg = gn_g[c];
  float A1 = inv1*gg;
  float D1 = gn_b[c] - m1*A1;
  float al = A1*ab;
  float be = A1*db + D1;
  float Et = al*m + be + mx;
  float Et2 = al*al*Ed2 + 2.f*al*be*m + be*be + 2.f*al*Edx + 2.f*be*mx + Ex2;
  __syncthreads();
  e1[c] = Et; e2[c] = Et2;
  __syncthreads();
  float m2 = 0, q2 = 0;
  for (int k = 0; k < 8; k++){ m2 += e1[(g << 3) + k]; q2 += e2[(g << 3) + k]; }
  m2 *= 0.125f; q2 *= 0.125f;
  float inv2 = rsqrtf(vclamp(q2 - m2*m2));
  float G = inv2*gg;
  float* o = pqr + (long)(b*C_ + c)*3;
  o[0] = G*al;
  o[1] = G;
  o[2] = G*(be - m2) + gn_b[c];
}

// ---------------- final elementwise: out = P*out + Q*x + R (in-place on d_out) -----
// grid (C, B), block 256
__global__ __launch_bounds__(256) void final_kernel(const float* __restrict__ x,
    const float* __restrict__ pqr, float* __restrict__ out)
{
  int c = blockIdx.x, b = blockIdx.y, tid = threadIdx.x;
  const float* o = pqr + (long)(b*C_ + c)*3;
  float P = o[0], Q = o[1], R = o[2];
  long base = ((long)(b*C_ + c))*4096;
  for (int it = 0; it < 16; it++){
    long idx = base + it*256 + tid;
    out[idx] = P*out[idx] + Q*x[idx] + R;
  }
}

extern "C" void kernel_launch(void* const* d_in, const int* in_sizes, int n_in,
                              void* d_out, int out_size, void* d_ws, size_t ws_size,
                              hipStream_t stream)
{
  (void)in_sizes; (void)n_in; (void)out_size; (void)ws_size;
  // ALL inputs/outputs are float32.
  const float* x         = (const float*)d_in[0];
  const float* pos       = (const float*)d_in[1];
  const float* ln_w      = (const float*)d_in[2];
  const float* ln_b      = (const float*)d_in[3];
  const float* proj_w    = (const float*)d_in[4];
  const float* proj_b    = (const float*)d_in[5];
  const float* up_dw_w   = (const float*)d_in[6];
  const float* up_bn1_g  = (const float*)d_in[7];
  const float* up_bn1_b  = (const float*)d_in[8];
  const float* up_pw_w   = (const float*)d_in[9];
  const float* up_bn2_g  = (const float*)d_in[10];
  const float* up_bn2_b  = (const float*)d_in[11];
  const float* down_pw_w = (const float*)d_in[12];
  const float* down_bn_g = (const float*)d_in[13];
  const float* down_bn_b = (const float*)d_in[14];
  const float* gn_g      = (const float*)d_in[15];
  const float* gn_b      = (const float*)d_in[16];
  const float* f_in_w    = (const float*)d_in[17];
  const float* f_conv_w  = (const float*)d_in[18];
  const float* f_conv_b  = (const float*)d_in[19];
  const float* f_xproj_w = (const float*)d_in[20];
  const float* f_dt_w    = (const float*)d_in[21];
  const float* f_dt_b    = (const float*)d_in[22];
  const float* f_Alog    = (const float*)d_in[23];
  const float* f_D       = (const float*)d_in[24];
  const float* f_out_w   = (const float*)d_in[25];
  const float* b_in_w    = (const float*)d_in[26];
  const float* b_conv_w  = (const float*)d_in[27];
  const float* b_conv_b  = (const float*)d_in[28];
  const float* b_xproj_w = (const float*)d_in[29];
  const float* b_dt_w    = (const float*)d_in[30];
  const float* b_dt_b    = (const float*)d_in[31];
  const float* b_Alog    = (const float*)d_in[32];
  const float* b_D       = (const float*)d_in[33];
  const float* b_out_w   = (const float*)d_in[34];

  // ======== workspace layout, PEAK = 4MB + 64MB = 68MB ========
  char* sb = (char*)d_ws;
  float* statz = (float*)(sb);               // 1536 f (zeroed each launch)
  float* abn   = (float*)(sb + 8192);        // 1024 f
  float* gnAD  = (float*)(sb + 16384);       // 4096 f
  float* stat5 = (float*)(sb + 65536);       // 10240 f
  float* pqr   = (float*)(sb + 131072);      // 6144 f
  float* rmrn  = (float*)(sb + 1*MB);        // 2MB: 2 x (1024,256)
  char* big = sb + 4*MB;
  float* pool4  = (float*)(big + 0*MB);      // 2 MB
  float* hbuf   = (float*)(big + 2*MB);      // 4 MB
  float* xzbuf  = (float*)(big + 6*MB);      // 16 MB
  float* ubuf   = (float*)(big + 22*MB);     // 8 MB
  float* dblbuf = (float*)(big + 30*MB);     // 768 KB
  float* dtbuf  = (float*)(big + 31*MB);     // 8 MB
  float* ybuf   = (float*)(big + 39*MB);     // 8 MB
  float* mout   = (float*)(big + 47*MB);     // 4 MB
  float* cbuf   = (float*)(big + 51*MB);     // 4 MB
  float* respre = (float*)(big + 55*MB);     // 2 MB  (ends at 57MB < 64MB)
  bf16*  z2buf  = (bf16*)(big);              // 64 MB bf16 (phase 2/3)
  float* dbuf   = (float*)d_out;             // 32 MB fp32 (phase 3)

  float* bn1sum = statz;        float* bn1sq = statz + 256;
  float* bn2sum = statz + 512;  float* bn2sq = statz + 768;
  float* gnsum  = statz + 1024; float* gnsq  = statz + 1280;
  float* abn1 = abn;       float* dbn1 = abn + 256;
  float* abn2 = abn + 512; float* dbn2 = abn + 768;
  float* gnA = gnAD;       float* gnD = gnAD + 2048;
  float* pcolmax = pool4;
  float* pcolmin = pool4 + 131072;
  float* prowmax = pool4 + 262144;
  float* prowmin = pool4 + 393216;

  hipMemsetAsync(statz, 0, 1536*sizeof(float), stream);

  // ---- phase 1: pooling + LN + mamba x4 (f/b x max/min) -> rmrn ----
  pool1_kernel<<<dim3(256, 8), 64, 0, stream>>>(x, pos, pcolmax, pcolmin, prowmax, prowmin);
  pool2_kernel<<<dim3(128, 8), 256, 0, stream>>>(pcolmax, pcolmin, prowmax, prowmin, ln_w, ln_b, hbuf);
  gemm_kernel<<<dim3(16, 16, 4), 256, 0, stream>>>(hbuf, 262144, 256, f_in_w, b_in_w, nullptr, nullptr, 2,
                                                   xzbuf, 1048576, 1024, 1024, 1024, 256, 0);
  conv1d_kernel<<<dim3(128, 8, 4), 512, 0, stream>>>(xzbuf, f_conv_w, f_conv_b, b_conv_w, b_conv_b, ubuf);
  gemm_kernel<<<dim3(1, 16, 4), 256, 0, stream>>>(ubuf, 524288, 512, f_xproj_w, b_xproj_w, nullptr, nullptr, 2,
                                                  dblbuf, 49152, 48, 1024, 48, 512, 0);
  gemm_kernel<<<dim3(8, 16, 4), 256, 0, stream>>>(dblbuf, 49152, 48, f_dt_w, b_dt_w, f_dt_b, b_dt_b, 2,
                                                  dtbuf, 524288, 512, 1024, 512, 16, 2);
  scan_kernel<<<dim3(2, 8, 4), 256, 0, stream>>>(dtbuf, ubuf, dblbuf, xzbuf, f_Alog, f_D, b_Alog, b_D, ybuf);
  gemm_kernel<<<dim3(4, 16, 4), 256, 0, stream>>>(ybuf, 524288, 512, f_out_w, b_out_w, nullptr, nullptr, 2,
                                                  mout, 262144, 256, 1024, 256, 512, 0);
  ln_kernel<<<dim3(128, 8, 4), 256, 0, stream>>>(mout, cbuf, cbuf + 524288, ln_w, ln_b, 1);
  gemm_kernel<<<dim3(4, 16, 2), 256, 0, stream>>>(cbuf, 524288, 512, proj_w, proj_w, proj_b, proj_b, 2,
                                                  respre, 262144, 256, 1024, 256, 512, 0);
  ln_kernel<<<dim3(128, 8, 2), 256, 0, stream>>>(respre, rmrn, nullptr, ln_w, ln_b, 0);

  // ---- phase 2: z path (mamba buffers dead; big region becomes z2buf) ----
  dwstats_kernel<<<2048, 256, 0, stream>>>(x, up_dw_w, bn1sum, bn1sq);
  fin_bn_kernel<<<1, 256, 0, stream>>>(bn1sum, bn1sq, up_bn1_g, up_bn1_b, 1.f/131072.f, abn1, dbn1);
  pwz_gemm_kernel<<<dim3(256, 1, 8), 256, 0, stream>>>(x, up_dw_w, up_pw_w, abn1, dbn1, z2buf);
  chstats_kernel<<<dim3(256, 8), 256, 0, stream>>>(z2buf, bn2sum, bn2sq);
  fin_bn_kernel<<<1, 256, 0, stream>>>(bn2sum, bn2sq, up_bn2_g, up_bn2_b, 1.f/131072.f, abn2, dbn2);

  // ---- phase 3: merge + tail ----
  hsig_kernel<<<dim3(256, 8), 256, 0, stream>>>(z2buf, rmrn, rmrn + 262144, abn2, dbn2, gnsum, gnsq);
  fin_gn_kernel<<<8, 256, 0, stream>>>(gnsum, gnsq, gn_g, gn_b, gnA, gnD);
  pwdown_gemm_kernel<<<dim3(64, 4, 8), 256, 0, stream>>>(z2buf, down_pw_w, gnA, gnD, dbuf);
  stat5_kernel<<<dim3(256, 8), 256, 0, stream>>>(dbuf, x, stat5);
  coeff_kernel<<<8, 256, 0, stream>>>(stat5, down_bn_g, down_bn_b, gn_g, gn_b, pqr);
  final_kernel<<<dim3(256, 8), 256, 0, stream>>>(x, pqr, (float*)d_out);
}

// Round 6
// 1018.788 us; speedup vs baseline: 1.9186x; 1.8803x over previous
//
#include <hip/hip_runtime.h>
#include <hip/hip_bf16.h>

typedef __hip_bfloat16 bf16;

#define B_ 8
#define C_ 256
#define L_ 128
#define MB 1048576UL

__device__ inline float b2f(bf16 v){ return __bfloat162float(v); }
__device__ inline bf16 f2b(float v){ return __float2bfloat16(v); }
__device__ inline float siluf(float x){ return x / (1.f + expf(-x)); }
__device__ inline float softplusf(float x){ return (x > 20.f) ? x : log1pf(expf(x)); }
__device__ inline float vclamp(float v){ return fmaxf(v, 0.f) + 1e-5f; }

// block = 256 threads. red must hold 512 floats.
__device__ inline void bred2(float& a, float& b, float* red){
  int t = threadIdx.x;
  __syncthreads();
  red[t] = a; red[256 + t] = b;
  __syncthreads();
  for (int off = 128; off > 0; off >>= 1){
    if (t < off){ red[t] += red[t + off]; red[256 + t] += red[256 + t + off]; }
    __syncthreads();
  }
  a = red[0]; b = red[256];
}
__device__ inline float bred1(float a, float* red){
  int t = threadIdx.x;
  __syncthreads();
  red[t] = a; __syncthreads();
  for (int off = 128; off > 0; off >>= 1){
    if (t < off) red[t] += red[t + off];
    __syncthreads();
  }
  return red[0];
}

// ---------------- pooling step 1: row/col max/min + argmax + pos-embed -------------
// grid (C, B), block 64
__global__ __launch_bounds__(64) void pool1_kernel(const float* __restrict__ x, const float* __restrict__ pos,
    float* __restrict__ pcolmax, float* __restrict__ pcolmin,
    float* __restrict__ prowmax, float* __restrict__ prowmin)
{
  int c = blockIdx.x, b = blockIdx.y, t = threadIdx.x;
  __shared__ float xs[64][65];
  const float* xp = x + ((long)(b*C_ + c))*4096;
  for (int i = 0; i < 64; i++) xs[i][t] = xp[i*64 + t];
  __syncthreads();
  // jax.image.resize 'linear' 16->64: half-pixel coords, edge clamp
  float tt = 0.25f*(float)t - 0.375f;
  const float* pp = pos + c*16;
  float pe;
  if (tt <= 0.f) pe = pp[0];
  else if (tt >= 15.f) pe = pp[15];
  else { int f = (int)floorf(tt); float w = tt - (float)f; pe = pp[f]*(1.f - w) + pp[f+1]*w; }
  float vmax = -1e30f, vmin = 1e30f; int amax = 0, amin = 0;
  for (int j = 0; j < 64; j++){
    float v = xs[t][j];
    if (v > vmax){ vmax = v; amax = j; }
    if (v < vmin){ vmin = v; amin = j; }
  }
  long o = (long)(b*64 + t)*C_ + c;
  prowmax[o] = vmax + pe + (float)amax;
  prowmin[o] = vmin + pe + (float)amin;
  vmax = -1e30f; vmin = 1e30f; amax = 0; amin = 0;
  for (int i = 0; i < 64; i++){
    float v = xs[i][t];
    if (v > vmax){ vmax = v; amax = i; }
    if (v < vmin){ vmin = v; amin = i; }
  }
  pcolmax[o] = vmax + pe + (float)amax;
  pcolmin[o] = vmin + pe + (float)amin;
}

// ---------------- pooling step 2: LN over channels, write 4 mamba inputs -----------
// grid (128, B), block 256
__global__ __launch_bounds__(256) void pool2_kernel(const float* __restrict__ pcolmax, const float* __restrict__ pcolmin,
    const float* __restrict__ prowmax, const float* __restrict__ prowmin,
    const float* __restrict__ lnw, const float* __restrict__ lnb, float* __restrict__ hbuf)
{
  int r = blockIdx.x, b = blockIdx.y, c = threadIdx.x;
  __shared__ float red[512];
  int p = r & 63;
  long src = (long)(b*64 + p)*C_ + c;
  float vmax = (r < 64) ? pcolmax[src] : prowmax[src];
  float vmin = (r < 64) ? pcolmin[src] : prowmin[src];
  float gw = lnw[c], gb = lnb[c];
  long row = (long)b*L_ + r, frow = (long)b*L_ + (127 - r);
  float s = vmax, s2 = vmax*vmax;
  bred2(s, s2, red);
  float m = s*(1.f/256.f), var = s2*(1.f/256.f) - m*m;
  float o = (vmax - m)*rsqrtf(vclamp(var))*gw + gb;
  hbuf[0*262144 + row*C_ + c]  = o;
  hbuf[2*262144 + frow*C_ + c] = o;
  s = vmin; s2 = vmin*vmin;
  bred2(s, s2, red);
  m = s*(1.f/256.f); var = s2*(1.f/256.f) - m*m;
  o = (vmin - m)*rsqrtf(vclamp(var))*gw + gb;
  hbuf[1*262144 + row*C_ + c]  = o;
  hbuf[3*262144 + frow*C_ + c] = o;
}

// ---------------- dwconvT on-the-fly helper ----------------------------------------
__device__ inline float dwconvT_at(const float* __restrict__ xp, const float* __restrict__ w, int i, int j)
{
  float acc = 0.f;
  #pragma unroll
  for (int ki = 0; ki < 3; ki++){
    int pi = i + ki - 1;
    if (pi < 0 || (pi & 1)) continue;
    int xi = pi >> 1;
    if (xi >= 64) continue;
    #pragma unroll
    for (int kj = 0; kj < 3; kj++){
      int pj = j + kj - 1;
      if (pj < 0 || (pj & 1)) continue;
      int xj = pj >> 1;
      if (xj >= 64) continue;
      acc += w[(2-ki)*3 + (2-kj)] * xp[xi*64 + xj];
    }
  }
  return acc;
}

// ---------------- z1raw = dwconvT(x) as bf16 + bn1 stats (one pass) ----------------
// x plane staged in LDS; coalesced bf16 stores. grid (B*C), block 256.
__global__ __launch_bounds__(256) void dwz1_kernel(const float* __restrict__ x, const float* __restrict__ dw,
    bf16* __restrict__ z1, float* __restrict__ bn1sum, float* __restrict__ bn1sq)
{
  int bc = blockIdx.x; int c = bc & 255;
  int tid = threadIdx.x;
  __shared__ float xs[4096];
  const float* xp = x + (long)bc*4096;
  for (int it = 0; it < 16; it++) xs[it*256 + tid] = xp[it*256 + tid];
  float w[9];
  #pragma unroll
  for (int q = 0; q < 9; q++) w[q] = dw[c*9 + q];
  __syncthreads();
  bf16* zp = z1 + (long)bc*16384;
  float s = 0.f, s2 = 0.f;
  for (int it = 0; it < 64; it++){
    int p = it*256 + tid; int i = p >> 7, j = p & 127;
    float acc = dwconvT_at(xs, w, i, j);
    zp[p] = f2b(acc);
    s += acc; s2 += acc*acc;
  }
  __shared__ float red[512];
  bred2(s, s2, red);
  if (tid == 0){ atomicAdd(&bn1sum[c], s); atomicAdd(&bn1sq[c], s2); }
}

// ---------------- bn finalize: per-channel affine ----------------------------------
__global__ void fin_bn_kernel(const float* __restrict__ sum, const float* __restrict__ sq,
                              const float* __restrict__ g, const float* __restrict__ b,
                              float cnt_inv, float* __restrict__ a, float* __restrict__ d)
{
  int c = threadIdx.x;
  float m = sum[c]*cnt_inv;
  float v = sq[c]*cnt_inv - m*m;
  float aa = g[c] * rsqrtf(vclamp(v));
  a[c] = aa;
  d[c] = b[c] - m*aa;
}

// ---------------- up-pw GEMM: z2[b,o,p] = sum_c W[o,c]*relu(fa[c]*z1[b,c,p]+fd[c]) -
// Clean dense GEMM over materialized z1 (bf16): coalesced bf16x2 B-loads, no
// scattered x reads (round-5's latency killer). 64x64 tile, 4x4 micro-tile.
// grid (256, 4, B), block 256
__global__ __launch_bounds__(256) void pwz_gemm_kernel(const bf16* __restrict__ z1,
    const float* __restrict__ W, const float* __restrict__ fa, const float* __restrict__ fd,
    bf16* __restrict__ z2)
{
  int b = blockIdx.z;
  int n0 = blockIdx.x*64, m0 = blockIdx.y*64;
  __shared__ __align__(16) float As[16][68];
  __shared__ __align__(16) float Bs[16][68];
  int tid = threadIdx.x, tx = tid & 15, ty = tid >> 4;
  float acc[4][4] = {};
  for (int c0 = 0; c0 < C_; c0 += 16){
    #pragma unroll
    for (int q = 0; q < 4; q++){
      int e = tid + q*256; int mm = e >> 4, kk = e & 15;
      As[kk][mm] = W[(m0 + mm)*C_ + c0 + kk];
    }
    #pragma unroll
    for (int q = 0; q < 2; q++){
      int kk = (tid >> 5) + q*8; int nn = (tid & 31)*2;
      int c = c0 + kk;
      float a1 = fa[c], d1 = fd[c];
      const bf16* zp = &z1[((long)(b*C_ + c))*16384 + n0 + nn];
      unsigned int u = *(const unsigned int*)zp;
      bf16 t0, t1;
      *(unsigned short*)&t0 = (unsigned short)(u & 0xffff);
      *(unsigned short*)&t1 = (unsigned short)(u >> 16);
      Bs[kk][nn]     = fmaxf(b2f(t0)*a1 + d1, 0.f);
      Bs[kk][nn + 1] = fmaxf(b2f(t1)*a1 + d1, 0.f);
    }
    __syncthreads();
    #pragma unroll
    for (int kk = 0; kk < 16; kk++){
      float4 a4 = *(const float4*)&As[kk][ty*4];
      float4 b4 = *(const float4*)&Bs[kk][tx*4];
      float av[4] = {a4.x, a4.y, a4.z, a4.w};
      float bv[4] = {b4.x, b4.y, b4.z, b4.w};
      #pragma unroll
      for (int mm = 0; mm < 4; mm++)
        #pragma unroll
        for (int nn = 0; nn < 4; nn++) acc[mm][nn] += av[mm]*bv[nn];
    }
    __syncthreads();
  }
  #pragma unroll
  for (int mm = 0; mm < 4; mm++){
    int o = m0 + ty*4 + mm;
    bf16 v[4];
    #pragma unroll
    for (int nn = 0; nn < 4; nn++) v[nn] = f2b(acc[mm][nn]);
    *(uint2*)&z2[((long)(b*C_ + o))*16384 + n0 + tx*4] = *(const uint2*)v;
  }
}

// ---------------- per-channel stats of bf16 tensor (B,C,16384) ---------------------
// grid (C, B), block 256
__global__ __launch_bounds__(256) void chstats_kernel(const bf16* __restrict__ t,
                                                      float* __restrict__ sum, float* __restrict__ sq)
{
  int c = blockIdx.x, b = blockIdx.y, tid = threadIdx.x;
  const bf16* p = t + ((long)(b*C_ + c))*16384;
  float s = 0.f, s2 = 0.f;
  for (int it = 0; it < 64; it++){ float v = b2f(p[it*256 + tid]); s += v; s2 += v*v; }
  __shared__ float red[512];
  bred2(s, s2, red);
  if (tid == 0){ atomicAdd(&sum[c], s); atomicAdd(&sq[c], s2); }
}

// ---------------- generic GEMM: C[m,n] = act(sum_k A[m,k] W[n,k] + bias[n]) --------
// A fp32 (lda, batch stride sA), W fp32 (N,K) row-major, batched over grid.z.
// grid ((N+63)/64, (M+63)/64, nbatch), block 256
__global__ __launch_bounds__(256) void gemm_kernel(
  const float* __restrict__ Abase, long sA, int lda,
  const float* __restrict__ W0, const float* __restrict__ W1,
  const float* __restrict__ bias0, const float* __restrict__ bias1, int wsplit,
  float* __restrict__ Cbase, long sC, int ldc,
  int M, int N, int K, int act)
{
  int z = blockIdx.z;
  const float* A = Abase + (long)z*sA;
  float* Cp = Cbase + (long)z*sC;
  const float* W = (z >= wsplit) ? W1 : W0;
  const float* bias = (z >= wsplit) ? bias1 : bias0;
  int m0 = blockIdx.y*64, n0 = blockIdx.x*64;
  __shared__ __align__(16) float As[16][68];
  __shared__ __align__(16) float Ws[16][68];
  int tid = threadIdx.x, tx = tid & 15, ty = tid >> 4;
  float acc[4][4] = {};
  for (int k0 = 0; k0 < K; k0 += 16){
    #pragma unroll
    for (int q = 0; q < 4; q++){
      int e = tid + q*256; int r = e >> 4, kk = e & 15;
      int mi = m0 + r, ki = k0 + kk;
      As[kk][r] = (mi < M && ki < K) ? A[(long)mi*lda + ki] : 0.f;
    }
    #pragma unroll
    for (int q = 0; q < 4; q++){
      int e = tid + q*256; int n = e >> 4, kk = e & 15;
      int ni = n0 + n, ki = k0 + kk;
      Ws[kk][n] = (ni < N && ki < K) ? W[(long)ni*K + ki] : 0.f;
    }
    __syncthreads();
    #pragma unroll
    for (int kk = 0; kk < 16; kk++){
      float4 a4 = *(const float4*)&As[kk][ty*4];
      float4 b4 = *(const float4*)&Ws[kk][tx*4];
      float av[4] = {a4.x, a4.y, a4.z, a4.w};
      float bv[4] = {b4.x, b4.y, b4.z, b4.w};
      #pragma unroll
      for (int mm = 0; mm < 4; mm++)
        #pragma unroll
        for (int nn = 0; nn < 4; nn++) acc[mm][nn] += av[mm]*bv[nn];
    }
    __syncthreads();
  }
  #pragma unroll
  for (int mm = 0; mm < 4; mm++){
    int mi = m0 + ty*4 + mm;
    if (mi >= M) continue;
    #pragma unroll
    for (int nn = 0; nn < 4; nn++){
      int ni = n0 + tx*4 + nn;
      if (ni >= N) continue;
      float v = acc[mm][nn];
      if (bias) v += bias[ni];
      if (act == 2) v = softplusf(v);
      Cp[(long)mi*ldc + ni] = v;
    }
  }
}

// ---------------- depthwise causal conv1d (k=4) + silu -----------------------------
// grid (L, B, 4), block 512
__global__ __launch_bounds__(512) void conv1d_kernel(const float* __restrict__ xzb,
    const float* __restrict__ fw, const float* __restrict__ fb,
    const float* __restrict__ bw, const float* __restrict__ bb,
    float* __restrict__ ub)
{
  int l = blockIdx.x, b = blockIdx.y, v = blockIdx.z, d = threadIdx.x;
  const float* xm = xzb + (long)v*1024*1024;
  const float* w  = (v < 2) ? fw : bw;
  const float* cb = (v < 2) ? fb : bb;
  float acc = cb[d];
  #pragma unroll
  for (int k = 0; k < 4; k++){
    int ll = l - 3 + k;
    if (ll >= 0) acc += xm[(long)(b*L_ + ll)*1024 + d] * w[d*4 + k];
  }
  ub[(long)v*1024*512 + (long)(b*L_ + l)*512 + d] = siluf(acc);
}

// ---------------- selective scan ---------------------------------------------------
// grid (2, B, 4), block 256 : thread = one (b,d)
__global__ __launch_bounds__(256) void scan_kernel(const float* __restrict__ dtb, const float* __restrict__ ub,
    const float* __restrict__ dblb, const float* __restrict__ xzb,
    const float* __restrict__ fAlog, const float* __restrict__ fD,
    const float* __restrict__ bAlog, const float* __restrict__ bD,
    float* __restrict__ yb)
{
  int v = blockIdx.z, b = blockIdx.y;
  int d = blockIdx.x*256 + threadIdx.x;
  const float* dt  = dtb  + (long)v*1024*512;
  const float* u   = ub   + (long)v*1024*512;
  const float* dbl = dblb + (long)v*1024*48;
  const float* zg  = xzb  + (long)v*1024*1024 + 512;
  const float* Alog = (v < 2) ? fAlog : bAlog;
  const float* Dp   = (v < 2) ? fD : bD;
  float a[16];
  #pragma unroll
  for (int n = 0; n < 16; n++) a[n] = -expf(Alog[d*16 + n]);
  float Dv = Dp[d];
  float h[16];
  #pragma unroll
  for (int n = 0; n < 16; n++) h[n] = 0.f;
  __shared__ float bc[2][32];
  float* yo = yb + (long)v*1024*512;
  for (int l = 0; l < L_; l++){
    int row = b*L_ + l;
    if (threadIdx.x < 32) bc[l & 1][threadIdx.x] = dbl[row*48 + 16 + threadIdx.x];
    __syncthreads();
    float dtv = dt[(long)row*512 + d];
    float uv  = u [(long)row*512 + d];
    float zgv = zg[(long)row*1024 + d];
    float dtu = dtv*uv;
    float acc = 0.f;
    const float* Bm = bc[l & 1];
    #pragma unroll
    for (int n = 0; n < 16; n++){
      float dA = expf(dtv*a[n]);
      h[n] = dA*h[n] + dtu*Bm[n];
      acc += h[n]*Bm[16 + n];
    }
    float yv = acc + Dv*uv;
    yo[(long)row*512 + d] = yv * siluf(zgv);
  }
}

// ---------------- LayerNorm over C, two output modes -------------------------------
// grid (128, B, NV), block 256
__global__ __launch_bounds__(256) void ln_kernel(const float* __restrict__ inb, float* __restrict__ out0,
    float* __restrict__ out1, const float* __restrict__ lnw, const float* __restrict__ lnb, int mode)
{
  int r = blockIdx.x, b = blockIdx.y, v = blockIdx.z, c = threadIdx.x;
  long row = (long)b*L_ + r;
  float val = inb[((long)v*1024 + row)*C_ + c];
  __shared__ float red[512];
  float s = val, s2 = val*val;
  bred2(s, s2, red);
  float m = s*(1.f/256.f), var = s2*(1.f/256.f) - m*m;
  float o = (val - m)*rsqrtf(vclamp(var))*lnw[c] + lnb[c];
  if (mode == 1){
    long frow = (long)b*L_ + (127 - r);
    if (v == 0)      out0[row*512 + c] = o;
    else if (v == 1) out1[row*512 + c] = o;
    else if (v == 2) out0[frow*512 + 256 + c] = o;
    else             out1[frow*512 + 256 + c] = o;
  } else {
    out0[((long)v*1024 + row)*C_ + c] = o;
  }
}

// ---------------- hsig(rm+rn)*clip(bn2(z2)) + gn stats; resq IN-PLACE in z2 --------
// Race-free: group g reads p in [g*1024,(g+1)*1024); after a barrier it writes
// q in [g*256,(g+1)*256) — every write index < every future read index.
// grid (C, B), block 256
__global__ __launch_bounds__(256) void hsig_kernel(bf16* __restrict__ z2, const float* __restrict__ rm,
    const float* __restrict__ rn, const float* __restrict__ a2, const float* __restrict__ d2,
    float* __restrict__ gnsum, float* __restrict__ gnsq)
{
  int c = blockIdx.x, b = blockIdx.y, tid = threadIdx.x;
  __shared__ float rms[128], rns[128];
  if (tid < 128){
    rms[tid] = rm[(long)(b*L_ + tid)*C_ + c];
    rns[tid] = rn[(long)(b*L_ + tid)*C_ + c];
  }
  __syncthreads();
  float aa = a2[c], dd = d2[c];
  bf16* zp = z2 + ((long)(b*C_ + c))*16384;
  float s = 0.f, s2 = 0.f;
  for (int g = 0; g < 16; g++){
    float tv[4]; int wq[4];
    #pragma unroll
    for (int q = 0; q < 4; q++){
      int p = g*1024 + q*256 + tid; int i = p >> 7, j = p & 127;
      float zv = b2f(zp[p])*aa + dd;
      zv = fminf(fmaxf(zv, 0.f), 6.f);
      float gate = rms[i] + rns[j];
      gate = fminf(fmaxf(gate + 3.f, 0.f), 6.f) * (1.f/6.f);
      float t = gate*zv;
      s += t; s2 += t*t;
      tv[q] = t;
      wq[q] = (((i | j) & 1) == 0) ? ((i >> 1)*64 + (j >> 1)) : -1;
    }
    __syncthreads();
    #pragma unroll
    for (int q = 0; q < 4; q++)
      if (wq[q] >= 0) zp[wq[q]] = f2b(tv[q]);
  }
  __shared__ float red[512];
  bred2(s, s2, red);
  if (tid == 0){ atomicAdd(&gnsum[b*32 + (c >> 3)], s); atomicAdd(&gnsq[b*32 + (c >> 3)], s2); }
}

// ---------------- gn finalize to per-(b,c) affine ----------------------------------
// grid (B), block 256
__global__ void fin_gn_kernel(const float* __restrict__ gnsum, const float* __restrict__ gnsq,
                              const float* __restrict__ g, const float* __restrict__ bb,
                              float* __restrict__ gnA, float* __restrict__ gnD)
{
  int b = blockIdx.x, c = threadIdx.x, gr = c >> 3;
  float inv_cnt = 1.f/131072.f;
  float m = gnsum[b*32 + gr]*inv_cnt;
  float v = gnsq[b*32 + gr]*inv_cnt - m*m;
  float inv = rsqrtf(vclamp(v));
  float A = inv*g[c];
  gnA[b*C_ + c] = A;
  gnD[b*C_ + c] = bb[c] - m*A;
}

// ---------------- down-pw GEMM: d[b,o,s] = sum_c W[o,c]*(resq[b,c,s]*gnA+gnD) ------
// resq rows strided 16384 (in-place inside z2); out fp32 (d_out), stride 4096.
// grid (64, 4, B), block 256
__global__ __launch_bounds__(256) void pwdown_gemm_kernel(const bf16* __restrict__ in,
    const float* __restrict__ W, const float* __restrict__ fa, const float* __restrict__ fd,
    float* __restrict__ out)
{
  int b = blockIdx.z;
  int n0 = blockIdx.x*64, m0 = blockIdx.y*64;
  __shared__ __align__(16) float As[16][68];
  __shared__ __align__(16) float Bs[16][68];
  int tid = threadIdx.x, tx = tid & 15, ty = tid >> 4;
  float acc[4][4] = {};
  for (int c0 = 0; c0 < C_; c0 += 16){
    #pragma unroll
    for (int q = 0; q < 4; q++){
      int e = tid + q*256; int mm = e >> 4, kk = e & 15;
      As[kk][mm] = W[(m0 + mm)*C_ + c0 + kk];
    }
    #pragma unroll
    for (int q = 0; q < 4; q++){
      int e = tid + q*256; int kk = e >> 6, nn = e & 63;
      int c = c0 + kk;
      int ai = b*C_ + c;
      float v = b2f(in[((long)(b*C_ + c))*16384 + n0 + nn]);
      Bs[kk][nn] = v*fa[ai] + fd[ai];
    }
    __syncthreads();
    #pragma unroll
    for (int kk = 0; kk < 16; kk++){
      float4 a4 = *(const float4*)&As[kk][ty*4];
      float4 b4 = *(const float4*)&Bs[kk][tx*4];
      float av[4] = {a4.x, a4.y, a4.z, a4.w};
      float bv[4] = {b4.x, b4.y, b4.z, b4.w};
      #pragma unroll
      for (int mm = 0; mm < 4; mm++)
        #pragma unroll
        for (int nn = 0; nn < 4; nn++) acc[mm][nn] += av[mm]*bv[nn];
    }
    __syncthreads();
  }
  #pragma unroll
  for (int mm = 0; mm < 4; mm++){
    int o = m0 + ty*4 + mm;
    #pragma unroll
    for (int nn = 0; nn < 4; nn++)
      out[((long)(b*C_ + o))*4096 + n0 + tx*4 + nn] = acc[mm][nn];
  }
}

// ---------------- 5 moments per (b,c): sum d, d^2, x, x^2, dx ----------------------
// grid (C, B), block 256
__global__ __launch_bounds__(256) void stat5_kernel(const float* __restrict__ dbuf, const float* __restrict__ x,
                                                    float* __restrict__ s5)
{
  int c = blockIdx.x, b = blockIdx.y, tid = threadIdx.x;
  const float* dp = dbuf + ((long)(b*C_ + c))*4096;
  const float* xp = x + ((long)(b*C_ + c))*4096;
  float sd = 0, sd2 = 0, sx = 0, sx2 = 0, sdx = 0;
  for (int it = 0; it < 16; it++){
    float d = dp[it*256 + tid];
    float xv = xp[it*256 + tid];
    sd += d; sd2 += d*d; sx += xv; sx2 += xv*xv; sdx += d*xv;
  }
  __shared__ float red[256];
  float r0 = bred1(sd, red); float r1 = bred1(sd2, red); float r2 = bred1(sx, red);
  float r3 = bred1(sx2, red); float r4 = bred1(sdx, red);
  if (tid == 0){
    float* o = s5 + (long)(b*C_ + c)*5;
    o[0] = r0; o[1] = r1; o[2] = r2; o[3] = r3; o[4] = r4;
  }
}

// ---------------- collapse bn -> gn -> (+x) -> gn into out = P*d + Q*x + R ---------
// grid (B), block 256
__global__ void coeff_kernel(const float* __restrict__ s5, const float* __restrict__ dbn_g, const float* __restrict__ dbn_b,
                             const float* __restrict__ gn_g, const float* __restrict__ gn_b, float* __restrict__ pqr)
{
  int b = blockIdx.x, c = threadIdx.x, g = c >> 3;
  float sd = 0, sd2 = 0;
  for (int bb = 0; bb < 8; bb++){ sd += s5[(long)(bb*C_ + c)*5 + 0]; sd2 += s5[(long)(bb*C_ + c)*5 + 1]; }
  float inv_cnt = 1.f/32768.f;
  float mB = sd*inv_cnt;
  float vB = sd2*inv_cnt - mB*mB;
  float ab = dbn_g[c] * rsqrtf(vclamp(vB));
  float db = dbn_b[c] - mB*ab;
  const float* s = s5 + (long)(b*C_ + c)*5;
  float inv_n = 1.f/4096.f;
  float m = s[0]*inv_n, Ed2 = s[1]*inv_n, mx = s[2]*inv_n, Ex2 = s[3]*inv_n, Edx = s[4]*inv_n;
  float Ev = ab*m + db;
  float Ev2 = ab*ab*Ed2 + 2.f*ab*db*m + db*db;
  __shared__ float e1[256], e2[256];
  e1[c] = Ev; e2[c] = Ev2;
  __syncthreads();
  float m1 = 0, q1 = 0;
  for (int k = 0; k < 8; k++){ m1 += e1[(g << 3) + k]; q1 += e2[(g << 3) + k]; }
  m1 *= 0.125f; q1 *= 0.125f;
  float inv1 = rsqrtf(vclamp(q1 - m1*m1));
  float gg = gn_g[c];
  float A1 = inv1*gg;
  float D1 = gn_b[c] - m1*A1;
  float al = A1*ab;
  float be = A1*db + D1;
  float Et = al*m + be + mx;
  float Et2 = al*al*Ed2 + 2.f*al*be*m + be*be + 2.f*al*Edx + 2.f*be*mx + Ex2;
  __syncthreads();
  e1[c] = Et; e2[c] = Et2;
  __syncthreads();
  float m2 = 0, q2 = 0;
  for (int k = 0; k < 8; k++){ m2 += e1[(g << 3) + k]; q2 += e2[(g << 3) + k]; }
  m2 *= 0.125f; q2 *= 0.125f;
  float inv2 = rsqrtf(vclamp(q2 - m2*m2));
  float G = inv2*gg;
  float* o = pqr + (long)(b*C_ + c)*3;
  o[0] = G*al;
  o[1] = G;
  o[2] = G*(be - m2) + gn_b[c];
}

// ---------------- final elementwise: out = P*out + Q*x + R (in-place on d_out) -----
// grid (C, B), block 256
__global__ __launch_bounds__(256) void final_kernel(const float* __restrict__ x,
    const float* __restrict__ pqr, float* __restrict__ out)
{
  int c = blockIdx.x, b = blockIdx.y, tid = threadIdx.x;
  const float* o = pqr + (long)(b*C_ + c)*3;
  float P = o[0], Q = o[1], R = o[2];
  long base = ((long)(b*C_ + c))*4096;
  for (int it = 0; it < 16; it++){
    long idx = base + it*256 + tid;
    out[idx] = P*out[idx] + Q*x[idx] + R;
  }
}

extern "C" void kernel_launch(void* const* d_in, const int* in_sizes, int n_in,
                              void* d_out, int out_size, void* d_ws, size_t ws_size,
                              hipStream_t stream)
{
  (void)in_sizes; (void)n_in; (void)out_size; (void)ws_size;
  // ALL inputs/outputs are float32.
  const float* x         = (const float*)d_in[0];
  const float* pos       = (const float*)d_in[1];
  const float* ln_w      = (const float*)d_in[2];
  const float* ln_b      = (const float*)d_in[3];
  const float* proj_w    = (const float*)d_in[4];
  const float* proj_b    = (const float*)d_in[5];
  const float* up_dw_w   = (const float*)d_in[6];
  const float* up_bn1_g  = (const float*)d_in[7];
  const float* up_bn1_b  = (const float*)d_in[8];
  const float* up_pw_w   = (const float*)d_in[9];
  const float* up_bn2_g  = (const float*)d_in[10];
  const float* up_bn2_b  = (const float*)d_in[11];
  const float* down_pw_w = (const float*)d_in[12];
  const float* down_bn_g = (const float*)d_in[13];
  const float* down_bn_b = (const float*)d_in[14];
  const float* gn_g      = (const float*)d_in[15];
  const float* gn_b      = (const float*)d_in[16];
  const float* f_in_w    = (const float*)d_in[17];
  const float* f_conv_w  = (const float*)d_in[18];
  const float* f_conv_b  = (const float*)d_in[19];
  const float* f_xproj_w = (const float*)d_in[20];
  const float* f_dt_w    = (const float*)d_in[21];
  const float* f_dt_b    = (const float*)d_in[22];
  const float* f_Alog    = (const float*)d_in[23];
  const float* f_D       = (const float*)d_in[24];
  const float* f_out_w   = (const float*)d_in[25];
  const float* b_in_w    = (const float*)d_in[26];
  const float* b_conv_w  = (const float*)d_in[27];
  const float* b_conv_b  = (const float*)d_in[28];
  const float* b_xproj_w = (const float*)d_in[29];
  const float* b_dt_w    = (const float*)d_in[30];
  const float* b_dt_b    = (const float*)d_in[31];
  const float* b_Alog    = (const float*)d_in[32];
  const float* b_D       = (const float*)d_in[33];
  const float* b_out_w   = (const float*)d_in[34];

  // ======== workspace layout, PEAK = 4MB + 64MB + 64MB = 132MB ========
  // [0, 4MB): small stats + rmrn (live across all phases)
  // [4MB, 68MB): big region — phase 1: mamba intermediates (57MB);
  //              phase 2: z1raw (dwconvT(x), bf16, exactly 64 MiB)
  // [68MB, 132MB): z2buf bf16 (phase 2/3; resq written in-place inside it)
  // dbuf (B,C,64,64 fp32, 32MB) lives in d_out; final updates d_out in-place.
  char* sb = (char*)d_ws;
  float* statz = (float*)(sb);               // 1536 f (zeroed each launch)
  float* abn   = (float*)(sb + 8192);        // 1024 f
  float* gnAD  = (float*)(sb + 16384);       // 4096 f
  float* stat5 = (float*)(sb + 65536);       // 10240 f
  float* pqr   = (float*)(sb + 131072);      // 6144 f
  float* rmrn  = (float*)(sb + 1*MB);        // 2MB: 2 x (1024,256)
  char* big = sb + 4*MB;
  float* pool4  = (float*)(big + 0*MB);      // 2 MB
  float* hbuf   = (float*)(big + 2*MB);      // 4 MB
  float* xzbuf  = (float*)(big + 6*MB);      // 16 MB
  float* ubuf   = (float*)(big + 22*MB);     // 8 MB
  float* dblbuf = (float*)(big + 30*MB);     // 768 KB
  float* dtbuf  = (float*)(big + 31*MB);     // 8 MB
  float* ybuf   = (float*)(big + 39*MB);     // 8 MB
  float* mout   = (float*)(big + 47*MB);     // 4 MB
  float* cbuf   = (float*)(big + 51*MB);     // 4 MB
  float* respre = (float*)(big + 55*MB);     // 2 MB  (ends at 57MB < 64MB)
  bf16*  z1buf  = (bf16*)(big);              // 64 MiB bf16 (phase 2)
  bf16*  z2buf  = (bf16*)(sb + 68*MB);       // 64 MiB bf16 (phase 2/3)
  float* dbuf   = (float*)d_out;             // 32 MB fp32 (phase 3)

  float* bn1sum = statz;        float* bn1sq = statz + 256;
  float* bn2sum = statz + 512;  float* bn2sq = statz + 768;
  float* gnsum  = statz + 1024; float* gnsq  = statz + 1280;
  float* abn1 = abn;       float* dbn1 = abn + 256;
  float* abn2 = abn + 512; float* dbn2 = abn + 768;
  float* gnA = gnAD;       float* gnD = gnAD + 2048;
  float* pcolmax = pool4;
  float* pcolmin = pool4 + 131072;
  float* prowmax = pool4 + 262144;
  float* prowmin = pool4 + 393216;

  hipMemsetAsync(statz, 0, 1536*sizeof(float), stream);

  // ---- phase 1: pooling + LN + mamba x4 (f/b x max/min) -> rmrn ----
  pool1_kernel<<<dim3(256, 8), 64, 0, stream>>>(x, pos, pcolmax, pcolmin, prowmax, prowmin);
  pool2_kernel<<<dim3(128, 8), 256, 0, stream>>>(pcolmax, pcolmin, prowmax, prowmin, ln_w, ln_b, hbuf);
  gemm_kernel<<<dim3(16, 16, 4), 256, 0, stream>>>(hbuf, 262144, 256, f_in_w, b_in_w, nullptr, nullptr, 2,
                                                   xzbuf, 1048576, 1024, 1024, 1024, 256, 0);
  conv1d_kernel<<<dim3(128, 8, 4), 512, 0, stream>>>(xzbuf, f_conv_w, f_conv_b, b_conv_w, b_conv_b, ubuf);
  gemm_kernel<<<dim3(1, 16, 4), 256, 0, stream>>>(ubuf, 524288, 512, f_xproj_w, b_xproj_w, nullptr, nullptr, 2,
                                                  dblbuf, 49152, 48, 1024, 48, 512, 0);
  gemm_kernel<<<dim3(8, 16, 4), 256, 0, stream>>>(dblbuf, 49152, 48, f_dt_w, b_dt_w, f_dt_b, b_dt_b, 2,
                                                  dtbuf, 524288, 512, 1024, 512, 16, 2);
  scan_kernel<<<dim3(2, 8, 4), 256, 0, stream>>>(dtbuf, ubuf, dblbuf, xzbuf, f_Alog, f_D, b_Alog, b_D, ybuf);
  gemm_kernel<<<dim3(4, 16, 4), 256, 0, stream>>>(ybuf, 524288, 512, f_out_w, b_out_w, nullptr, nullptr, 2,
                                                  mout, 262144, 256, 1024, 256, 512, 0);
  ln_kernel<<<dim3(128, 8, 4), 256, 0, stream>>>(mout, cbuf, cbuf + 524288, ln_w, ln_b, 1);
  gemm_kernel<<<dim3(4, 16, 2), 256, 0, stream>>>(cbuf, 524288, 512, proj_w, proj_w, proj_b, proj_b, 2,
                                                  respre, 262144, 256, 1024, 256, 512, 0);
  ln_kernel<<<dim3(128, 8, 2), 256, 0, stream>>>(respre, rmrn, nullptr, ln_w, ln_b, 0);

  // ---- phase 2: z path (mamba buffers dead; big region becomes z1raw) ----
  dwz1_kernel<<<2048, 256, 0, stream>>>(x, up_dw_w, z1buf, bn1sum, bn1sq);
  fin_bn_kernel<<<1, 256, 0, stream>>>(bn1sum, bn1sq, up_bn1_g, up_bn1_b, 1.f/131072.f, abn1, dbn1);
  pwz_gemm_kernel<<<dim3(256, 4, 8), 256, 0, stream>>>(z1buf, up_pw_w, abn1, dbn1, z2buf);
  chstats_kernel<<<dim3(256, 8), 256, 0, stream>>>(z2buf, bn2sum, bn2sq);
  fin_bn_kernel<<<1, 256, 0, stream>>>(bn2sum, bn2sq, up_bn2_g, up_bn2_b, 1.f/131072.f, abn2, dbn2);

  // ---- phase 3: merge + tail ----
  hsig_kernel<<<dim3(256, 8), 256, 0, stream>>>(z2buf, rmrn, rmrn + 262144, abn2, dbn2, gnsum, gnsq);
  fin_gn_kernel<<<8, 256, 0, stream>>>(gnsum, gnsq, gn_g, gn_b, gnA, gnD);
  pwdown_gemm_kernel<<<dim3(64, 4, 8), 256, 0, stream>>>(z2buf, down_pw_w, gnA, gnD, dbuf);
  stat5_kernel<<<dim3(256, 8), 256, 0, stream>>>(dbuf, x, stat5);
  coeff_kernel<<<8, 256, 0, stream>>>(stat5, down_bn_g, down_bn_b, gn_g, gn_b, pqr);
  final_kernel<<<dim3(256, 8), 256, 0, stream>>>(x, pqr, (float*)d_out);
}

// Round 7
// 874.390 us; speedup vs baseline: 2.2355x; 1.1651x over previous
//
#include <hip/hip_runtime.h>
#include <hip/hip_bf16.h>

typedef __hip_bfloat16 bf16;
typedef __attribute__((ext_vector_type(8))) short bf16x8v;
typedef __attribute__((ext_vector_type(4))) float f32x4v;

#define B_ 8
#define C_ 256
#define L_ 128
#define MB 1048576UL

__device__ inline float b2f(bf16 v){ return __bfloat162float(v); }
__device__ inline bf16 f2b(float v){ return __float2bfloat16(v); }
__device__ inline float siluf(float x){ return x / (1.f + expf(-x)); }
__device__ inline float softplusf(float x){ return (x > 20.f) ? x : log1pf(expf(x)); }
__device__ inline float vclamp(float v){ return fmaxf(v, 0.f) + 1e-5f; }

// block = 256 threads. red must hold 512 floats.
__device__ inline void bred2(float& a, float& b, float* red){
  int t = threadIdx.x;
  __syncthreads();
  red[t] = a; red[256 + t] = b;
  __syncthreads();
  for (int off = 128; off > 0; off >>= 1){
    if (t < off){ red[t] += red[t + off]; red[256 + t] += red[256 + t + off]; }
    __syncthreads();
  }
  a = red[0]; b = red[256];
}
__device__ inline float bred1(float a, float* red){
  int t = threadIdx.x;
  __syncthreads();
  red[t] = a; __syncthreads();
  for (int off = 128; off > 0; off >>= 1){
    if (t < off) red[t] += red[t + off];
    __syncthreads();
  }
  return red[0];
}

// ---------------- pooling step 1: row/col max/min + argmax + pos-embed -------------
// grid (C, B), block 64
__global__ __launch_bounds__(64) void pool1_kernel(const float* __restrict__ x, const float* __restrict__ pos,
    float* __restrict__ pcolmax, float* __restrict__ pcolmin,
    float* __restrict__ prowmax, float* __restrict__ prowmin)
{
  int c = blockIdx.x, b = blockIdx.y, t = threadIdx.x;
  __shared__ float xs[64][65];
  const float* xp = x + ((long)(b*C_ + c))*4096;
  for (int i = 0; i < 64; i++) xs[i][t] = xp[i*64 + t];
  __syncthreads();
  // jax.image.resize 'linear' 16->64: half-pixel coords, edge clamp
  float tt = 0.25f*(float)t - 0.375f;
  const float* pp = pos + c*16;
  float pe;
  if (tt <= 0.f) pe = pp[0];
  else if (tt >= 15.f) pe = pp[15];
  else { int f = (int)floorf(tt); float w = tt - (float)f; pe = pp[f]*(1.f - w) + pp[f+1]*w; }
  float vmax = -1e30f, vmin = 1e30f; int amax = 0, amin = 0;
  for (int j = 0; j < 64; j++){
    float v = xs[t][j];
    if (v > vmax){ vmax = v; amax = j; }
    if (v < vmin){ vmin = v; amin = j; }
  }
  long o = (long)(b*64 + t)*C_ + c;
  prowmax[o] = vmax + pe + (float)amax;
  prowmin[o] = vmin + pe + (float)amin;
  vmax = -1e30f; vmin = 1e30f; amax = 0; amin = 0;
  for (int i = 0; i < 64; i++){
    float v = xs[i][t];
    if (v > vmax){ vmax = v; amax = i; }
    if (v < vmin){ vmin = v; amin = i; }
  }
  pcolmax[o] = vmax + pe + (float)amax;
  pcolmin[o] = vmin + pe + (float)amin;
}

// ---------------- pooling step 2: LN over channels, write 4 mamba inputs -----------
// grid (128, B), block 256
__global__ __launch_bounds__(256) void pool2_kernel(const float* __restrict__ pcolmax, const float* __restrict__ pcolmin,
    const float* __restrict__ prowmax, const float* __restrict__ prowmin,
    const float* __restrict__ lnw, const float* __restrict__ lnb, float* __restrict__ hbuf)
{
  int r = blockIdx.x, b = blockIdx.y, c = threadIdx.x;
  __shared__ float red[512];
  int p = r & 63;
  long src = (long)(b*64 + p)*C_ + c;
  float vmax = (r < 64) ? pcolmax[src] : prowmax[src];
  float vmin = (r < 64) ? pcolmin[src] : prowmin[src];
  float gw = lnw[c], gb = lnb[c];
  long row = (long)b*L_ + r, frow = (long)b*L_ + (127 - r);
  float s = vmax, s2 = vmax*vmax;
  bred2(s, s2, red);
  float m = s*(1.f/256.f), var = s2*(1.f/256.f) - m*m;
  float o = (vmax - m)*rsqrtf(vclamp(var))*gw + gb;
  hbuf[0*262144 + row*C_ + c]  = o;
  hbuf[2*262144 + frow*C_ + c] = o;
  s = vmin; s2 = vmin*vmin;
  bred2(s, s2, red);
  m = s*(1.f/256.f); var = s2*(1.f/256.f) - m*m;
  o = (vmin - m)*rsqrtf(vclamp(var))*gw + gb;
  hbuf[1*262144 + row*C_ + c]  = o;
  hbuf[3*262144 + frow*C_ + c] = o;
}

// ---------------- dwconvT on-the-fly helper ----------------------------------------
__device__ inline float dwconvT_at(const float* __restrict__ xp, const float* __restrict__ w, int i, int j)
{
  float acc = 0.f;
  #pragma unroll
  for (int ki = 0; ki < 3; ki++){
    int pi = i + ki - 1;
    if (pi < 0 || (pi & 1)) continue;
    int xi = pi >> 1;
    if (xi >= 64) continue;
    #pragma unroll
    for (int kj = 0; kj < 3; kj++){
      int pj = j + kj - 1;
      if (pj < 0 || (pj & 1)) continue;
      int xj = pj >> 1;
      if (xj >= 64) continue;
      acc += w[(2-ki)*3 + (2-kj)] * xp[xi*64 + xj];
    }
  }
  return acc;
}

// ---------------- z1raw = dwconvT(x) as bf16 + bn1 stats (one pass) ----------------
// x plane staged in LDS; coalesced bf16 stores. grid (B*C), block 256.
__global__ __launch_bounds__(256) void dwz1_kernel(const float* __restrict__ x, const float* __restrict__ dw,
    bf16* __restrict__ z1, float* __restrict__ bn1sum, float* __restrict__ bn1sq)
{
  int bc = blockIdx.x; int c = bc & 255;
  int tid = threadIdx.x;
  __shared__ float xs[4096];
  const float* xp = x + (long)bc*4096;
  for (int it = 0; it < 16; it++) xs[it*256 + tid] = xp[it*256 + tid];
  float w[9];
  #pragma unroll
  for (int q = 0; q < 9; q++) w[q] = dw[c*9 + q];
  __syncthreads();
  bf16* zp = z1 + (long)bc*16384;
  float s = 0.f, s2 = 0.f;
  for (int it = 0; it < 64; it++){
    int p = it*256 + tid; int i = p >> 7, j = p & 127;
    float acc = dwconvT_at(xs, w, i, j);
    zp[p] = f2b(acc);
    s += acc; s2 += acc*acc;
  }
  __shared__ float red[512];
  bred2(s, s2, red);
  if (tid == 0){ atomicAdd(&bn1sum[c], s); atomicAdd(&bn1sq[c], s2); }
}

// ---------------- bn finalize: per-channel affine ----------------------------------
__global__ void fin_bn_kernel(const float* __restrict__ sum, const float* __restrict__ sq,
                              const float* __restrict__ g, const float* __restrict__ b,
                              float cnt_inv, float* __restrict__ a, float* __restrict__ d)
{
  int c = threadIdx.x;
  float m = sum[c]*cnt_inv;
  float v = sq[c]*cnt_inv - m*m;
  float aa = g[c] * rsqrtf(vclamp(v));
  a[c] = aa;
  d[c] = b[c] - m*aa;
}

// ---------------- fp32 -> bf16 weight convert --------------------------------------
__global__ void wcvt_kernel(const float* __restrict__ W, bf16* __restrict__ Wb, int n)
{
  int i = blockIdx.x*256 + threadIdx.x;
  if (i < n) Wb[i] = f2b(W[i]);
}

// ---------------- actz1: z1t[b][p][c] = bf16(relu(fa[c]*z1[b,c,p]+fd[c])) ----------
// 64x64 transpose via LDS fp32 tile (bank-clean). grid (256, 4, B), block 256.
__global__ __launch_bounds__(256) void actz1_kernel(const bf16* __restrict__ z1,
    const float* __restrict__ fa, const float* __restrict__ fd, bf16* __restrict__ z1t)
{
  int p0 = blockIdx.x*64, c0 = blockIdx.y*64, b = blockIdx.z;
  int tid = threadIdx.x;
  __shared__ float t[64][65];
  #pragma unroll
  for (int q = 0; q < 2; q++){
    int cl = (tid >> 3) + q*32;
    int p8 = (tid & 7)*8;
    const bf16* src = &z1[((long)(b*C_ + c0 + cl))*16384 + p0 + p8];
    float a = fa[c0 + cl], d = fd[c0 + cl];
    bf16 v[8];
    *(uint4*)v = *(const uint4*)src;
    #pragma unroll
    for (int i = 0; i < 8; i++) t[p8 + i][cl] = fmaxf(b2f(v[i])*a + d, 0.f);
  }
  __syncthreads();
  #pragma unroll
  for (int q = 0; q < 2; q++){
    int pl = (tid >> 3) + q*32;
    int c8 = (tid & 7)*8;
    bf16 v[8];
    #pragma unroll
    for (int i = 0; i < 8; i++) v[i] = f2b(t[pl][c8 + i]);
    *(uint4*)&z1t[((long)b*16384 + p0 + pl)*256 + c0 + c8] = *(const uint4*)v;
  }
}

// ---------------- up-pw GEMM on MFMA: z2[b,o,p] = sum_c Wb[o,c]*z1t[b,p,c] ---------
// Block: M=256 x N=64 x K=256, 4 waves, wave handles 64 M rows; 4x4 16x16 acc tiles.
// A-frag: m=lane&15, k=quad*8+j (Wb row, 16B). B-frag: n=lane&15 (pixel), k=quad*8+j
// (z1t row, 16B). D: col=lane&15, row=quad*4+reg.  grid (256, B), block 256.
__global__ __launch_bounds__(256) void pwz_mfma_kernel(const bf16* __restrict__ z1t,
    const bf16* __restrict__ Wb, bf16* __restrict__ z2)
{
  int b = blockIdx.y;
  int p0 = blockIdx.x*64;
  int tid = threadIdx.x;
  int wave = tid >> 6, lane = tid & 63;
  int quad = lane >> 4, l16 = lane & 15;
  const bf16* zb = z1t + (long)b*16384*256;
  f32x4v acc[4][4];
  #pragma unroll
  for (int i = 0; i < 4; i++)
    #pragma unroll
    for (int j = 0; j < 4; j++) acc[i][j] = (f32x4v){0.f, 0.f, 0.f, 0.f};
  for (int k0 = 0; k0 < 256; k0 += 32){
    int c = k0 + quad*8;
    bf16x8v a[4], bb[4];
    #pragma unroll
    for (int ms = 0; ms < 4; ms++)
      a[ms] = *(const bf16x8v*)&Wb[(wave*64 + ms*16 + l16)*C_ + c];
    #pragma unroll
    for (int ns = 0; ns < 4; ns++)
      bb[ns] = *(const bf16x8v*)&zb[((long)(p0 + ns*16 + l16))*C_ + c];
    #pragma unroll
    for (int ms = 0; ms < 4; ms++)
      #pragma unroll
      for (int ns = 0; ns < 4; ns++)
        acc[ms][ns] = __builtin_amdgcn_mfma_f32_16x16x32_bf16(a[ms], bb[ns], acc[ms][ns], 0, 0, 0);
  }
  #pragma unroll
  for (int ms = 0; ms < 4; ms++){
    int o = wave*64 + ms*16 + quad*4;
    #pragma unroll
    for (int r = 0; r < 4; r++){
      long rowbase = ((long)(b*C_ + o + r))*16384 + p0;
      #pragma unroll
      for (int ns = 0; ns < 4; ns++)
        z2[rowbase + ns*16 + l16] = f2b(acc[ms][ns][r]);
    }
  }
}

// ---------------- per-channel stats of bf16 tensor (B,C,16384) ---------------------
// grid (C, B), block 256
__global__ __launch_bounds__(256) void chstats_kernel(const bf16* __restrict__ t,
                                                      float* __restrict__ sum, float* __restrict__ sq)
{
  int c = blockIdx.x, b = blockIdx.y, tid = threadIdx.x;
  const bf16* p = t + ((long)(b*C_ + c))*16384;
  float s = 0.f, s2 = 0.f;
  for (int it = 0; it < 64; it++){ float v = b2f(p[it*256 + tid]); s += v; s2 += v*v; }
  __shared__ float red[512];
  bred2(s, s2, red);
  if (tid == 0){ atomicAdd(&sum[c], s); atomicAdd(&sq[c], s2); }
}

// ---------------- generic GEMM: C[m,n] = act(sum_k A[m,k] W[n,k] + bias[n]) --------
// A fp32 (lda, batch stride sA), W fp32 (N,K) row-major, batched over grid.z.
// grid ((N+63)/64, (M+63)/64, nbatch), block 256
__global__ __launch_bounds__(256) void gemm_kernel(
  const float* __restrict__ Abase, long sA, int lda,
  const float* __restrict__ W0, const float* __restrict__ W1,
  const float* __restrict__ bias0, const float* __restrict__ bias1, int wsplit,
  float* __restrict__ Cbase, long sC, int ldc,
  int M, int N, int K, int act)
{
  int z = blockIdx.z;
  const float* A = Abase + (long)z*sA;
  float* Cp = Cbase + (long)z*sC;
  const float* W = (z >= wsplit) ? W1 : W0;
  const float* bias = (z >= wsplit) ? bias1 : bias0;
  int m0 = blockIdx.y*64, n0 = blockIdx.x*64;
  __shared__ __align__(16) float As[16][68];
  __shared__ __align__(16) float Ws[16][68];
  int tid = threadIdx.x, tx = tid & 15, ty = tid >> 4;
  float acc[4][4] = {};
  for (int k0 = 0; k0 < K; k0 += 16){
    #pragma unroll
    for (int q = 0; q < 4; q++){
      int e = tid + q*256; int r = e >> 4, kk = e & 15;
      int mi = m0 + r, ki = k0 + kk;
      As[kk][r] = (mi < M && ki < K) ? A[(long)mi*lda + ki] : 0.f;
    }
    #pragma unroll
    for (int q = 0; q < 4; q++){
      int e = tid + q*256; int n = e >> 4, kk = e & 15;
      int ni = n0 + n, ki = k0 + kk;
      Ws[kk][n] = (ni < N && ki < K) ? W[(long)ni*K + ki] : 0.f;
    }
    __syncthreads();
    #pragma unroll
    for (int kk = 0; kk < 16; kk++){
      float4 a4 = *(const float4*)&As[kk][ty*4];
      float4 b4 = *(const float4*)&Ws[kk][tx*4];
      float av[4] = {a4.x, a4.y, a4.z, a4.w};
      float bv[4] = {b4.x, b4.y, b4.z, b4.w};
      #pragma unroll
      for (int mm = 0; mm < 4; mm++)
        #pragma unroll
        for (int nn = 0; nn < 4; nn++) acc[mm][nn] += av[mm]*bv[nn];
    }
    __syncthreads();
  }
  #pragma unroll
  for (int mm = 0; mm < 4; mm++){
    int mi = m0 + ty*4 + mm;
    if (mi >= M) continue;
    #pragma unroll
    for (int nn = 0; nn < 4; nn++){
      int ni = n0 + tx*4 + nn;
      if (ni >= N) continue;
      float v = acc[mm][nn];
      if (bias) v += bias[ni];
      if (act == 2) v = softplusf(v);
      Cp[(long)mi*ldc + ni] = v;
    }
  }
}

// ---------------- depthwise causal conv1d (k=4) + silu -----------------------------
// grid (L, B, 4), block 512
__global__ __launch_bounds__(512) void conv1d_kernel(const float* __restrict__ xzb,
    const float* __restrict__ fw, const float* __restrict__ fb,
    const float* __restrict__ bw, const float* __restrict__ bb,
    float* __restrict__ ub)
{
  int l = blockIdx.x, b = blockIdx.y, v = blockIdx.z, d = threadIdx.x;
  const float* xm = xzb + (long)v*1024*1024;
  const float* w  = (v < 2) ? fw : bw;
  const float* cb = (v < 2) ? fb : bb;
  float acc = cb[d];
  #pragma unroll
  for (int k = 0; k < 4; k++){
    int ll = l - 3 + k;
    if (ll >= 0) acc += xm[(long)(b*L_ + ll)*1024 + d] * w[d*4 + k];
  }
  ub[(long)v*1024*512 + (long)(b*L_ + l)*512 + d] = siluf(acc);
}

// ---------------- selective scan ---------------------------------------------------
// grid (2, B, 4), block 256 : thread = one (b,d)
__global__ __launch_bounds__(256) void scan_kernel(const float* __restrict__ dtb, const float* __restrict__ ub,
    const float* __restrict__ dblb, const float* __restrict__ xzb,
    const float* __restrict__ fAlog, const float* __restrict__ fD,
    const float* __restrict__ bAlog, const float* __restrict__ bD,
    float* __restrict__ yb)
{
  int v = blockIdx.z, b = blockIdx.y;
  int d = blockIdx.x*256 + threadIdx.x;
  const float* dt  = dtb  + (long)v*1024*512;
  const float* u   = ub   + (long)v*1024*512;
  const float* dbl = dblb + (long)v*1024*48;
  const float* zg  = xzb  + (long)v*1024*1024 + 512;
  const float* Alog = (v < 2) ? fAlog : bAlog;
  const float* Dp   = (v < 2) ? fD : bD;
  float a[16];
  #pragma unroll
  for (int n = 0; n < 16; n++) a[n] = -expf(Alog[d*16 + n]);
  float Dv = Dp[d];
  float h[16];
  #pragma unroll
  for (int n = 0; n < 16; n++) h[n] = 0.f;
  __shared__ float bc[2][32];
  float* yo = yb + (long)v*1024*512;
  for (int l = 0; l < L_; l++){
    int row = b*L_ + l;
    if (threadIdx.x < 32) bc[l & 1][threadIdx.x] = dbl[row*48 + 16 + threadIdx.x];
    __syncthreads();
    float dtv = dt[(long)row*512 + d];
    float uv  = u [(long)row*512 + d];
    float zgv = zg[(long)row*1024 + d];
    float dtu = dtv*uv;
    float acc = 0.f;
    const float* Bm = bc[l & 1];
    #pragma unroll
    for (int n = 0; n < 16; n++){
      float dA = expf(dtv*a[n]);
      h[n] = dA*h[n] + dtu*Bm[n];
      acc += h[n]*Bm[16 + n];
    }
    float yv = acc + Dv*uv;
    yo[(long)row*512 + d] = yv * siluf(zgv);
  }
}

// ---------------- LayerNorm over C, two output modes -------------------------------
// grid (128, B, NV), block 256
__global__ __launch_bounds__(256) void ln_kernel(const float* __restrict__ inb, float* __restrict__ out0,
    float* __restrict__ out1, const float* __restrict__ lnw, const float* __restrict__ lnb, int mode)
{
  int r = blockIdx.x, b = blockIdx.y, v = blockIdx.z, c = threadIdx.x;
  long row = (long)b*L_ + r;
  float val = inb[((long)v*1024 + row)*C_ + c];
  __shared__ float red[512];
  float s = val, s2 = val*val;
  bred2(s, s2, red);
  float m = s*(1.f/256.f), var = s2*(1.f/256.f) - m*m;
  float o = (val - m)*rsqrtf(vclamp(var))*lnw[c] + lnb[c];
  if (mode == 1){
    long frow = (long)b*L_ + (127 - r);
    if (v == 0)      out0[row*512 + c] = o;
    else if (v == 1) out1[row*512 + c] = o;
    else if (v == 2) out0[frow*512 + 256 + c] = o;
    else             out1[frow*512 + 256 + c] = o;
  } else {
    out0[((long)v*1024 + row)*C_ + c] = o;
  }
}

// ---------------- hsig(rm+rn)*clip(bn2(z2)) + gn stats; resq IN-PLACE in z2 --------
// Race-free: group g reads p in [g*1024,(g+1)*1024); after a barrier it writes
// q in [g*256,(g+1)*256) — every write index < every future read index.
// grid (C, B), block 256
__global__ __launch_bounds__(256) void hsig_kernel(bf16* __restrict__ z2, const float* __restrict__ rm,
    const float* __restrict__ rn, const float* __restrict__ a2, const float* __restrict__ d2,
    float* __restrict__ gnsum, float* __restrict__ gnsq)
{
  int c = blockIdx.x, b = blockIdx.y, tid = threadIdx.x;
  __shared__ float rms[128], rns[128];
  if (tid < 128){
    rms[tid] = rm[(long)(b*L_ + tid)*C_ + c];
    rns[tid] = rn[(long)(b*L_ + tid)*C_ + c];
  }
  __syncthreads();
  float aa = a2[c], dd = d2[c];
  bf16* zp = z2 + ((long)(b*C_ + c))*16384;
  float s = 0.f, s2 = 0.f;
  for (int g = 0; g < 16; g++){
    float tv[4]; int wq[4];
    #pragma unroll
    for (int q = 0; q < 4; q++){
      int p = g*1024 + q*256 + tid; int i = p >> 7, j = p & 127;
      float zv = b2f(zp[p])*aa + dd;
      zv = fminf(fmaxf(zv, 0.f), 6.f);
      float gate = rms[i] + rns[j];
      gate = fminf(fmaxf(gate + 3.f, 0.f), 6.f) * (1.f/6.f);
      float t = gate*zv;
      s += t; s2 += t*t;
      tv[q] = t;
      wq[q] = (((i | j) & 1) == 0) ? ((i >> 1)*64 + (j >> 1)) : -1;
    }
    __syncthreads();
    #pragma unroll
    for (int q = 0; q < 4; q++)
      if (wq[q] >= 0) zp[wq[q]] = f2b(tv[q]);
  }
  __shared__ float red[512];
  bred2(s, s2, red);
  if (tid == 0){ atomicAdd(&gnsum[b*32 + (c >> 3)], s); atomicAdd(&gnsq[b*32 + (c >> 3)], s2); }
}

// ---------------- gn finalize to per-(b,c) affine ----------------------------------
// grid (B), block 256
__global__ void fin_gn_kernel(const float* __restrict__ gnsum, const float* __restrict__ gnsq,
                              const float* __restrict__ g, const float* __restrict__ bb,
                              float* __restrict__ gnA, float* __restrict__ gnD)
{
  int b = blockIdx.x, c = threadIdx.x, gr = c >> 3;
  float inv_cnt = 1.f/131072.f;
  float m = gnsum[b*32 + gr]*inv_cnt;
  float v = gnsq[b*32 + gr]*inv_cnt - m*m;
  float inv = rsqrtf(vclamp(v));
  float A = inv*g[c];
  gnA[b*C_ + c] = A;
  gnD[b*C_ + c] = bb[c] - m*A;
}

// ---------------- down-pw GEMM: d[b,o,s] = sum_c W[o,c]*(resq[b,c,s]*gnA+gnD) ------
// resq rows strided 16384 (in-place inside z2); out fp32 (d_out), stride 4096.
// grid (64, 4, B), block 256
__global__ __launch_bounds__(256) void pwdown_gemm_kernel(const bf16* __restrict__ in,
    const float* __restrict__ W, const float* __restrict__ fa, const float* __restrict__ fd,
    float* __restrict__ out)
{
  int b = blockIdx.z;
  int n0 = blockIdx.x*64, m0 = blockIdx.y*64;
  __shared__ __align__(16) float As[16][68];
  __shared__ __align__(16) float Bs[16][68];
  int tid = threadIdx.x, tx = tid & 15, ty = tid >> 4;
  float acc[4][4] = {};
  for (int c0 = 0; c0 < C_; c0 += 16){
    #pragma unroll
    for (int q = 0; q < 4; q++){
      int e = tid + q*256; int mm = e >> 4, kk = e & 15;
      As[kk][mm] = W[(m0 + mm)*C_ + c0 + kk];
    }
    #pragma unroll
    for (int q = 0; q < 4; q++){
      int e = tid + q*256; int kk = e >> 6, nn = e & 63;
      int c = c0 + kk;
      int ai = b*C_ + c;
      float v = b2f(in[((long)(b*C_ + c))*16384 + n0 + nn]);
      Bs[kk][nn] = v*fa[ai] + fd[ai];
    }
    __syncthreads();
    #pragma unroll
    for (int kk = 0; kk < 16; kk++){
      float4 a4 = *(const float4*)&As[kk][ty*4];
      float4 b4 = *(const float4*)&Bs[kk][tx*4];
      float av[4] = {a4.x, a4.y, a4.z, a4.w};
      float bv[4] = {b4.x, b4.y, b4.z, b4.w};
      #pragma unroll
      for (int mm = 0; mm < 4; mm++)
        #pragma unroll
        for (int nn = 0; nn < 4; nn++) acc[mm][nn] += av[mm]*bv[nn];
    }
    __syncthreads();
  }
  #pragma unroll
  for (int mm = 0; mm < 4; mm++){
    int o = m0 + ty*4 + mm;
    #pragma unroll
    for (int nn = 0; nn < 4; nn++)
      out[((long)(b*C_ + o))*4096 + n0 + tx*4 + nn] = acc[mm][nn];
  }
}

// ---------------- 5 moments per (b,c): sum d, d^2, x, x^2, dx ----------------------
// grid (C, B), block 256
__global__ __launch_bounds__(256) void stat5_kernel(const float* __restrict__ dbuf, const float* __restrict__ x,
                                                    float* __restrict__ s5)
{
  int c = blockIdx.x, b = blockIdx.y, tid = threadIdx.x;
  const float* dp = dbuf + ((long)(b*C_ + c))*4096;
  const float* xp = x + ((long)(b*C_ + c))*4096;
  float sd = 0, sd2 = 0, sx = 0, sx2 = 0, sdx = 0;
  for (int it = 0; it < 16; it++){
    float d = dp[it*256 + tid];
    float xv = xp[it*256 + tid];
    sd += d; sd2 += d*d; sx += xv; sx2 += xv*xv; sdx += d*xv;
  }
  __shared__ float red[256];
  float r0 = bred1(sd, red); float r1 = bred1(sd2, red); float r2 = bred1(sx, red);
  float r3 = bred1(sx2, red); float r4 = bred1(sdx, red);
  if (tid == 0){
    float* o = s5 + (long)(b*C_ + c)*5;
    o[0] = r0; o[1] = r1; o[2] = r2; o[3] = r3; o[4] = r4;
  }
}

// ---------------- collapse bn -> gn -> (+x) -> gn into out = P*d + Q*x + R ---------
// grid (B), block 256
__global__ void coeff_kernel(const float* __restrict__ s5, const float* __restrict__ dbn_g, const float* __restrict__ dbn_b,
                             const float* __restrict__ gn_g, const float* __restrict__ gn_b, float* __restrict__ pqr)
{
  int b = blockIdx.x, c = threadIdx.x, g = c >> 3;
  float sd = 0, sd2 = 0;
  for (int bb = 0; bb < 8; bb++){ sd += s5[(long)(bb*C_ + c)*5 + 0]; sd2 += s5[(long)(bb*C_ + c)*5 + 1]; }
  float inv_cnt = 1.f/32768.f;
  float mB = sd*inv_cnt;
  float vB = sd2*inv_cnt - mB*mB;
  float ab = dbn_g[c] * rsqrtf(vclamp(vB));
  float db = dbn_b[c] - mB*ab;
  const float* s = s5 + (long)(b*C_ + c)*5;
  float inv_n = 1.f/4096.f;
  float m = s[0]*inv_n, Ed2 = s[1]*inv_n, mx = s[2]*inv_n, Ex2 = s[3]*inv_n, Edx = s[4]*inv_n;
  float Ev = ab*m + db;
  float Ev2 = ab*ab*Ed2 + 2.f*ab*db*m + db*db;
  __shared__ float e1[256], e2[256];
  e1[c] = Ev; e2[c] = Ev2;
  __syncthreads();
  float m1 = 0, q1 = 0;
  for (int k = 0; k < 8; k++){ m1 += e1[(g << 3) + k]; q1 += e2[(g << 3) + k]; }
  m1 *= 0.125f; q1 *= 0.125f;
  float inv1 = rsqrtf(vclamp(q1 - m1*m1));
  float gg = gn_g[c];
  float A1 = inv1*gg;
  float D1 = gn_b[c] - m1*A1;
  float al = A1*ab;
  float be = A1*db + D1;
  float Et = al*m + be + mx;
  float Et2 = al*al*Ed2 + 2.f*al*be*m + be*be + 2.f*al*Edx + 2.f*be*mx + Ex2;
  __syncthreads();
  e1[c] = Et; e2[c] = Et2;
  __syncthreads();
  float m2 = 0, q2 = 0;
  for (int k = 0; k < 8; k++){ m2 += e1[(g << 3) + k]; q2 += e2[(g << 3) + k]; }
  m2 *= 0.125f; q2 *= 0.125f;
  float inv2 = rsqrtf(vclamp(q2 - m2*m2));
  float G = inv2*gg;
  float* o = pqr + (long)(b*C_ + c)*3;
  o[0] = G*al;
  o[1] = G;
  o[2] = G*(be - m2) + gn_b[c];
}

// ---------------- final elementwise: out = P*out + Q*x + R (in-place on d_out) -----
// grid (C, B), block 256
__global__ __launch_bounds__(256) void final_kernel(const float* __restrict__ x,
    const float* __restrict__ pqr, float* __restrict__ out)
{
  int c = blockIdx.x, b = blockIdx.y, tid = threadIdx.x;
  const float* o = pqr + (long)(b*C_ + c)*3;
  float P = o[0], Q = o[1], R = o[2];
  long base = ((long)(b*C_ + c))*4096;
  for (int it = 0; it < 16; it++){
    long idx = base + it*256 + tid;
    out[idx] = P*out[idx] + Q*x[idx] + R;
  }
}

extern "C" void kernel_launch(void* const* d_in, const int* in_sizes, int n_in,
                              void* d_out, int out_size, void* d_ws, size_t ws_size,
                              hipStream_t stream)
{
  (void)in_sizes; (void)n_in; (void)out_size; (void)ws_size;
  // ALL inputs/outputs are float32.
  const float* x         = (const float*)d_in[0];
  const float* pos       = (const float*)d_in[1];
  const float* ln_w      = (const float*)d_in[2];
  const float* ln_b      = (const float*)d_in[3];
  const float* proj_w    = (const float*)d_in[4];
  const float* proj_b    = (const float*)d_in[5];
  const float* up_dw_w   = (const float*)d_in[6];
  const float* up_bn1_g  = (const float*)d_in[7];
  const float* up_bn1_b  = (const float*)d_in[8];
  const float* up_pw_w   = (const float*)d_in[9];
  const float* up_bn2_g  = (const float*)d_in[10];
  const float* up_bn2_b  = (const float*)d_in[11];
  const float* down_pw_w = (const float*)d_in[12];
  const float* down_bn_g = (const float*)d_in[13];
  const float* down_bn_b = (const float*)d_in[14];
  const float* gn_g      = (const float*)d_in[15];
  const float* gn_b      = (const float*)d_in[16];
  const float* f_in_w    = (const float*)d_in[17];
  const float* f_conv_w  = (const float*)d_in[18];
  const float* f_conv_b  = (const float*)d_in[19];
  const float* f_xproj_w = (const float*)d_in[20];
  const float* f_dt_w    = (const float*)d_in[21];
  const float* f_dt_b    = (const float*)d_in[22];
  const float* f_Alog    = (const float*)d_in[23];
  const float* f_D       = (const float*)d_in[24];
  const float* f_out_w   = (const float*)d_in[25];
  const float* b_in_w    = (const float*)d_in[26];
  const float* b_conv_w  = (const float*)d_in[27];
  const float* b_conv_b  = (const float*)d_in[28];
  const float* b_xproj_w = (const float*)d_in[29];
  const float* b_dt_w    = (const float*)d_in[30];
  const float* b_dt_b    = (const float*)d_in[31];
  const float* b_Alog    = (const float*)d_in[32];
  const float* b_D       = (const float*)d_in[33];
  const float* b_out_w   = (const float*)d_in[34];

  // ======== workspace layout, PEAK = 132MB ========
  // [0, 4MB): small stats + rmrn + Wb (live across phases)
  // [4MB, 68MB) "big": phase 1 mamba intermediates; phase 2a z1 (c-major, bf16);
  //                    phase 2b+3: z2 (bf16; z1 dead after actz1; resq in-place)
  // [68MB, 132MB): z1t (p-major bf16, phase 2 only)
  // dbuf (fp32 32MB) lives in d_out; final updates d_out in-place.
  char* sb = (char*)d_ws;
  float* statz = (float*)(sb);               // 1536 f (zeroed each launch)
  float* abn   = (float*)(sb + 8192);        // 1024 f
  float* gnAD  = (float*)(sb + 16384);       // 4096 f
  float* stat5 = (float*)(sb + 65536);       // 10240 f
  float* pqr   = (float*)(sb + 131072);      // 6144 f
  float* rmrn  = (float*)(sb + 1*MB);        // 2MB: 2 x (1024,256)
  bf16*  Wbbuf = (bf16*)(sb + 3*MB);         // 128KB: up_pw_w in bf16
  char* big = sb + 4*MB;
  float* pool4  = (float*)(big + 0*MB);      // 2 MB
  float* hbuf   = (float*)(big + 2*MB);      // 4 MB
  float* xzbuf  = (float*)(big + 6*MB);      // 16 MB
  float* ubuf   = (float*)(big + 22*MB);     // 8 MB
  float* dblbuf = (float*)(big + 30*MB);     // 768 KB
  float* dtbuf  = (float*)(big + 31*MB);     // 8 MB
  float* ybuf   = (float*)(big + 39*MB);     // 8 MB
  float* mout   = (float*)(big + 47*MB);     // 4 MB
  float* cbuf   = (float*)(big + 51*MB);     // 4 MB
  float* respre = (float*)(big + 55*MB);     // 2 MB  (ends at 57MB < 64MB)
  bf16*  z1buf  = (bf16*)(big);              // 64 MiB bf16, c-major (phase 2a)
  bf16*  z2buf  = (bf16*)(big);              // 64 MiB bf16 (phase 2b/3; z1 dead)
  bf16*  z1tbuf = (bf16*)(sb + 68*MB);       // 64 MiB bf16, p-major
  float* dbuf   = (float*)d_out;             // 32 MB fp32 (phase 3)

  float* bn1sum = statz;        float* bn1sq = statz + 256;
  float* bn2sum = statz + 512;  float* bn2sq = statz + 768;
  float* gnsum  = statz + 1024; float* gnsq  = statz + 1280;
  float* abn1 = abn;       float* dbn1 = abn + 256;
  float* abn2 = abn + 512; float* dbn2 = abn + 768;
  float* gnA = gnAD;       float* gnD = gnAD + 2048;
  float* pcolmax = pool4;
  float* pcolmin = pool4 + 131072;
  float* prowmax = pool4 + 262144;
  float* prowmin = pool4 + 393216;

  hipMemsetAsync(statz, 0, 1536*sizeof(float), stream);

  // ---- phase 1: pooling + LN + mamba x4 (f/b x max/min) -> rmrn ----
  pool1_kernel<<<dim3(256, 8), 64, 0, stream>>>(x, pos, pcolmax, pcolmin, prowmax, prowmin);
  pool2_kernel<<<dim3(128, 8), 256, 0, stream>>>(pcolmax, pcolmin, prowmax, prowmin, ln_w, ln_b, hbuf);
  gemm_kernel<<<dim3(16, 16, 4), 256, 0, stream>>>(hbuf, 262144, 256, f_in_w, b_in_w, nullptr, nullptr, 2,
                                                   xzbuf, 1048576, 1024, 1024, 1024, 256, 0);
  conv1d_kernel<<<dim3(128, 8, 4), 512, 0, stream>>>(xzbuf, f_conv_w, f_conv_b, b_conv_w, b_conv_b, ubuf);
  gemm_kernel<<<dim3(1, 16, 4), 256, 0, stream>>>(ubuf, 524288, 512, f_xproj_w, b_xproj_w, nullptr, nullptr, 2,
                                                  dblbuf, 49152, 48, 1024, 48, 512, 0);
  gemm_kernel<<<dim3(8, 16, 4), 256, 0, stream>>>(dblbuf, 49152, 48, f_dt_w, b_dt_w, f_dt_b, b_dt_b, 2,
                                                  dtbuf, 524288, 512, 1024, 512, 16, 2);
  scan_kernel<<<dim3(2, 8, 4), 256, 0, stream>>>(dtbuf, ubuf, dblbuf, xzbuf, f_Alog, f_D, b_Alog, b_D, ybuf);
  gemm_kernel<<<dim3(4, 16, 4), 256, 0, stream>>>(ybuf, 524288, 512, f_out_w, b_out_w, nullptr, nullptr, 2,
                                                  mout, 262144, 256, 1024, 256, 512, 0);
  ln_kernel<<<dim3(128, 8, 4), 256, 0, stream>>>(mout, cbuf, cbuf + 524288, ln_w, ln_b, 1);
  gemm_kernel<<<dim3(4, 16, 2), 256, 0, stream>>>(cbuf, 524288, 512, proj_w, proj_w, proj_b, proj_b, 2,
                                                  respre, 262144, 256, 1024, 256, 512, 0);
  ln_kernel<<<dim3(128, 8, 2), 256, 0, stream>>>(respre, rmrn, nullptr, ln_w, ln_b, 0);

  // ---- phase 2: z path ----
  dwz1_kernel<<<2048, 256, 0, stream>>>(x, up_dw_w, z1buf, bn1sum, bn1sq);
  fin_bn_kernel<<<1, 256, 0, stream>>>(bn1sum, bn1sq, up_bn1_g, up_bn1_b, 1.f/131072.f, abn1, dbn1);
  wcvt_kernel<<<256, 256, 0, stream>>>(up_pw_w, Wbbuf, 65536);
  actz1_kernel<<<dim3(256, 4, 8), 256, 0, stream>>>(z1buf, abn1, dbn1, z1tbuf);
  pwz_mfma_kernel<<<dim3(256, 8), 256, 0, stream>>>(z1tbuf, Wbbuf, z2buf);
  chstats_kernel<<<dim3(256, 8), 256, 0, stream>>>(z2buf, bn2sum, bn2sq);
  fin_bn_kernel<<<1, 256, 0, stream>>>(bn2sum, bn2sq, up_bn2_g, up_bn2_b, 1.f/131072.f, abn2, dbn2);

  // ---- phase 3: merge + tail ----
  hsig_kernel<<<dim3(256, 8), 256, 0, stream>>>(z2buf, rmrn, rmrn + 262144, abn2, dbn2, gnsum, gnsq);
  fin_gn_kernel<<<8, 256, 0, stream>>>(gnsum, gnsq, gn_g, gn_b, gnA, gnD);
  pwdown_gemm_kernel<<<dim3(64, 4, 8), 256, 0, stream>>>(z2buf, down_pw_w, gnA, gnD, dbuf);
  stat5_kernel<<<dim3(256, 8), 256, 0, stream>>>(dbuf, x, stat5);
  coeff_kernel<<<8, 256, 0, stream>>>(stat5, down_bn_g, down_bn_b, gn_g, gn_b, pqr);
  final_kernel<<<dim3(256, 8), 256, 0, stream>>>(x, pqr, (float*)d_out);
}

// Round 8
// 802.631 us; speedup vs baseline: 2.4353x; 1.0894x over previous
//
#include <hip/hip_runtime.h>
#include <hip/hip_bf16.h>

typedef __hip_bfloat16 bf16;
typedef __attribute__((ext_vector_type(8))) short bf16x8v;
typedef __attribute__((ext_vector_type(4))) float f32x4v;

#define B_ 8
#define C_ 256
#define L_ 128
#define MB 1048576UL

__device__ inline float b2f(bf16 v){ return __bfloat162float(v); }
__device__ inline bf16 f2b(float v){ return __float2bfloat16(v); }
__device__ inline float siluf(float x){ return x / (1.f + expf(-x)); }
__device__ inline float softplusf(float x){ return (x > 20.f) ? x : log1pf(expf(x)); }
__device__ inline float vclamp(float v){ return fmaxf(v, 0.f) + 1e-5f; }

// block = 256 threads. red must hold 512 floats.
__device__ inline void bred2(float& a, float& b, float* red){
  int t = threadIdx.x;
  __syncthreads();
  red[t] = a; red[256 + t] = b;
  __syncthreads();
  for (int off = 128; off > 0; off >>= 1){
    if (t < off){ red[t] += red[t + off]; red[256 + t] += red[256 + t + off]; }
    __syncthreads();
  }
  a = red[0]; b = red[256];
}
__device__ inline float bred1(float a, float* red){
  int t = threadIdx.x;
  __syncthreads();
  red[t] = a; __syncthreads();
  for (int off = 128; off > 0; off >>= 1){
    if (t < off) red[t] += red[t + off];
    __syncthreads();
  }
  return red[0];
}

// ---------------- pooling step 1: row/col max/min + argmax + pos-embed -------------
// grid (C, B), block 64
__global__ __launch_bounds__(64) void pool1_kernel(const float* __restrict__ x, const float* __restrict__ pos,
    float* __restrict__ pcolmax, float* __restrict__ pcolmin,
    float* __restrict__ prowmax, float* __restrict__ prowmin)
{
  int c = blockIdx.x, b = blockIdx.y, t = threadIdx.x;
  __shared__ float xs[64][65];
  const float* xp = x + ((long)(b*C_ + c))*4096;
  for (int i = 0; i < 64; i++) xs[i][t] = xp[i*64 + t];
  __syncthreads();
  // jax.image.resize 'linear' 16->64: half-pixel coords, edge clamp
  float tt = 0.25f*(float)t - 0.375f;
  const float* pp = pos + c*16;
  float pe;
  if (tt <= 0.f) pe = pp[0];
  else if (tt >= 15.f) pe = pp[15];
  else { int f = (int)floorf(tt); float w = tt - (float)f; pe = pp[f]*(1.f - w) + pp[f+1]*w; }
  float vmax = -1e30f, vmin = 1e30f; int amax = 0, amin = 0;
  for (int j = 0; j < 64; j++){
    float v = xs[t][j];
    if (v > vmax){ vmax = v; amax = j; }
    if (v < vmin){ vmin = v; amin = j; }
  }
  long o = (long)(b*64 + t)*C_ + c;
  prowmax[o] = vmax + pe + (float)amax;
  prowmin[o] = vmin + pe + (float)amin;
  vmax = -1e30f; vmin = 1e30f; amax = 0; amin = 0;
  for (int i = 0; i < 64; i++){
    float v = xs[i][t];
    if (v > vmax){ vmax = v; amax = i; }
    if (v < vmin){ vmin = v; amin = i; }
  }
  pcolmax[o] = vmax + pe + (float)amax;
  pcolmin[o] = vmin + pe + (float)amin;
}

// ---------------- pooling step 2: LN over channels, write 4 mamba inputs -----------
// grid (128, B), block 256
__global__ __launch_bounds__(256) void pool2_kernel(const float* __restrict__ pcolmax, const float* __restrict__ pcolmin,
    const float* __restrict__ prowmax, const float* __restrict__ prowmin,
    const float* __restrict__ lnw, const float* __restrict__ lnb, float* __restrict__ hbuf)
{
  int r = blockIdx.x, b = blockIdx.y, c = threadIdx.x;
  __shared__ float red[512];
  int p = r & 63;
  long src = (long)(b*64 + p)*C_ + c;
  float vmax = (r < 64) ? pcolmax[src] : prowmax[src];
  float vmin = (r < 64) ? pcolmin[src] : prowmin[src];
  float gw = lnw[c], gb = lnb[c];
  long row = (long)b*L_ + r, frow = (long)b*L_ + (127 - r);
  float s = vmax, s2 = vmax*vmax;
  bred2(s, s2, red);
  float m = s*(1.f/256.f), var = s2*(1.f/256.f) - m*m;
  float o = (vmax - m)*rsqrtf(vclamp(var))*gw + gb;
  hbuf[0*262144 + row*C_ + c]  = o;
  hbuf[2*262144 + frow*C_ + c] = o;
  s = vmin; s2 = vmin*vmin;
  bred2(s, s2, red);
  m = s*(1.f/256.f); var = s2*(1.f/256.f) - m*m;
  o = (vmin - m)*rsqrtf(vclamp(var))*gw + gb;
  hbuf[1*262144 + row*C_ + c]  = o;
  hbuf[3*262144 + frow*C_ + c] = o;
}

// ---------------- dwconvT on-the-fly helper ----------------------------------------
__device__ inline float dwconvT_at(const float* __restrict__ xp, const float* __restrict__ w, int i, int j)
{
  float acc = 0.f;
  #pragma unroll
  for (int ki = 0; ki < 3; ki++){
    int pi = i + ki - 1;
    if (pi < 0 || (pi & 1)) continue;
    int xi = pi >> 1;
    if (xi >= 64) continue;
    #pragma unroll
    for (int kj = 0; kj < 3; kj++){
      int pj = j + kj - 1;
      if (pj < 0 || (pj & 1)) continue;
      int xj = pj >> 1;
      if (xj >= 64) continue;
      acc += w[(2-ki)*3 + (2-kj)] * xp[xi*64 + xj];
    }
  }
  return acc;
}

// ---------------- z1raw = dwconvT(x) as bf16 + bn1 stats (one pass) ----------------
// x plane staged in LDS; coalesced bf16 stores. grid (B*C), block 256.
__global__ __launch_bounds__(256) void dwz1_kernel(const float* __restrict__ x, const float* __restrict__ dw,
    bf16* __restrict__ z1, float* __restrict__ bn1sum, float* __restrict__ bn1sq)
{
  int bc = blockIdx.x; int c = bc & 255;
  int tid = threadIdx.x;
  __shared__ float xs[4096];
  const float* xp = x + (long)bc*4096;
  for (int it = 0; it < 16; it++) xs[it*256 + tid] = xp[it*256 + tid];
  float w[9];
  #pragma unroll
  for (int q = 0; q < 9; q++) w[q] = dw[c*9 + q];
  __syncthreads();
  bf16* zp = z1 + (long)bc*16384;
  float s = 0.f, s2 = 0.f;
  for (int it = 0; it < 64; it++){
    int p = it*256 + tid; int i = p >> 7, j = p & 127;
    float acc = dwconvT_at(xs, w, i, j);
    zp[p] = f2b(acc);
    s += acc; s2 += acc*acc;
  }
  __shared__ float red[512];
  bred2(s, s2, red);
  if (tid == 0){ atomicAdd(&bn1sum[c], s); atomicAdd(&bn1sq[c], s2); }
}

// ---------------- bn finalize: per-channel affine ----------------------------------
__global__ void fin_bn_kernel(const float* __restrict__ sum, const float* __restrict__ sq,
                              const float* __restrict__ g, const float* __restrict__ b,
                              float cnt_inv, float* __restrict__ a, float* __restrict__ d)
{
  int c = threadIdx.x;
  float m = sum[c]*cnt_inv;
  float v = sq[c]*cnt_inv - m*m;
  float aa = g[c] * rsqrtf(vclamp(v));
  a[c] = aa;
  d[c] = b[c] - m*aa;
}

// ---------------- fp32 -> bf16 weight convert --------------------------------------
__global__ void wcvt_kernel(const float* __restrict__ W, bf16* __restrict__ Wb, int n)
{
  int i = blockIdx.x*256 + threadIdx.x;
  if (i < n) Wb[i] = f2b(W[i]);
}

// ---------------- actz1: z1t[b][p][c] = bf16(relu(fa[c]*z1[b,c,p]+fd[c])) ----------
// 64x64 transpose via LDS fp32 tile (bank-clean). grid (256, 4, B), block 256.
__global__ __launch_bounds__(256) void actz1_kernel(const bf16* __restrict__ z1,
    const float* __restrict__ fa, const float* __restrict__ fd, bf16* __restrict__ z1t)
{
  int p0 = blockIdx.x*64, c0 = blockIdx.y*64, b = blockIdx.z;
  int tid = threadIdx.x;
  __shared__ float t[64][65];
  #pragma unroll
  for (int q = 0; q < 2; q++){
    int cl = (tid >> 3) + q*32;
    int p8 = (tid & 7)*8;
    const bf16* src = &z1[((long)(b*C_ + c0 + cl))*16384 + p0 + p8];
    float a = fa[c0 + cl], d = fd[c0 + cl];
    bf16 v[8];
    *(uint4*)v = *(const uint4*)src;
    #pragma unroll
    for (int i = 0; i < 8; i++) t[p8 + i][cl] = fmaxf(b2f(v[i])*a + d, 0.f);
  }
  __syncthreads();
  #pragma unroll
  for (int q = 0; q < 2; q++){
    int pl = (tid >> 3) + q*32;
    int c8 = (tid & 7)*8;
    bf16 v[8];
    #pragma unroll
    for (int i = 0; i < 8; i++) v[i] = f2b(t[pl][c8 + i]);
    *(uint4*)&z1t[((long)b*16384 + p0 + pl)*256 + c0 + c8] = *(const uint4*)v;
  }
}

// ---------------- up-pw GEMM on MFMA: z2[b,o,p] = sum_c Wb[o,c]*z1t[b,p,c] ---------
// Block: M=256 x N=64 x K=256, 4 waves, wave handles 64 M rows; 4x4 16x16 acc tiles.
// grid (256, B), block 256.
__global__ __launch_bounds__(256) void pwz_mfma_kernel(const bf16* __restrict__ z1t,
    const bf16* __restrict__ Wb, bf16* __restrict__ z2)
{
  int b = blockIdx.y;
  int p0 = blockIdx.x*64;
  int tid = threadIdx.x;
  int wave = tid >> 6, lane = tid & 63;
  int quad = lane >> 4, l16 = lane & 15;
  const bf16* zb = z1t + (long)b*16384*256;
  f32x4v acc[4][4];
  #pragma unroll
  for (int i = 0; i < 4; i++)
    #pragma unroll
    for (int j = 0; j < 4; j++) acc[i][j] = (f32x4v){0.f, 0.f, 0.f, 0.f};
  for (int k0 = 0; k0 < 256; k0 += 32){
    int c = k0 + quad*8;
    bf16x8v a[4], bb[4];
    #pragma unroll
    for (int ms = 0; ms < 4; ms++)
      a[ms] = *(const bf16x8v*)&Wb[(wave*64 + ms*16 + l16)*C_ + c];
    #pragma unroll
    for (int ns = 0; ns < 4; ns++)
      bb[ns] = *(const bf16x8v*)&zb[((long)(p0 + ns*16 + l16))*C_ + c];
    #pragma unroll
    for (int ms = 0; ms < 4; ms++)
      #pragma unroll
      for (int ns = 0; ns < 4; ns++)
        acc[ms][ns] = __builtin_amdgcn_mfma_f32_16x16x32_bf16(a[ms], bb[ns], acc[ms][ns], 0, 0, 0);
  }
  #pragma unroll
  for (int ms = 0; ms < 4; ms++){
    int o = wave*64 + ms*16 + quad*4;
    #pragma unroll
    for (int r = 0; r < 4; r++){
      long rowbase = ((long)(b*C_ + o + r))*16384 + p0;
      #pragma unroll
      for (int ns = 0; ns < 4; ns++)
        z2[rowbase + ns*16 + l16] = f2b(acc[ms][ns][r]);
    }
  }
}

// ---------------- per-channel stats of bf16 tensor (B,C,16384) ---------------------
// grid (C, B), block 256
__global__ __launch_bounds__(256) void chstats_kernel(const bf16* __restrict__ t,
                                                      float* __restrict__ sum, float* __restrict__ sq)
{
  int c = blockIdx.x, b = blockIdx.y, tid = threadIdx.x;
  const bf16* p = t + ((long)(b*C_ + c))*16384;
  float s = 0.f, s2 = 0.f;
  for (int it = 0; it < 64; it++){ float v = b2f(p[it*256 + tid]); s += v; s2 += v*v; }
  __shared__ float red[512];
  bred2(s, s2, red);
  if (tid == 0){ atomicAdd(&sum[c], s); atomicAdd(&sq[c], s2); }
}

// ---------------- generic GEMM: C[m,n] = act(sum_k A[m,k] W[n,k] + bias[n]) --------
// A fp32 (lda, batch stride sA), W fp32 (N,K) row-major, batched over grid.z.
// grid ((N+63)/64, (M+63)/64, nbatch), block 256
__global__ __launch_bounds__(256) void gemm_kernel(
  const float* __restrict__ Abase, long sA, int lda,
  const float* __restrict__ W0, const float* __restrict__ W1,
  const float* __restrict__ bias0, const float* __restrict__ bias1, int wsplit,
  float* __restrict__ Cbase, long sC, int ldc,
  int M, int N, int K, int act)
{
  int z = blockIdx.z;
  const float* A = Abase + (long)z*sA;
  float* Cp = Cbase + (long)z*sC;
  const float* W = (z >= wsplit) ? W1 : W0;
  const float* bias = (z >= wsplit) ? bias1 : bias0;
  int m0 = blockIdx.y*64, n0 = blockIdx.x*64;
  __shared__ __align__(16) float As[16][68];
  __shared__ __align__(16) float Ws[16][68];
  int tid = threadIdx.x, tx = tid & 15, ty = tid >> 4;
  float acc[4][4] = {};
  for (int k0 = 0; k0 < K; k0 += 16){
    #pragma unroll
    for (int q = 0; q < 4; q++){
      int e = tid + q*256; int r = e >> 4, kk = e & 15;
      int mi = m0 + r, ki = k0 + kk;
      As[kk][r] = (mi < M && ki < K) ? A[(long)mi*lda + ki] : 0.f;
    }
    #pragma unroll
    for (int q = 0; q < 4; q++){
      int e = tid + q*256; int n = e >> 4, kk = e & 15;
      int ni = n0 + n, ki = k0 + kk;
      Ws[kk][n] = (ni < N && ki < K) ? W[(long)ni*K + ki] : 0.f;
    }
    __syncthreads();
    #pragma unroll
    for (int kk = 0; kk < 16; kk++){
      float4 a4 = *(const float4*)&As[kk][ty*4];
      float4 b4 = *(const float4*)&Ws[kk][tx*4];
      float av[4] = {a4.x, a4.y, a4.z, a4.w};
      float bv[4] = {b4.x, b4.y, b4.z, b4.w};
      #pragma unroll
      for (int mm = 0; mm < 4; mm++)
        #pragma unroll
        for (int nn = 0; nn < 4; nn++) acc[mm][nn] += av[mm]*bv[nn];
    }
    __syncthreads();
  }
  #pragma unroll
  for (int mm = 0; mm < 4; mm++){
    int mi = m0 + ty*4 + mm;
    if (mi >= M) continue;
    #pragma unroll
    for (int nn = 0; nn < 4; nn++){
      int ni = n0 + tx*4 + nn;
      if (ni >= N) continue;
      float v = acc[mm][nn];
      if (bias) v += bias[ni];
      if (act == 2) v = softplusf(v);
      Cp[(long)mi*ldc + ni] = v;
    }
  }
}

// ---------------- depthwise causal conv1d (k=4) + silu -----------------------------
// grid (L, B, 4), block 512
__global__ __launch_bounds__(512) void conv1d_kernel(const float* __restrict__ xzb,
    const float* __restrict__ fw, const float* __restrict__ fb,
    const float* __restrict__ bw, const float* __restrict__ bb,
    float* __restrict__ ub)
{
  int l = blockIdx.x, b = blockIdx.y, v = blockIdx.z, d = threadIdx.x;
  const float* xm = xzb + (long)v*1024*1024;
  const float* w  = (v < 2) ? fw : bw;
  const float* cb = (v < 2) ? fb : bb;
  float acc = cb[d];
  #pragma unroll
  for (int k = 0; k < 4; k++){
    int ll = l - 3 + k;
    if (ll >= 0) acc += xm[(long)(b*L_ + ll)*1024 + d] * w[d*4 + k];
  }
  ub[(long)v*1024*512 + (long)(b*L_ + l)*512 + d] = siluf(acc);
}

// ---------------- selective scan (latency-optimized) -------------------------------
// One wave per block, 256 blocks (full chip). B/C preloaded to LDS once (no in-loop
// barrier); dt/u/zg software-pipelined one step ahead to hide global-load latency.
// grid (8, B, 4), block 64 : thread = one (b,d), d = bx*64 + lane
__global__ __launch_bounds__(64) void scan_kernel(const float* __restrict__ dtb, const float* __restrict__ ub,
    const float* __restrict__ dblb, const float* __restrict__ xzb,
    const float* __restrict__ fAlog, const float* __restrict__ fD,
    const float* __restrict__ bAlog, const float* __restrict__ bD,
    float* __restrict__ yb)
{
  int v = blockIdx.z, b = blockIdx.y;
  int d = blockIdx.x*64 + threadIdx.x;
  const float* dt  = dtb  + (long)v*1024*512;
  const float* u   = ub   + (long)v*1024*512;
  const float* dbl = dblb + (long)v*1024*48;
  const float* zg  = xzb  + (long)v*1024*1024 + 512;
  const float* Alog = (v < 2) ? fAlog : bAlog;
  const float* Dp   = (v < 2) ? fD : bD;
  __shared__ float bcs[128][32];      // [l][0..15]=B, [16..31]=C — wave-broadcast reads
  for (int idx = threadIdx.x; idx < 4096; idx += 64){
    int l = idx >> 5, i = idx & 31;
    bcs[l][i] = dbl[(long)(b*L_ + l)*48 + 16 + i];
  }
  float a[16];
  #pragma unroll
  for (int n = 0; n < 16; n++) a[n] = -expf(Alog[d*16 + n]);
  float Dv = Dp[d];
  float h[16];
  #pragma unroll
  for (int n = 0; n < 16; n++) h[n] = 0.f;
  __syncthreads();
  long row = (long)b*L_;
  float* yo = yb + (long)v*1024*512;
  float dtv = dt[row*512 + d];
  float uv  = u [row*512 + d];
  float zgv = zg[row*1024 + d];
  for (int l = 0; l < L_; l++){
    float dtn = 0.f, un = 0.f, zgn = 0.f;
    if (l < L_ - 1){
      long r2 = row + l + 1;
      dtn = dt[r2*512 + d];
      un  = u [r2*512 + d];
      zgn = zg[r2*1024 + d];
    }
    float dtu = dtv*uv;
    float acc = 0.f;
    const float* Bm = bcs[l];
    #pragma unroll
    for (int n = 0; n < 16; n++){
      float dA = expf(dtv*a[n]);
      h[n] = dA*h[n] + dtu*Bm[n];
      acc += h[n]*Bm[16 + n];
    }
    yo[(row + l)*512 + d] = (acc + Dv*uv) * siluf(zgv);
    dtv = dtn; uv = un; zgv = zgn;
  }
}

// ---------------- LayerNorm over C, two output modes -------------------------------
// grid (128, B, NV), block 256
__global__ __launch_bounds__(256) void ln_kernel(const float* __restrict__ inb, float* __restrict__ out0,
    float* __restrict__ out1, const float* __restrict__ lnw, const float* __restrict__ lnb, int mode)
{
  int r = blockIdx.x, b = blockIdx.y, v = blockIdx.z, c = threadIdx.x;
  long row = (long)b*L_ + r;
  float val = inb[((long)v*1024 + row)*C_ + c];
  __shared__ float red[512];
  float s = val, s2 = val*val;
  bred2(s, s2, red);
  float m = s*(1.f/256.f), var = s2*(1.f/256.f) - m*m;
  float o = (val - m)*rsqrtf(vclamp(var))*lnw[c] + lnb[c];
  if (mode == 1){
    long frow = (long)b*L_ + (127 - r);
    if (v == 0)      out0[row*512 + c] = o;
    else if (v == 1) out1[row*512 + c] = o;
    else if (v == 2) out0[frow*512 + 256 + c] = o;
    else             out1[frow*512 + 256 + c] = o;
  } else {
    out0[((long)v*1024 + row)*C_ + c] = o;
  }
}

// ---------------- hsig(rm+rn)*clip(bn2(z2)) + gn stats; resq IN-PLACE in z2 --------
// grid (C, B), block 256
__global__ __launch_bounds__(256) void hsig_kernel(bf16* __restrict__ z2, const float* __restrict__ rm,
    const float* __restrict__ rn, const float* __restrict__ a2, const float* __restrict__ d2,
    float* __restrict__ gnsum, float* __restrict__ gnsq)
{
  int c = blockIdx.x, b = blockIdx.y, tid = threadIdx.x;
  __shared__ float rms[128], rns[128];
  if (tid < 128){
    rms[tid] = rm[(long)(b*L_ + tid)*C_ + c];
    rns[tid] = rn[(long)(b*L_ + tid)*C_ + c];
  }
  __syncthreads();
  float aa = a2[c], dd = d2[c];
  bf16* zp = z2 + ((long)(b*C_ + c))*16384;
  float s = 0.f, s2 = 0.f;
  for (int g = 0; g < 16; g++){
    float tv[4]; int wq[4];
    #pragma unroll
    for (int q = 0; q < 4; q++){
      int p = g*1024 + q*256 + tid; int i = p >> 7, j = p & 127;
      float zv = b2f(zp[p])*aa + dd;
      zv = fminf(fmaxf(zv, 0.f), 6.f);
      float gate = rms[i] + rns[j];
      gate = fminf(fmaxf(gate + 3.f, 0.f), 6.f) * (1.f/6.f);
      float t = gate*zv;
      s += t; s2 += t*t;
      tv[q] = t;
      wq[q] = (((i | j) & 1) == 0) ? ((i >> 1)*64 + (j >> 1)) : -1;
    }
    __syncthreads();
    #pragma unroll
    for (int q = 0; q < 4; q++)
      if (wq[q] >= 0) zp[wq[q]] = f2b(tv[q]);
  }
  __shared__ float red[512];
  bred2(s, s2, red);
  if (tid == 0){ atomicAdd(&gnsum[b*32 + (c >> 3)], s); atomicAdd(&gnsq[b*32 + (c >> 3)], s2); }
}

// ---------------- gn finalize to per-(b,c) affine ----------------------------------
// grid (B), block 256
__global__ void fin_gn_kernel(const float* __restrict__ gnsum, const float* __restrict__ gnsq,
                              const float* __restrict__ g, const float* __restrict__ bb,
                              float* __restrict__ gnA, float* __restrict__ gnD)
{
  int b = blockIdx.x, c = threadIdx.x, gr = c >> 3;
  float inv_cnt = 1.f/131072.f;
  float m = gnsum[b*32 + gr]*inv_cnt;
  float v = gnsq[b*32 + gr]*inv_cnt - m*m;
  float inv = rsqrtf(vclamp(v));
  float A = inv*g[c];
  gnA[b*C_ + c] = A;
  gnD[b*C_ + c] = bb[c] - m*A;
}

// ---------------- down-pw GEMM: d[b,o,s] = sum_c W[o,c]*(resq[b,c,s]*gnA+gnD) ------
// resq rows strided 16384 (in-place inside z2); out fp32 (d_out), stride 4096.
// grid (64, 4, B), block 256
__global__ __launch_bounds__(256) void pwdown_gemm_kernel(const bf16* __restrict__ in,
    const float* __restrict__ W, const float* __restrict__ fa, const float* __restrict__ fd,
    float* __restrict__ out)
{
  int b = blockIdx.z;
  int n0 = blockIdx.x*64, m0 = blockIdx.y*64;
  __shared__ __align__(16) float As[16][68];
  __shared__ __align__(16) float Bs[16][68];
  int tid = threadIdx.x, tx = tid & 15, ty = tid >> 4;
  float acc[4][4] = {};
  for (int c0 = 0; c0 < C_; c0 += 16){
    #pragma unroll
    for (int q = 0; q < 4; q++){
      int e = tid + q*256; int mm = e >> 4, kk = e & 15;
      As[kk][mm] = W[(m0 + mm)*C_ + c0 + kk];
    }
    #pragma unroll
    for (int q = 0; q < 4; q++){
      int e = tid + q*256; int kk = e >> 6, nn = e & 63;
      int c = c0 + kk;
      int ai = b*C_ + c;
      float v = b2f(in[((long)(b*C_ + c))*16384 + n0 + nn]);
      Bs[kk][nn] = v*fa[ai] + fd[ai];
    }
    __syncthreads();
    #pragma unroll
    for (int kk = 0; kk < 16; kk++){
      float4 a4 = *(const float4*)&As[kk][ty*4];
      float4 b4 = *(const float4*)&Bs[kk][tx*4];
      float av[4] = {a4.x, a4.y, a4.z, a4.w};
      float bv[4] = {b4.x, b4.y, b4.z, b4.w};
      #pragma unroll
      for (int mm = 0; mm < 4; mm++)
        #pragma unroll
        for (int nn = 0; nn < 4; nn++) acc[mm][nn] += av[mm]*bv[nn];
    }
    __syncthreads();
  }
  #pragma unroll
  for (int mm = 0; mm < 4; mm++){
    int o = m0 + ty*4 + mm;
    #pragma unroll
    for (int nn = 0; nn < 4; nn++)
      out[((long)(b*C_ + o))*4096 + n0 + tx*4 + nn] = acc[mm][nn];
  }
}

// ---------------- 5 moments per (b,c): sum d, d^2, x, x^2, dx ----------------------
// grid (C, B), block 256
__global__ __launch_bounds__(256) void stat5_kernel(const float* __restrict__ dbuf, const float* __restrict__ x,
                                                    float* __restrict__ s5)
{
  int c = blockIdx.x, b = blockIdx.y, tid = threadIdx.x;
  const float* dp = dbuf + ((long)(b*C_ + c))*4096;
  const float* xp = x + ((long)(b*C_ + c))*4096;
  float sd = 0, sd2 = 0, sx = 0, sx2 = 0, sdx = 0;
  for (int it = 0; it < 16; it++){
    float d = dp[it*256 + tid];
    float xv = xp[it*256 + tid];
    sd += d; sd2 += d*d; sx += xv; sx2 += xv*xv; sdx += d*xv;
  }
  __shared__ float red[256];
  float r0 = bred1(sd, red); float r1 = bred1(sd2, red); float r2 = bred1(sx, red);
  float r3 = bred1(sx2, red); float r4 = bred1(sdx, red);
  if (tid == 0){
    float* o = s5 + (long)(b*C_ + c)*5;
    o[0] = r0; o[1] = r1; o[2] = r2; o[3] = r3; o[4] = r4;
  }
}

// ---------------- collapse bn -> gn -> (+x) -> gn into out = P*d + Q*x + R ---------
// grid (B), block 256
__global__ void coeff_kernel(const float* __restrict__ s5, const float* __restrict__ dbn_g, const float* __restrict__ dbn_b,
                             const float* __restrict__ gn_g, const float* __restrict__ gn_b, float* __restrict__ pqr)
{
  int b = blockIdx.x, c = threadIdx.x, g = c >> 3;
  float sd = 0, sd2 = 0;
  for (int bb = 0; bb < 8; bb++){ sd += s5[(long)(bb*C_ + c)*5 + 0]; sd2 += s5[(long)(bb*C_ + c)*5 + 1]; }
  float inv_cnt = 1.f/32768.f;
  float mB = sd*inv_cnt;
  float vB = sd2*inv_cnt - mB*mB;
  float ab = dbn_g[c] * rsqrtf(vclamp(vB));
  float db = dbn_b[c] - mB*ab;
  const float* s = s5 + (long)(b*C_ + c)*5;
  float inv_n = 1.f/4096.f;
  float m = s[0]*inv_n, Ed2 = s[1]*inv_n, mx = s[2]*inv_n, Ex2 = s[3]*inv_n, Edx = s[4]*inv_n;
  float Ev = ab*m + db;
  float Ev2 = ab*ab*Ed2 + 2.f*ab*db*m + db*db;
  __shared__ float e1[256], e2[256];
  e1[c] = Ev; e2[c] = Ev2;
  __syncthreads();
  float m1 = 0, q1 = 0;
  for (int k = 0; k < 8; k++){ m1 += e1[(g << 3) + k]; q1 += e2[(g << 3) + k]; }
  m1 *= 0.125f; q1 *= 0.125f;
  float inv1 = rsqrtf(vclamp(q1 - m1*m1));
  float gg = gn_g[c];
  float A1 = inv1*gg;
  float D1 = gn_b[c] - m1*A1;
  float al = A1*ab;
  float be = A1*db + D1;
  float Et = al*m + be + mx;
  float Et2 = al*al*Ed2 + 2.f*al*be*m + be*be + 2.f*al*Edx + 2.f*be*mx + Ex2;
  __syncthreads();
  e1[c] = Et; e2[c] = Et2;
  __syncthreads();
  float m2 = 0, q2 = 0;
  for (int k = 0; k < 8; k++){ m2 += e1[(g << 3) + k]; q2 += e2[(g << 3) + k]; }
  m2 *= 0.125f; q2 *= 0.125f;
  float inv2 = rsqrtf(vclamp(q2 - m2*m2));
  float G = inv2*gg;
  float* o = pqr + (long)(b*C_ + c)*3;
  o[0] = G*al;
  o[1] = G;
  o[2] = G*(be - m2) + gn_b[c];
}

// ---------------- final elementwise: out = P*out + Q*x + R (in-place on d_out) -----
// grid (C, B), block 256
__global__ __launch_bounds__(256) void final_kernel(const float* __restrict__ x,
    const float* __restrict__ pqr, float* __restrict__ out)
{
  int c = blockIdx.x, b = blockIdx.y, tid = threadIdx.x;
  const float* o = pqr + (long)(b*C_ + c)*3;
  float P = o[0], Q = o[1], R = o[2];
  long base = ((long)(b*C_ + c))*4096;
  for (int it = 0; it < 16; it++){
    long idx = base + it*256 + tid;
    out[idx] = P*out[idx] + Q*x[idx] + R;
  }
}

extern "C" void kernel_launch(void* const* d_in, const int* in_sizes, int n_in,
                              void* d_out, int out_size, void* d_ws, size_t ws_size,
                              hipStream_t stream)
{
  (void)in_sizes; (void)n_in; (void)out_size; (void)ws_size;
  // ALL inputs/outputs are float32.
  const float* x         = (const float*)d_in[0];
  const float* pos       = (const float*)d_in[1];
  const float* ln_w      = (const float*)d_in[2];
  const float* ln_b      = (const float*)d_in[3];
  const float* proj_w    = (const float*)d_in[4];
  const float* proj_b    = (const float*)d_in[5];
  const float* up_dw_w   = (const float*)d_in[6];
  const float* up_bn1_g  = (const float*)d_in[7];
  const float* up_bn1_b  = (const float*)d_in[8];
  const float* up_pw_w   = (const float*)d_in[9];
  const float* up_bn2_g  = (const float*)d_in[10];
  const float* up_bn2_b  = (const float*)d_in[11];
  const float* down_pw_w = (const float*)d_in[12];
  const float* down_bn_g = (const float*)d_in[13];
  const float* down_bn_b = (const float*)d_in[14];
  const float* gn_g      = (const float*)d_in[15];
  const float* gn_b      = (const float*)d_in[16];
  const float* f_in_w    = (const float*)d_in[17];
  const float* f_conv_w  = (const float*)d_in[18];
  const float* f_conv_b  = (const float*)d_in[19];
  const float* f_xproj_w = (const float*)d_in[20];
  const float* f_dt_w    = (const float*)d_in[21];
  const float* f_dt_b    = (const float*)d_in[22];
  const float* f_Alog    = (const float*)d_in[23];
  const float* f_D       = (const float*)d_in[24];
  const float* f_out_w   = (const float*)d_in[25];
  const float* b_in_w    = (const float*)d_in[26];
  const float* b_conv_w  = (const float*)d_in[27];
  const float* b_conv_b  = (const float*)d_in[28];
  const float* b_xproj_w = (const float*)d_in[29];
  const float* b_dt_w    = (const float*)d_in[30];
  const float* b_dt_b    = (const float*)d_in[31];
  const float* b_Alog    = (const float*)d_in[32];
  const float* b_D       = (const float*)d_in[33];
  const float* b_out_w   = (const float*)d_in[34];

  // ======== workspace layout, PEAK = 132MB ========
  char* sb = (char*)d_ws;
  float* statz = (float*)(sb);               // 1536 f (zeroed each launch)
  float* abn   = (float*)(sb + 8192);        // 1024 f
  float* gnAD  = (float*)(sb + 16384);       // 4096 f
  float* stat5 = (float*)(sb + 65536);       // 10240 f
  float* pqr   = (float*)(sb + 131072);      // 6144 f
  float* rmrn  = (float*)(sb + 1*MB);        // 2MB: 2 x (1024,256)
  bf16*  Wbbuf = (bf16*)(sb + 3*MB);         // 128KB: up_pw_w in bf16
  char* big = sb + 4*MB;
  float* pool4  = (float*)(big + 0*MB);      // 2 MB
  float* hbuf   = (float*)(big + 2*MB);      // 4 MB
  float* xzbuf  = (float*)(big + 6*MB);      // 16 MB
  float* ubuf   = (float*)(big + 22*MB);     // 8 MB
  float* dblbuf = (float*)(big + 30*MB);     // 768 KB
  float* dtbuf  = (float*)(big + 31*MB);     // 8 MB
  float* ybuf   = (float*)(big + 39*MB);     // 8 MB
  float* mout   = (float*)(big + 47*MB);     // 4 MB
  float* cbuf   = (float*)(big + 51*MB);     // 4 MB
  float* respre = (float*)(big + 55*MB);     // 2 MB  (ends at 57MB < 64MB)
  bf16*  z1buf  = (bf16*)(big);              // 64 MiB bf16, c-major (phase 2a)
  bf16*  z2buf  = (bf16*)(big);              // 64 MiB bf16 (phase 2b/3; z1 dead)
  bf16*  z1tbuf = (bf16*)(sb + 68*MB);       // 64 MiB bf16, p-major
  float* dbuf   = (float*)d_out;             // 32 MB fp32 (phase 3)

  float* bn1sum = statz;        float* bn1sq = statz + 256;
  float* bn2sum = statz + 512;  float* bn2sq = statz + 768;
  float* gnsum  = statz + 1024; float* gnsq  = statz + 1280;
  float* abn1 = abn;       float* dbn1 = abn + 256;
  float* abn2 = abn + 512; float* dbn2 = abn + 768;
  float* gnA = gnAD;       float* gnD = gnAD + 2048;
  float* pcolmax = pool4;
  float* pcolmin = pool4 + 131072;
  float* prowmax = pool4 + 262144;
  float* prowmin = pool4 + 393216;

  hipMemsetAsync(statz, 0, 1536*sizeof(float), stream);

  // ---- phase 1: pooling + LN + mamba x4 (f/b x max/min) -> rmrn ----
  pool1_kernel<<<dim3(256, 8), 64, 0, stream>>>(x, pos, pcolmax, pcolmin, prowmax, prowmin);
  pool2_kernel<<<dim3(128, 8), 256, 0, stream>>>(pcolmax, pcolmin, prowmax, prowmin, ln_w, ln_b, hbuf);
  gemm_kernel<<<dim3(16, 16, 4), 256, 0, stream>>>(hbuf, 262144, 256, f_in_w, b_in_w, nullptr, nullptr, 2,
                                                   xzbuf, 1048576, 1024, 1024, 1024, 256, 0);
  conv1d_kernel<<<dim3(128, 8, 4), 512, 0, stream>>>(xzbuf, f_conv_w, f_conv_b, b_conv_w, b_conv_b, ubuf);
  gemm_kernel<<<dim3(1, 16, 4), 256, 0, stream>>>(ubuf, 524288, 512, f_xproj_w, b_xproj_w, nullptr, nullptr, 2,
                                                  dblbuf, 49152, 48, 1024, 48, 512, 0);
  gemm_kernel<<<dim3(8, 16, 4), 256, 0, stream>>>(dblbuf, 49152, 48, f_dt_w, b_dt_w, f_dt_b, b_dt_b, 2,
                                                  dtbuf, 524288, 512, 1024, 512, 16, 2);
  scan_kernel<<<dim3(8, 8, 4), 64, 0, stream>>>(dtbuf, ubuf, dblbuf, xzbuf, f_Alog, f_D, b_Alog, b_D, ybuf);
  gemm_kernel<<<dim3(4, 16, 4), 256, 0, stream>>>(ybuf, 524288, 512, f_out_w, b_out_w, nullptr, nullptr, 2,
                                                  mout, 262144, 256, 1024, 256, 512, 0);
  ln_kernel<<<dim3(128, 8, 4), 256, 0, stream>>>(mout, cbuf, cbuf + 524288, ln_w, ln_b, 1);
  gemm_kernel<<<dim3(4, 16, 2), 256, 0, stream>>>(cbuf, 524288, 512, proj_w, proj_w, proj_b, proj_b, 2,
                                                  respre, 262144, 256, 1024, 256, 512, 0);
  ln_kernel<<<dim3(128, 8, 2), 256, 0, stream>>>(respre, rmrn, nullptr, ln_w, ln_b, 0);

  // ---- phase 2: z path ----
  dwz1_kernel<<<2048, 256, 0, stream>>>(x, up_dw_w, z1buf, bn1sum, bn1sq);
  fin_bn_kernel<<<1, 256, 0, stream>>>(bn1sum, bn1sq, up_bn1_g, up_bn1_b, 1.f/131072.f, abn1, dbn1);
  wcvt_kernel<<<256, 256, 0, stream>>>(up_pw_w, Wbbuf, 65536);
  actz1_kernel<<<dim3(256, 4, 8), 256, 0, stream>>>(z1buf, abn1, dbn1, z1tbuf);
  pwz_mfma_kernel<<<dim3(256, 8), 256, 0, stream>>>(z1tbuf, Wbbuf, z2buf);
  chstats_kernel<<<dim3(256, 8), 256, 0, stream>>>(z2buf, bn2sum, bn2sq);
  fin_bn_kernel<<<1, 256, 0, stream>>>(bn2sum, bn2sq, up_bn2_g, up_bn2_b, 1.f/131072.f, abn2, dbn2);

  // ---- phase 3: merge + tail ----
  hsig_kernel<<<dim3(256, 8), 256, 0, stream>>>(z2buf, rmrn, rmrn + 262144, abn2, dbn2, gnsum, gnsq);
  fin_gn_kernel<<<8, 256, 0, stream>>>(gnsum, gnsq, gn_g, gn_b, gnA, gnD);
  pwdown_gemm_kernel<<<dim3(64, 4, 8), 256, 0, stream>>>(z2buf, down_pw_w, gnA, gnD, dbuf);
  stat5_kernel<<<dim3(256, 8), 256, 0, stream>>>(dbuf, x, stat5);
  coeff_kernel<<<8, 256, 0, stream>>>(stat5, down_bn_g, down_bn_b, gn_g, gn_b, pqr);
  final_kernel<<<dim3(256, 8), 256, 0, stream>>>(x, pqr, (float*)d_out);
}

// Round 9
// 788.464 us; speedup vs baseline: 2.4791x; 1.0180x over previous
//
#include <hip/hip_runtime.h>
#include <hip/hip_bf16.h>

typedef __hip_bfloat16 bf16;
typedef __attribute__((ext_vector_type(8))) short bf16x8v;
typedef __attribute__((ext_vector_type(4))) float f32x4v;

#define B_ 8
#define C_ 256
#define L_ 128
#define MB 1048576UL

__device__ inline float b2f(bf16 v){ return __bfloat162float(v); }
__device__ inline bf16 f2b(float v){ return __float2bfloat16(v); }
__device__ inline float siluf(float x){ return x / (1.f + expf(-x)); }
__device__ inline float softplusf(float x){ return (x > 20.f) ? x : log1pf(expf(x)); }
__device__ inline float vclamp(float v){ return fmaxf(v, 0.f) + 1e-5f; }

// block = 256 threads. red must hold 512 floats.
__device__ inline void bred2(float& a, float& b, float* red){
  int t = threadIdx.x;
  __syncthreads();
  red[t] = a; red[256 + t] = b;
  __syncthreads();
  for (int off = 128; off > 0; off >>= 1){
    if (t < off){ red[t] += red[t + off]; red[256 + t] += red[256 + t + off]; }
    __syncthreads();
  }
  a = red[0]; b = red[256];
}
__device__ inline float bred1(float a, float* red){
  int t = threadIdx.x;
  __syncthreads();
  red[t] = a; __syncthreads();
  for (int off = 128; off > 0; off >>= 1){
    if (t < off) red[t] += red[t + off];
    __syncthreads();
  }
  return red[0];
}

// ---------------- pooling step 1: row/col max/min + argmax + pos-embed -------------
// grid (C, B), block 64
__global__ __launch_bounds__(64) void pool1_kernel(const float* __restrict__ x, const float* __restrict__ pos,
    float* __restrict__ pcolmax, float* __restrict__ pcolmin,
    float* __restrict__ prowmax, float* __restrict__ prowmin)
{
  int c = blockIdx.x, b = blockIdx.y, t = threadIdx.x;
  __shared__ float xs[64][65];
  const float* xp = x + ((long)(b*C_ + c))*4096;
  for (int i = 0; i < 64; i++) xs[i][t] = xp[i*64 + t];
  __syncthreads();
  // jax.image.resize 'linear' 16->64: half-pixel coords, edge clamp
  float tt = 0.25f*(float)t - 0.375f;
  const float* pp = pos + c*16;
  float pe;
  if (tt <= 0.f) pe = pp[0];
  else if (tt >= 15.f) pe = pp[15];
  else { int f = (int)floorf(tt); float w = tt - (float)f; pe = pp[f]*(1.f - w) + pp[f+1]*w; }
  float vmax = -1e30f, vmin = 1e30f; int amax = 0, amin = 0;
  for (int j = 0; j < 64; j++){
    float v = xs[t][j];
    if (v > vmax){ vmax = v; amax = j; }
    if (v < vmin){ vmin = v; amin = j; }
  }
  long o = (long)(b*64 + t)*C_ + c;
  prowmax[o] = vmax + pe + (float)amax;
  prowmin[o] = vmin + pe + (float)amin;
  vmax = -1e30f; vmin = 1e30f; amax = 0; amin = 0;
  for (int i = 0; i < 64; i++){
    float v = xs[i][t];
    if (v > vmax){ vmax = v; amax = i; }
    if (v < vmin){ vmin = v; amin = i; }
  }
  pcolmax[o] = vmax + pe + (float)amax;
  pcolmin[o] = vmin + pe + (float)amin;
}

// ---------------- pooling step 2: LN over channels, write 4 mamba inputs -----------
// grid (128, B), block 256
__global__ __launch_bounds__(256) void pool2_kernel(const float* __restrict__ pcolmax, const float* __restrict__ pcolmin,
    const float* __restrict__ prowmax, const float* __restrict__ prowmin,
    const float* __restrict__ lnw, const float* __restrict__ lnb, float* __restrict__ hbuf)
{
  int r = blockIdx.x, b = blockIdx.y, c = threadIdx.x;
  __shared__ float red[512];
  int p = r & 63;
  long src = (long)(b*64 + p)*C_ + c;
  float vmax = (r < 64) ? pcolmax[src] : prowmax[src];
  float vmin = (r < 64) ? pcolmin[src] : prowmin[src];
  float gw = lnw[c], gb = lnb[c];
  long row = (long)b*L_ + r, frow = (long)b*L_ + (127 - r);
  float s = vmax, s2 = vmax*vmax;
  bred2(s, s2, red);
  float m = s*(1.f/256.f), var = s2*(1.f/256.f) - m*m;
  float o = (vmax - m)*rsqrtf(vclamp(var))*gw + gb;
  hbuf[0*262144 + row*C_ + c]  = o;
  hbuf[2*262144 + frow*C_ + c] = o;
  s = vmin; s2 = vmin*vmin;
  bred2(s, s2, red);
  m = s*(1.f/256.f); var = s2*(1.f/256.f) - m*m;
  o = (vmin - m)*rsqrtf(vclamp(var))*gw + gb;
  hbuf[1*262144 + row*C_ + c]  = o;
  hbuf[3*262144 + frow*C_ + c] = o;
}

// ---------------- dwconvT on-the-fly helper ----------------------------------------
__device__ inline float dwconvT_at(const float* __restrict__ xp, const float* __restrict__ w, int i, int j)
{
  float acc = 0.f;
  #pragma unroll
  for (int ki = 0; ki < 3; ki++){
    int pi = i + ki - 1;
    if (pi < 0 || (pi & 1)) continue;
    int xi = pi >> 1;
    if (xi >= 64) continue;
    #pragma unroll
    for (int kj = 0; kj < 3; kj++){
      int pj = j + kj - 1;
      if (pj < 0 || (pj & 1)) continue;
      int xj = pj >> 1;
      if (xj >= 64) continue;
      acc += w[(2-ki)*3 + (2-kj)] * xp[xi*64 + xj];
    }
  }
  return acc;
}

// ---------------- z1raw = dwconvT(x) as bf16 + bn1 stats (one pass) ----------------
// x plane staged in LDS; coalesced bf16 stores. grid (B*C), block 256.
__global__ __launch_bounds__(256) void dwz1_kernel(const float* __restrict__ x, const float* __restrict__ dw,
    bf16* __restrict__ z1, float* __restrict__ bn1sum, float* __restrict__ bn1sq)
{
  int bc = blockIdx.x; int c = bc & 255;
  int tid = threadIdx.x;
  __shared__ float xs[4096];
  const float* xp = x + (long)bc*4096;
  for (int it = 0; it < 16; it++) xs[it*256 + tid] = xp[it*256 + tid];
  float w[9];
  #pragma unroll
  for (int q = 0; q < 9; q++) w[q] = dw[c*9 + q];
  __syncthreads();
  bf16* zp = z1 + (long)bc*16384;
  float s = 0.f, s2 = 0.f;
  for (int it = 0; it < 64; it++){
    int p = it*256 + tid; int i = p >> 7, j = p & 127;
    float acc = dwconvT_at(xs, w, i, j);
    zp[p] = f2b(acc);
    s += acc; s2 += acc*acc;
  }
  __shared__ float red[512];
  bred2(s, s2, red);
  if (tid == 0){ atomicAdd(&bn1sum[c], s); atomicAdd(&bn1sq[c], s2); }
}

// ---------------- bn finalize: per-channel affine ----------------------------------
__global__ void fin_bn_kernel(const float* __restrict__ sum, const float* __restrict__ sq,
                              const float* __restrict__ g, const float* __restrict__ b,
                              float cnt_inv, float* __restrict__ a, float* __restrict__ d)
{
  int c = threadIdx.x;
  float m = sum[c]*cnt_inv;
  float v = sq[c]*cnt_inv - m*m;
  float aa = g[c] * rsqrtf(vclamp(v));
  a[c] = aa;
  d[c] = b[c] - m*aa;
}

// ---------------- fp32 -> bf16 weight convert --------------------------------------
__global__ void wcvt_kernel(const float* __restrict__ W, bf16* __restrict__ Wb, int n)
{
  int i = blockIdx.x*256 + threadIdx.x;
  if (i < n) Wb[i] = f2b(W[i]);
}

// ---------------- actz1: z1t[b][p][c] = bf16(relu(fa[c]*z1[b,c,p]+fd[c])) ----------
// 64x64 transpose via LDS fp32 tile (bank-clean). grid (256, 4, B), block 256.
__global__ __launch_bounds__(256) void actz1_kernel(const bf16* __restrict__ z1,
    const float* __restrict__ fa, const float* __restrict__ fd, bf16* __restrict__ z1t)
{
  int p0 = blockIdx.x*64, c0 = blockIdx.y*64, b = blockIdx.z;
  int tid = threadIdx.x;
  __shared__ float t[64][65];
  #pragma unroll
  for (int q = 0; q < 2; q++){
    int cl = (tid >> 3) + q*32;
    int p8 = (tid & 7)*8;
    const bf16* src = &z1[((long)(b*C_ + c0 + cl))*16384 + p0 + p8];
    float a = fa[c0 + cl], d = fd[c0 + cl];
    bf16 v[8];
    *(uint4*)v = *(const uint4*)src;
    #pragma unroll
    for (int i = 0; i < 8; i++) t[p8 + i][cl] = fmaxf(b2f(v[i])*a + d, 0.f);
  }
  __syncthreads();
  #pragma unroll
  for (int q = 0; q < 2; q++){
    int pl = (tid >> 3) + q*32;
    int c8 = (tid & 7)*8;
    bf16 v[8];
    #pragma unroll
    for (int i = 0; i < 8; i++) v[i] = f2b(t[pl][c8 + i]);
    *(uint4*)&z1t[((long)b*16384 + p0 + pl)*256 + c0 + c8] = *(const uint4*)v;
  }
}

// ---------------- up-pw GEMM on MFMA: z2[b,o,p] = sum_c Wb[o,c]*z1t[b,p,c] ---------
// Block: M=256 x N=64 x K=256, 4 waves, wave handles 64 M rows; 4x4 16x16 acc tiles.
// grid (256, B), block 256.
__global__ __launch_bounds__(256) void pwz_mfma_kernel(const bf16* __restrict__ z1t,
    const bf16* __restrict__ Wb, bf16* __restrict__ z2)
{
  int b = blockIdx.y;
  int p0 = blockIdx.x*64;
  int tid = threadIdx.x;
  int wave = tid >> 6, lane = tid & 63;
  int quad = lane >> 4, l16 = lane & 15;
  const bf16* zb = z1t + (long)b*16384*256;
  f32x4v acc[4][4];
  #pragma unroll
  for (int i = 0; i < 4; i++)
    #pragma unroll
    for (int j = 0; j < 4; j++) acc[i][j] = (f32x4v){0.f, 0.f, 0.f, 0.f};
  for (int k0 = 0; k0 < 256; k0 += 32){
    int c = k0 + quad*8;
    bf16x8v a[4], bb[4];
    #pragma unroll
    for (int ms = 0; ms < 4; ms++)
      a[ms] = *(const bf16x8v*)&Wb[(wave*64 + ms*16 + l16)*C_ + c];
    #pragma unroll
    for (int ns = 0; ns < 4; ns++)
      bb[ns] = *(const bf16x8v*)&zb[((long)(p0 + ns*16 + l16))*C_ + c];
    #pragma unroll
    for (int ms = 0; ms < 4; ms++)
      #pragma unroll
      for (int ns = 0; ns < 4; ns++)
        acc[ms][ns] = __builtin_amdgcn_mfma_f32_16x16x32_bf16(a[ms], bb[ns], acc[ms][ns], 0, 0, 0);
  }
  #pragma unroll
  for (int ms = 0; ms < 4; ms++){
    int o = wave*64 + ms*16 + quad*4;
    #pragma unroll
    for (int r = 0; r < 4; r++){
      long rowbase = ((long)(b*C_ + o + r))*16384 + p0;
      #pragma unroll
      for (int ns = 0; ns < 4; ns++)
        z2[rowbase + ns*16 + l16] = f2b(acc[ms][ns][r]);
    }
  }
}

// ---------------- per-channel stats of bf16 tensor (B,C,16384) ---------------------
// grid (C, B), block 256
__global__ __launch_bounds__(256) void chstats_kernel(const bf16* __restrict__ t,
                                                      float* __restrict__ sum, float* __restrict__ sq)
{
  int c = blockIdx.x, b = blockIdx.y, tid = threadIdx.x;
  const bf16* p = t + ((long)(b*C_ + c))*16384;
  float s = 0.f, s2 = 0.f;
  for (int it = 0; it < 64; it++){ float v = b2f(p[it*256 + tid]); s += v; s2 += v*v; }
  __shared__ float red[512];
  bred2(s, s2, red);
  if (tid == 0){ atomicAdd(&sum[c], s); atomicAdd(&sq[c], s2); }
}

// ---------------- generic GEMM: C[m,n] = act(sum_k A[m,k] W[n,k] + bias[n]) --------
// A fp32 (lda, batch stride sA), W fp32 (N,K) row-major, batched over grid.z.
// grid ((N+63)/64, (M+63)/64, nbatch), block 256
__global__ __launch_bounds__(256) void gemm_kernel(
  const float* __restrict__ Abase, long sA, int lda,
  const float* __restrict__ W0, const float* __restrict__ W1,
  const float* __restrict__ bias0, const float* __restrict__ bias1, int wsplit,
  float* __restrict__ Cbase, long sC, int ldc,
  int M, int N, int K, int act)
{
  int z = blockIdx.z;
  const float* A = Abase + (long)z*sA;
  float* Cp = Cbase + (long)z*sC;
  const float* W = (z >= wsplit) ? W1 : W0;
  const float* bias = (z >= wsplit) ? bias1 : bias0;
  int m0 = blockIdx.y*64, n0 = blockIdx.x*64;
  __shared__ __align__(16) float As[16][68];
  __shared__ __align__(16) float Ws[16][68];
  int tid = threadIdx.x, tx = tid & 15, ty = tid >> 4;
  float acc[4][4] = {};
  for (int k0 = 0; k0 < K; k0 += 16){
    #pragma unroll
    for (int q = 0; q < 4; q++){
      int e = tid + q*256; int r = e >> 4, kk = e & 15;
      int mi = m0 + r, ki = k0 + kk;
      As[kk][r] = (mi < M && ki < K) ? A[(long)mi*lda + ki] : 0.f;
    }
    #pragma unroll
    for (int q = 0; q < 4; q++){
      int e = tid + q*256; int n = e >> 4, kk = e & 15;
      int ni = n0 + n, ki = k0 + kk;
      Ws[kk][n] = (ni < N && ki < K) ? W[(long)ni*K + ki] : 0.f;
    }
    __syncthreads();
    #pragma unroll
    for (int kk = 0; kk < 16; kk++){
      float4 a4 = *(const float4*)&As[kk][ty*4];
      float4 b4 = *(const float4*)&Ws[kk][tx*4];
      float av[4] = {a4.x, a4.y, a4.z, a4.w};
      float bv[4] = {b4.x, b4.y, b4.z, b4.w};
      #pragma unroll
      for (int mm = 0; mm < 4; mm++)
        #pragma unroll
        for (int nn = 0; nn < 4; nn++) acc[mm][nn] += av[mm]*bv[nn];
    }
    __syncthreads();
  }
  #pragma unroll
  for (int mm = 0; mm < 4; mm++){
    int mi = m0 + ty*4 + mm;
    if (mi >= M) continue;
    #pragma unroll
    for (int nn = 0; nn < 4; nn++){
      int ni = n0 + tx*4 + nn;
      if (ni >= N) continue;
      float v = acc[mm][nn];
      if (bias) v += bias[ni];
      if (act == 2) v = softplusf(v);
      Cp[(long)mi*ldc + ni] = v;
    }
  }
}

// ---------------- depthwise causal conv1d (k=4) + silu -----------------------------
// grid (L, B, 4), block 512
__global__ __launch_bounds__(512) void conv1d_kernel(const float* __restrict__ xzb,
    const float* __restrict__ fw, const float* __restrict__ fb,
    const float* __restrict__ bw, const float* __restrict__ bb,
    float* __restrict__ ub)
{
  int l = blockIdx.x, b = blockIdx.y, v = blockIdx.z, d = threadIdx.x;
  const float* xm = xzb + (long)v*1024*1024;
  const float* w  = (v < 2) ? fw : bw;
  const float* cb = (v < 2) ? fb : bb;
  float acc = cb[d];
  #pragma unroll
  for (int k = 0; k < 4; k++){
    int ll = l - 3 + k;
    if (ll >= 0) acc += xm[(long)(b*L_ + ll)*1024 + d] * w[d*4 + k];
  }
  ub[(long)v*1024*512 + (long)(b*L_ + l)*512 + d] = siluf(acc);
}

// ---------------- selective scan (deep software pipeline) --------------------------
// One wave per block, 256 blocks. B/C preloaded to LDS once; dt/u/zg prefetched
// EIGHT steps ahead via circular register buffer (T = max(compute, latency/8)).
// grid (8, B, 4), block 64 : thread = one (b,d), d = bx*64 + lane
__global__ __launch_bounds__(64) void scan_kernel(const float* __restrict__ dtb, const float* __restrict__ ub,
    const float* __restrict__ dblb, const float* __restrict__ xzb,
    const float* __restrict__ fAlog, const float* __restrict__ fD,
    const float* __restrict__ bAlog, const float* __restrict__ bD,
    float* __restrict__ yb)
{
  int v = blockIdx.z, b = blockIdx.y;
  int d = blockIdx.x*64 + threadIdx.x;
  const float* dt  = dtb  + (long)v*1024*512;
  const float* u   = ub   + (long)v*1024*512;
  const float* dbl = dblb + (long)v*1024*48;
  const float* zg  = xzb  + (long)v*1024*1024 + 512;
  const float* Alog = (v < 2) ? fAlog : bAlog;
  const float* Dp   = (v < 2) ? fD : bD;
  __shared__ __align__(16) float bcs[128][32];  // [l][0..15]=B, [16..31]=C
  for (int idx = threadIdx.x; idx < 4096; idx += 64){
    int l = idx >> 5, i = idx & 31;
    bcs[l][i] = dbl[(long)(b*L_ + l)*48 + 16 + i];
  }
  float a[16];
  #pragma unroll
  for (int n = 0; n < 16; n++) a[n] = -expf(Alog[d*16 + n]);
  float Dv = Dp[d];
  float h[16];
  #pragma unroll
  for (int n = 0; n < 16; n++) h[n] = 0.f;
  __syncthreads();
  long row = (long)b*L_;
  float* yo = yb + (long)v*1024*512;
  float pdt[8], pu[8], pzg[8];
  #pragma unroll
  for (int q = 0; q < 8; q++){
    long r2 = row + q;
    pdt[q] = dt[r2*512 + d];
    pu[q]  = u [r2*512 + d];
    pzg[q] = zg[r2*1024 + d];
  }
  for (int l0 = 0; l0 < L_; l0 += 8){
    #pragma unroll
    for (int ph = 0; ph < 8; ph++){
      int l = l0 + ph;
      float dtv = pdt[ph], uv = pu[ph], zgv = pzg[ph];
      if (l + 8 < L_){
        long r2 = row + l + 8;
        pdt[ph] = dt[r2*512 + d];
        pu[ph]  = u [r2*512 + d];
        pzg[ph] = zg[r2*1024 + d];
      }
      float Bv[16], Cv[16];
      #pragma unroll
      for (int q4 = 0; q4 < 4; q4++){
        *(float4*)&Bv[q4*4] = *(const float4*)&bcs[l][q4*4];
        *(float4*)&Cv[q4*4] = *(const float4*)&bcs[l][16 + q4*4];
      }
      float dtu = dtv*uv;
      float acc = 0.f;
      #pragma unroll
      for (int n = 0; n < 16; n++){
        float dA = expf(dtv*a[n]);
        h[n] = dA*h[n] + dtu*Bv[n];
        acc += h[n]*Cv[n];
      }
      yo[(row + l)*512 + d] = (acc + Dv*uv) * siluf(zgv);
    }
  }
}

// ---------------- LayerNorm over C, two output modes -------------------------------
// grid (128, B, NV), block 256
__global__ __launch_bounds__(256) void ln_kernel(const float* __restrict__ inb, float* __restrict__ out0,
    float* __restrict__ out1, const float* __restrict__ lnw, const float* __restrict__ lnb, int mode)
{
  int r = blockIdx.x, b = blockIdx.y, v = blockIdx.z, c = threadIdx.x;
  long row = (long)b*L_ + r;
  float val = inb[((long)v*1024 + row)*C_ + c];
  __shared__ float red[512];
  float s = val, s2 = val*val;
  bred2(s, s2, red);
  float m = s*(1.f/256.f), var = s2*(1.f/256.f) - m*m;
  float o = (val - m)*rsqrtf(vclamp(var))*lnw[c] + lnb[c];
  if (mode == 1){
    long frow = (long)b*L_ + (127 - r);
    if (v == 0)      out0[row*512 + c] = o;
    else if (v == 1) out1[row*512 + c] = o;
    else if (v == 2) out0[frow*512 + 256 + c] = o;
    else             out1[frow*512 + 256 + c] = o;
  } else {
    out0[((long)v*1024 + row)*C_ + c] = o;
  }
}

// ---------------- hsig(rm+rn)*clip(bn2(z2)) + gn stats; resq IN-PLACE in z2 --------
// grid (C, B), block 256
__global__ __launch_bounds__(256) void hsig_kernel(bf16* __restrict__ z2, const float* __restrict__ rm,
    const float* __restrict__ rn, const float* __restrict__ a2, const float* __restrict__ d2,
    float* __restrict__ gnsum, float* __restrict__ gnsq)
{
  int c = blockIdx.x, b = blockIdx.y, tid = threadIdx.x;
  __shared__ float rms[128], rns[128];
  if (tid < 128){
    rms[tid] = rm[(long)(b*L_ + tid)*C_ + c];
    rns[tid] = rn[(long)(b*L_ + tid)*C_ + c];
  }
  __syncthreads();
  float aa = a2[c], dd = d2[c];
  bf16* zp = z2 + ((long)(b*C_ + c))*16384;
  float s = 0.f, s2 = 0.f;
  for (int g = 0; g < 16; g++){
    float tv[4]; int wq[4];
    #pragma unroll
    for (int q = 0; q < 4; q++){
      int p = g*1024 + q*256 + tid; int i = p >> 7, j = p & 127;
      float zv = b2f(zp[p])*aa + dd;
      zv = fminf(fmaxf(zv, 0.f), 6.f);
      float gate = rms[i] + rns[j];
      gate = fminf(fmaxf(gate + 3.f, 0.f), 6.f) * (1.f/6.f);
      float t = gate*zv;
      s += t; s2 += t*t;
      tv[q] = t;
      wq[q] = (((i | j) & 1) == 0) ? ((i >> 1)*64 + (j >> 1)) : -1;
    }
    __syncthreads();
    #pragma unroll
    for (int q = 0; q < 4; q++)
      if (wq[q] >= 0) zp[wq[q]] = f2b(tv[q]);
  }
  __shared__ float red[512];
  bred2(s, s2, red);
  if (tid == 0){ atomicAdd(&gnsum[b*32 + (c >> 3)], s); atomicAdd(&gnsq[b*32 + (c >> 3)], s2); }
}

// ---------------- gn finalize to per-(b,c) affine ----------------------------------
// grid (B), block 256
__global__ void fin_gn_kernel(const float* __restrict__ gnsum, const float* __restrict__ gnsq,
                              const float* __restrict__ g, const float* __restrict__ bb,
                              float* __restrict__ gnA, float* __restrict__ gnD)
{
  int b = blockIdx.x, c = threadIdx.x, gr = c >> 3;
  float inv_cnt = 1.f/131072.f;
  float m = gnsum[b*32 + gr]*inv_cnt;
  float v = gnsq[b*32 + gr]*inv_cnt - m*m;
  float inv = rsqrtf(vclamp(v));
  float A = inv*g[c];
  gnA[b*C_ + c] = A;
  gnD[b*C_ + c] = bb[c] - m*A;
}

// ---------------- trd: rqt[b][s][c] = bf16(gnA*resq[b,c,s]+gnD) --------------------
// resq rows strided 16384 (in-place inside z2); 64x64 LDS transpose.
// grid (64, 4, B), block 256.
__global__ __launch_bounds__(256) void trd_kernel(const bf16* __restrict__ z2,
    const float* __restrict__ gnA, const float* __restrict__ gnD, bf16* __restrict__ rqt)
{
  int p0 = blockIdx.x*64, c0 = blockIdx.y*64, b = blockIdx.z;
  int tid = threadIdx.x;
  __shared__ float t[64][65];
  #pragma unroll
  for (int q = 0; q < 2; q++){
    int cl = (tid >> 3) + q*32;
    int p8 = (tid & 7)*8;
    int c = c0 + cl;
    const bf16* src = &z2[((long)(b*C_ + c))*16384 + p0 + p8];
    float a = gnA[b*C_ + c], dd = gnD[b*C_ + c];
    bf16 v[8];
    *(uint4*)v = *(const uint4*)src;
    #pragma unroll
    for (int i = 0; i < 8; i++) t[p8 + i][cl] = b2f(v[i])*a + dd;
  }
  __syncthreads();
  #pragma unroll
  for (int q = 0; q < 2; q++){
    int pl = (tid >> 3) + q*32;
    int c8 = (tid & 7)*8;
    bf16 v[8];
    #pragma unroll
    for (int i = 0; i < 8; i++) v[i] = f2b(t[pl][c8 + i]);
    *(uint4*)&rqt[((long)b*4096 + p0 + pl)*256 + c0 + c8] = *(const uint4*)v;
  }
}

// ---------------- down-pw GEMM on MFMA: d[b,o,s] = sum_c Wb[o,c]*rqt[b,s,c] --------
// Same structure as pwz_mfma; fp32 output to d_out (stride 4096). grid (64, B).
__global__ __launch_bounds__(256) void pwdown_mfma_kernel(const bf16* __restrict__ rqt,
    const bf16* __restrict__ Wb, float* __restrict__ out)
{
  int b = blockIdx.y;
  int p0 = blockIdx.x*64;
  int tid = threadIdx.x;
  int wave = tid >> 6, lane = tid & 63;
  int quad = lane >> 4, l16 = lane & 15;
  const bf16* zb = rqt + (long)b*4096*256;
  f32x4v acc[4][4];
  #pragma unroll
  for (int i = 0; i < 4; i++)
    #pragma unroll
    for (int j = 0; j < 4; j++) acc[i][j] = (f32x4v){0.f, 0.f, 0.f, 0.f};
  for (int k0 = 0; k0 < 256; k0 += 32){
    int c = k0 + quad*8;
    bf16x8v a[4], bb[4];
    #pragma unroll
    for (int ms = 0; ms < 4; ms++)
      a[ms] = *(const bf16x8v*)&Wb[(wave*64 + ms*16 + l16)*C_ + c];
    #pragma unroll
    for (int ns = 0; ns < 4; ns++)
      bb[ns] = *(const bf16x8v*)&zb[((long)(p0 + ns*16 + l16))*C_ + c];
    #pragma unroll
    for (int ms = 0; ms < 4; ms++)
      #pragma unroll
      for (int ns = 0; ns < 4; ns++)
        acc[ms][ns] = __builtin_amdgcn_mfma_f32_16x16x32_bf16(a[ms], bb[ns], acc[ms][ns], 0, 0, 0);
  }
  #pragma unroll
  for (int ms = 0; ms < 4; ms++){
    int o = wave*64 + ms*16 + quad*4;
    #pragma unroll
    for (int r = 0; r < 4; r++){
      long rowbase = ((long)(b*C_ + o + r))*4096 + p0;
      #pragma unroll
      for (int ns = 0; ns < 4; ns++)
        out[rowbase + ns*16 + l16] = acc[ms][ns][r];
    }
  }
}

// ---------------- 5 moments per (b,c): sum d, d^2, x, x^2, dx ----------------------
// grid (C, B), block 256
__global__ __launch_bounds__(256) void stat5_kernel(const float* __restrict__ dbuf, const float* __restrict__ x,
                                                    float* __restrict__ s5)
{
  int c = blockIdx.x, b = blockIdx.y, tid = threadIdx.x;
  const float* dp = dbuf + ((long)(b*C_ + c))*4096;
  const float* xp = x + ((long)(b*C_ + c))*4096;
  float sd = 0, sd2 = 0, sx = 0, sx2 = 0, sdx = 0;
  for (int it = 0; it < 16; it++){
    float d = dp[it*256 + tid];
    float xv = xp[it*256 + tid];
    sd += d; sd2 += d*d; sx += xv; sx2 += xv*xv; sdx += d*xv;
  }
  __shared__ float red[256];
  float r0 = bred1(sd, red); float r1 = bred1(sd2, red); float r2 = bred1(sx, red);
  float r3 = bred1(sx2, red); float r4 = bred1(sdx, red);
  if (tid == 0){
    float* o = s5 + (long)(b*C_ + c)*5;
    o[0] = r0; o[1] = r1; o[2] = r2; o[3] = r3; o[4] = r4;
  }
}

// ---------------- collapse bn -> gn -> (+x) -> gn into out = P*d + Q*x + R ---------
// grid (B), block 256
__global__ void coeff_kernel(const float* __restrict__ s5, const float* __restrict__ dbn_g, const float* __restrict__ dbn_b,
                             const float* __restrict__ gn_g, const float* __restrict__ gn_b, float* __restrict__ pqr)
{
  int b = blockIdx.x, c = threadIdx.x, g = c >> 3;
  float sd = 0, sd2 = 0;
  for (int bb = 0; bb < 8; bb++){ sd += s5[(long)(bb*C_ + c)*5 + 0]; sd2 += s5[(long)(bb*C_ + c)*5 + 1]; }
  float inv_cnt = 1.f/32768.f;
  float mB = sd*inv_cnt;
  float vB = sd2*inv_cnt - mB*mB;
  float ab = dbn_g[c] * rsqrtf(vclamp(vB));
  float db = dbn_b[c] - mB*ab;
  const float* s = s5 + (long)(b*C_ + c)*5;
  float inv_n = 1.f/4096.f;
  float m = s[0]*inv_n, Ed2 = s[1]*inv_n, mx = s[2]*inv_n, Ex2 = s[3]*inv_n, Edx = s[4]*inv_n;
  float Ev = ab*m + db;
  float Ev2 = ab*ab*Ed2 + 2.f*ab*db*m + db*db;
  __shared__ float e1[256], e2[256];
  e1[c] = Ev; e2[c] = Ev2;
  __syncthreads();
  float m1 = 0, q1 = 0;
  for (int k = 0; k < 8; k++){ m1 += e1[(g << 3) + k]; q1 += e2[(g << 3) + k]; }
  m1 *= 0.125f; q1 *= 0.125f;
  float inv1 = rsqrtf(vclamp(q1 - m1*m1));
  float gg = gn_g[c];
  float A1 = inv1*gg;
  float D1 = gn_b[c] - m1*A1;
  float al = A1*ab;
  float be = A1*db + D1;
  float Et = al*m + be + mx;
  float Et2 = al*al*Ed2 + 2.f*al*be*m + be*be + 2.f*al*Edx + 2.f*be*mx + Ex2;
  __syncthreads();
  e1[c] = Et; e2[c] = Et2;
  __syncthreads();
  float m2 = 0, q2 = 0;
  for (int k = 0; k < 8; k++){ m2 += e1[(g << 3) + k]; q2 += e2[(g << 3) + k]; }
  m2 *= 0.125f; q2 *= 0.125f;
  float inv2 = rsqrtf(vclamp(q2 - m2*m2));
  float G = inv2*gg;
  float* o = pqr + (long)(b*C_ + c)*3;
  o[0] = G*al;
  o[1] = G;
  o[2] = G*(be - m2) + gn_b[c];
}

// ---------------- final elementwise: out = P*out + Q*x + R (in-place on d_out) -----
// grid (C, B), block 256
__global__ __launch_bounds__(256) void final_kernel(const float* __restrict__ x,
    const float* __restrict__ pqr, float* __restrict__ out)
{
  int c = blockIdx.x, b = blockIdx.y, tid = threadIdx.x;
  const float* o = pqr + (long)(b*C_ + c)*3;
  float P = o[0], Q = o[1], R = o[2];
  long base = ((long)(b*C_ + c))*4096;
  for (int it = 0; it < 16; it++){
    long idx = base + it*256 + tid;
    out[idx] = P*out[idx] + Q*x[idx] + R;
  }
}

extern "C" void kernel_launch(void* const* d_in, const int* in_sizes, int n_in,
                              void* d_out, int out_size, void* d_ws, size_t ws_size,
                              hipStream_t stream)
{
  (void)in_sizes; (void)n_in; (void)out_size; (void)ws_size;
  // ALL inputs/outputs are float32.
  const float* x         = (const float*)d_in[0];
  const float* pos       = (const float*)d_in[1];
  const float* ln_w      = (const float*)d_in[2];
  const float* ln_b      = (const float*)d_in[3];
  const float* proj_w    = (const float*)d_in[4];
  const float* proj_b    = (const float*)d_in[5];
  const float* up_dw_w   = (const float*)d_in[6];
  const float* up_bn1_g  = (const float*)d_in[7];
  const float* up_bn1_b  = (const float*)d_in[8];
  const float* up_pw_w   = (const float*)d_in[9];
  const float* up_bn2_g  = (const float*)d_in[10];
  const float* up_bn2_b  = (const float*)d_in[11];
  const float* down_pw_w = (const float*)d_in[12];
  const float* down_bn_g = (const float*)d_in[13];
  const float* down_bn_b = (const float*)d_in[14];
  const float* gn_g      = (const float*)d_in[15];
  const float* gn_b      = (const float*)d_in[16];
  const float* f_in_w    = (const float*)d_in[17];
  const float* f_conv_w  = (const float*)d_in[18];
  const float* f_conv_b  = (const float*)d_in[19];
  const float* f_xproj_w = (const float*)d_in[20];
  const float* f_dt_w    = (const float*)d_in[21];
  const float* f_dt_b    = (const float*)d_in[22];
  const float* f_Alog    = (const float*)d_in[23];
  const float* f_D       = (const float*)d_in[24];
  const float* f_out_w   = (const float*)d_in[25];
  const float* b_in_w    = (const float*)d_in[26];
  const float* b_conv_w  = (const float*)d_in[27];
  const float* b_conv_b  = (const float*)d_in[28];
  const float* b_xproj_w = (const float*)d_in[29];
  const float* b_dt_w    = (const float*)d_in[30];
  const float* b_dt_b    = (const float*)d_in[31];
  const float* b_Alog    = (const float*)d_in[32];
  const float* b_D       = (const float*)d_in[33];
  const float* b_out_w   = (const float*)d_in[34];

  // ======== workspace layout, PEAK = 132MB ========
  char* sb = (char*)d_ws;
  float* statz = (float*)(sb);               // 1536 f (zeroed each launch)
  float* abn   = (float*)(sb + 8192);        // 1024 f
  float* gnAD  = (float*)(sb + 16384);       // 4096 f
  float* stat5 = (float*)(sb + 65536);       // 10240 f
  float* pqr   = (float*)(sb + 131072);      // 6144 f
  float* rmrn  = (float*)(sb + 1*MB);        // 2MB: 2 x (1024,256)
  bf16*  Wbbuf = (bf16*)(sb + 3*MB);         // 128KB: up_pw_w bf16
  bf16*  Wb2buf= (bf16*)(sb + 3*MB + 262144);// 128KB: down_pw_w bf16
  char* big = sb + 4*MB;
  float* pool4  = (float*)(big + 0*MB);      // 2 MB
  float* hbuf   = (float*)(big + 2*MB);      // 4 MB
  float* xzbuf  = (float*)(big + 6*MB);      // 16 MB
  float* ubuf   = (float*)(big + 22*MB);     // 8 MB
  float* dblbuf = (float*)(big + 30*MB);     // 768 KB
  float* dtbuf  = (float*)(big + 31*MB);     // 8 MB
  float* ybuf   = (float*)(big + 39*MB);     // 8 MB
  float* mout   = (float*)(big + 47*MB);     // 4 MB
  float* cbuf   = (float*)(big + 51*MB);     // 4 MB
  float* respre = (float*)(big + 55*MB);     // 2 MB  (ends at 57MB < 64MB)
  bf16*  z1buf  = (bf16*)(big);              // 64 MiB bf16, c-major (phase 2a)
  bf16*  z2buf  = (bf16*)(big);              // 64 MiB bf16 (phase 2b/3; z1 dead)
  bf16*  z1tbuf = (bf16*)(sb + 68*MB);       // 64 MiB bf16, p-major (phase 2)
  bf16*  rqtbuf = (bf16*)(sb + 68*MB);       // 16 MiB bf16, p-major (phase 3; z1t dead)
  float* dbuf   = (float*)d_out;             // 32 MB fp32 (phase 3)

  float* bn1sum = statz;        float* bn1sq = statz + 256;
  float* bn2sum = statz + 512;  float* bn2sq = statz + 768;
  float* gnsum  = statz + 1024; float* gnsq  = statz + 1280;
  float* abn1 = abn;       float* dbn1 = abn + 256;
  float* abn2 = abn + 512; float* dbn2 = abn + 768;
  float* gnA = gnAD;       float* gnD = gnAD + 2048;
  float* pcolmax = pool4;
  float* pcolmin = pool4 + 131072;
  float* prowmax = pool4 + 262144;
  float* prowmin = pool4 + 393216;

  hipMemsetAsync(statz, 0, 1536*sizeof(float), stream);

  // ---- phase 1: pooling + LN + mamba x4 (f/b x max/min) -> rmrn ----
  pool1_kernel<<<dim3(256, 8), 64, 0, stream>>>(x, pos, pcolmax, pcolmin, prowmax, prowmin);
  pool2_kernel<<<dim3(128, 8), 256, 0, stream>>>(pcolmax, pcolmin, prowmax, prowmin, ln_w, ln_b, hbuf);
  gemm_kernel<<<dim3(16, 16, 4), 256, 0, stream>>>(hbuf, 262144, 256, f_in_w, b_in_w, nullptr, nullptr, 2,
                                                   xzbuf, 1048576, 1024, 1024, 1024, 256, 0);
  conv1d_kernel<<<dim3(128, 8, 4), 512, 0, stream>>>(xzbuf, f_conv_w, f_conv_b, b_conv_w, b_conv_b, ubuf);
  gemm_kernel<<<dim3(1, 16, 4), 256, 0, stream>>>(ubuf, 524288, 512, f_xproj_w, b_xproj_w, nullptr, nullptr, 2,
                                                  dblbuf, 49152, 48, 1024, 48, 512, 0);
  gemm_kernel<<<dim3(8, 16, 4), 256, 0, stream>>>(dblbuf, 49152, 48, f_dt_w, b_dt_w, f_dt_b, b_dt_b, 2,
                                                  dtbuf, 524288, 512, 1024, 512, 16, 2);
  scan_kernel<<<dim3(8, 8, 4), 64, 0, stream>>>(dtbuf, ubuf, dblbuf, xzbuf, f_Alog, f_D, b_Alog, b_D, ybuf);
  gemm_kernel<<<dim3(4, 16, 4), 256, 0, stream>>>(ybuf, 524288, 512, f_out_w, b_out_w, nullptr, nullptr, 2,
                                                  mout, 262144, 256, 1024, 256, 512, 0);
  ln_kernel<<<dim3(128, 8, 4), 256, 0, stream>>>(mout, cbuf, cbuf + 524288, ln_w, ln_b, 1);
  gemm_kernel<<<dim3(4, 16, 2), 256, 0, stream>>>(cbuf, 524288, 512, proj_w, proj_w, proj_b, proj_b, 2,
                                                  respre, 262144, 256, 1024, 256, 512, 0);
  ln_kernel<<<dim3(128, 8, 2), 256, 0, stream>>>(respre, rmrn, nullptr, ln_w, ln_b, 0);

  // ---- phase 2: z path ----
  dwz1_kernel<<<2048, 256, 0, stream>>>(x, up_dw_w, z1buf, bn1sum, bn1sq);
  fin_bn_kernel<<<1, 256, 0, stream>>>(bn1sum, bn1sq, up_bn1_g, up_bn1_b, 1.f/131072.f, abn1, dbn1);
  wcvt_kernel<<<256, 256, 0, stream>>>(up_pw_w, Wbbuf, 65536);
  wcvt_kernel<<<256, 256, 0, stream>>>(down_pw_w, Wb2buf, 65536);
  actz1_kernel<<<dim3(256, 4, 8), 256, 0, stream>>>(z1buf, abn1, dbn1, z1tbuf);
  pwz_mfma_kernel<<<dim3(256, 8), 256, 0, stream>>>(z1tbuf, Wbbuf, z2buf);
  chstats_kernel<<<dim3(256, 8), 256, 0, stream>>>(z2buf, bn2sum, bn2sq);
  fin_bn_kernel<<<1, 256, 0, stream>>>(bn2sum, bn2sq, up_bn2_g, up_bn2_b, 1.f/131072.f, abn2, dbn2);

  // ---- phase 3: merge + tail ----
  hsig_kernel<<<dim3(256, 8), 256, 0, stream>>>(z2buf, rmrn, rmrn + 262144, abn2, dbn2, gnsum, gnsq);
  fin_gn_kernel<<<8, 256, 0, stream>>>(gnsum, gnsq, gn_g, gn_b, gnA, gnD);
  trd_kernel<<<dim3(64, 4, 8), 256, 0, stream>>>(z2buf, gnA, gnD, rqtbuf);
  pwdown_mfma_kernel<<<dim3(64, 8), 256, 0, stream>>>(rqtbuf, Wb2buf, dbuf);
  stat5_kernel<<<dim3(256, 8), 256, 0, stream>>>(dbuf, x, stat5);
  coeff_kernel<<<8, 256, 0, stream>>>(stat5, down_bn_g, down_bn_b, gn_g, gn_b, pqr);
  final_kernel<<<dim3(256, 8), 256, 0, stream>>>(x, pqr, (float*)d_out);
}

// Round 10
// 717.682 us; speedup vs baseline: 2.7236x; 1.0986x over previous
//
#include <hip/hip_runtime.h>
#include <hip/hip_bf16.h>

typedef __hip_bfloat16 bf16;
typedef __attribute__((ext_vector_type(8))) short bf16x8v;
typedef __attribute__((ext_vector_type(4))) float f32x4v;

#define B_ 8
#define C_ 256
#define L_ 128
#define MB 1048576UL

__device__ inline float b2f(bf16 v){ return __bfloat162float(v); }
__device__ inline bf16 f2b(float v){ return __float2bfloat16(v); }
__device__ inline float siluf(float x){ return x / (1.f + expf(-x)); }
__device__ inline float softplusf(float x){ return (x > 20.f) ? x : log1pf(expf(x)); }
__device__ inline float vclamp(float v){ return fmaxf(v, 0.f) + 1e-5f; }

// block = 256 threads. red must hold 512 floats.
__device__ inline void bred2(float& a, float& b, float* red){
  int t = threadIdx.x;
  __syncthreads();
  red[t] = a; red[256 + t] = b;
  __syncthreads();
  for (int off = 128; off > 0; off >>= 1){
    if (t < off){ red[t] += red[t + off]; red[256 + t] += red[256 + t + off]; }
    __syncthreads();
  }
  a = red[0]; b = red[256];
}
__device__ inline float bred1(float a, float* red){
  int t = threadIdx.x;
  __syncthreads();
  red[t] = a; __syncthreads();
  for (int off = 128; off > 0; off >>= 1){
    if (t < off) red[t] += red[t + off];
    __syncthreads();
  }
  return red[0];
}

// ---------------- pooling step 1: row/col max/min + argmax + pos-embed -------------
// grid (C, B), block 64
__global__ __launch_bounds__(64) void pool1_kernel(const float* __restrict__ x, const float* __restrict__ pos,
    float* __restrict__ pcolmax, float* __restrict__ pcolmin,
    float* __restrict__ prowmax, float* __restrict__ prowmin)
{
  int c = blockIdx.x, b = blockIdx.y, t = threadIdx.x;
  __shared__ float xs[64][65];
  const float* xp = x + ((long)(b*C_ + c))*4096;
  for (int i = 0; i < 64; i++) xs[i][t] = xp[i*64 + t];
  __syncthreads();
  // jax.image.resize 'linear' 16->64: half-pixel coords, edge clamp
  float tt = 0.25f*(float)t - 0.375f;
  const float* pp = pos + c*16;
  float pe;
  if (tt <= 0.f) pe = pp[0];
  else if (tt >= 15.f) pe = pp[15];
  else { int f = (int)floorf(tt); float w = tt - (float)f; pe = pp[f]*(1.f - w) + pp[f+1]*w; }
  float vmax = -1e30f, vmin = 1e30f; int amax = 0, amin = 0;
  for (int j = 0; j < 64; j++){
    float v = xs[t][j];
    if (v > vmax){ vmax = v; amax = j; }
    if (v < vmin){ vmin = v; amin = j; }
  }
  long o = (long)(b*64 + t)*C_ + c;
  prowmax[o] = vmax + pe + (float)amax;
  prowmin[o] = vmin + pe + (float)amin;
  vmax = -1e30f; vmin = 1e30f; amax = 0; amin = 0;
  for (int i = 0; i < 64; i++){
    float v = xs[i][t];
    if (v > vmax){ vmax = v; amax = i; }
    if (v < vmin){ vmin = v; amin = i; }
  }
  pcolmax[o] = vmax + pe + (float)amax;
  pcolmin[o] = vmin + pe + (float)amin;
}

// ---------------- pooling step 2: LN over channels, write 4 mamba inputs (bf16) ----
// grid (128, B), block 256
__global__ __launch_bounds__(256) void pool2_kernel(const float* __restrict__ pcolmax, const float* __restrict__ pcolmin,
    const float* __restrict__ prowmax, const float* __restrict__ prowmin,
    const float* __restrict__ lnw, const float* __restrict__ lnb, bf16* __restrict__ hbuf)
{
  int r = blockIdx.x, b = blockIdx.y, c = threadIdx.x;
  __shared__ float red[512];
  int p = r & 63;
  long src = (long)(b*64 + p)*C_ + c;
  float vmax = (r < 64) ? pcolmax[src] : prowmax[src];
  float vmin = (r < 64) ? pcolmin[src] : prowmin[src];
  float gw = lnw[c], gb = lnb[c];
  long row = (long)b*L_ + r, frow = (long)b*L_ + (127 - r);
  float s = vmax, s2 = vmax*vmax;
  bred2(s, s2, red);
  float m = s*(1.f/256.f), var = s2*(1.f/256.f) - m*m;
  float o = (vmax - m)*rsqrtf(vclamp(var))*gw + gb;
  hbuf[0*262144 + row*C_ + c]  = f2b(o);
  hbuf[2*262144 + frow*C_ + c] = f2b(o);
  s = vmin; s2 = vmin*vmin;
  bred2(s, s2, red);
  m = s*(1.f/256.f); var = s2*(1.f/256.f) - m*m;
  o = (vmin - m)*rsqrtf(vclamp(var))*gw + gb;
  hbuf[1*262144 + row*C_ + c]  = f2b(o);
  hbuf[3*262144 + frow*C_ + c] = f2b(o);
}

// ---------------- dwconvT on-the-fly helper ----------------------------------------
__device__ inline float dwconvT_at(const float* __restrict__ xp, const float* __restrict__ w, int i, int j)
{
  float acc = 0.f;
  #pragma unroll
  for (int ki = 0; ki < 3; ki++){
    int pi = i + ki - 1;
    if (pi < 0 || (pi & 1)) continue;
    int xi = pi >> 1;
    if (xi >= 64) continue;
    #pragma unroll
    for (int kj = 0; kj < 3; kj++){
      int pj = j + kj - 1;
      if (pj < 0 || (pj & 1)) continue;
      int xj = pj >> 1;
      if (xj >= 64) continue;
      acc += w[(2-ki)*3 + (2-kj)] * xp[xi*64 + xj];
    }
  }
  return acc;
}

// ---------------- z1raw = dwconvT(x) as bf16 + bn1 stats (one pass) ----------------
// x plane staged in LDS; coalesced bf16 stores. grid (B*C), block 256.
__global__ __launch_bounds__(256) void dwz1_kernel(const float* __restrict__ x, const float* __restrict__ dw,
    bf16* __restrict__ z1, float* __restrict__ bn1sum, float* __restrict__ bn1sq)
{
  int bc = blockIdx.x; int c = bc & 255;
  int tid = threadIdx.x;
  __shared__ float xs[4096];
  const float* xp = x + (long)bc*4096;
  for (int it = 0; it < 16; it++) xs[it*256 + tid] = xp[it*256 + tid];
  float w[9];
  #pragma unroll
  for (int q = 0; q < 9; q++) w[q] = dw[c*9 + q];
  __syncthreads();
  bf16* zp = z1 + (long)bc*16384;
  float s = 0.f, s2 = 0.f;
  for (int it = 0; it < 64; it++){
    int p = it*256 + tid; int i = p >> 7, j = p & 127;
    float acc = dwconvT_at(xs, w, i, j);
    zp[p] = f2b(acc);
    s += acc; s2 += acc*acc;
  }
  __shared__ float red[512];
  bred2(s, s2, red);
  if (tid == 0){ atomicAdd(&bn1sum[c], s); atomicAdd(&bn1sq[c], s2); }
}

// ---------------- bn finalize: per-channel affine ----------------------------------
__global__ void fin_bn_kernel(const float* __restrict__ sum, const float* __restrict__ sq,
                              const float* __restrict__ g, const float* __restrict__ b,
                              float cnt_inv, float* __restrict__ a, float* __restrict__ d)
{
  int c = threadIdx.x;
  float m = sum[c]*cnt_inv;
  float v = sq[c]*cnt_inv - m*m;
  float aa = g[c] * rsqrtf(vclamp(v));
  a[c] = aa;
  d[c] = b[c] - m*aa;
}

// ---------------- fp32 -> bf16 weight convert --------------------------------------
__global__ void wcvt_kernel(const float* __restrict__ W, bf16* __restrict__ Wb, int n)
{
  int i = blockIdx.x*256 + threadIdx.x;
  if (i < n) Wb[i] = f2b(W[i]);
}

// ---------------- actz1: z1t[b][p][c] = bf16(relu(fa[c]*z1[b,c,p]+fd[c])) ----------
// 64x64 transpose via LDS fp32 tile (bank-clean). grid (256, 4, B), block 256.
__global__ __launch_bounds__(256) void actz1_kernel(const bf16* __restrict__ z1,
    const float* __restrict__ fa, const float* __restrict__ fd, bf16* __restrict__ z1t)
{
  int p0 = blockIdx.x*64, c0 = blockIdx.y*64, b = blockIdx.z;
  int tid = threadIdx.x;
  __shared__ float t[64][65];
  #pragma unroll
  for (int q = 0; q < 2; q++){
    int cl = (tid >> 3) + q*32;
    int p8 = (tid & 7)*8;
    const bf16* src = &z1[((long)(b*C_ + c0 + cl))*16384 + p0 + p8];
    float a = fa[c0 + cl], d = fd[c0 + cl];
    bf16 v[8];
    *(uint4*)v = *(const uint4*)src;
    #pragma unroll
    for (int i = 0; i < 8; i++) t[p8 + i][cl] = fmaxf(b2f(v[i])*a + d, 0.f);
  }
  __syncthreads();
  #pragma unroll
  for (int q = 0; q < 2; q++){
    int pl = (tid >> 3) + q*32;
    int c8 = (tid & 7)*8;
    bf16 v[8];
    #pragma unroll
    for (int i = 0; i < 8; i++) v[i] = f2b(t[pl][c8 + i]);
    *(uint4*)&z1t[((long)b*16384 + p0 + pl)*256 + c0 + c8] = *(const uint4*)v;
  }
}

// ---------------- up-pw GEMM on MFMA: z2[b,o,p] = sum_c Wb[o,c]*z1t[b,p,c] ---------
// Block: M=256 x N=64 x K=256, 4 waves, wave handles 64 M rows; 4x4 16x16 acc tiles.
// grid (256, B), block 256.
__global__ __launch_bounds__(256) void pwz_mfma_kernel(const bf16* __restrict__ z1t,
    const bf16* __restrict__ Wb, bf16* __restrict__ z2)
{
  int b = blockIdx.y;
  int p0 = blockIdx.x*64;
  int tid = threadIdx.x;
  int wave = tid >> 6, lane = tid & 63;
  int quad = lane >> 4, l16 = lane & 15;
  const bf16* zb = z1t + (long)b*16384*256;
  f32x4v acc[4][4];
  #pragma unroll
  for (int i = 0; i < 4; i++)
    #pragma unroll
    for (int j = 0; j < 4; j++) acc[i][j] = (f32x4v){0.f, 0.f, 0.f, 0.f};
  for (int k0 = 0; k0 < 256; k0 += 32){
    int c = k0 + quad*8;
    bf16x8v a[4], bb[4];
    #pragma unroll
    for (int ms = 0; ms < 4; ms++)
      a[ms] = *(const bf16x8v*)&Wb[(wave*64 + ms*16 + l16)*C_ + c];
    #pragma unroll
    for (int ns = 0; ns < 4; ns++)
      bb[ns] = *(const bf16x8v*)&zb[((long)(p0 + ns*16 + l16))*C_ + c];
    #pragma unroll
    for (int ms = 0; ms < 4; ms++)
      #pragma unroll
      for (int ns = 0; ns < 4; ns++)
        acc[ms][ns] = __builtin_amdgcn_mfma_f32_16x16x32_bf16(a[ms], bb[ns], acc[ms][ns], 0, 0, 0);
  }
  #pragma unroll
  for (int ms = 0; ms < 4; ms++){
    int o = wave*64 + ms*16 + quad*4;
    #pragma unroll
    for (int r = 0; r < 4; r++){
      long rowbase = ((long)(b*C_ + o + r))*16384 + p0;
      #pragma unroll
      for (int ns = 0; ns < 4; ns++)
        z2[rowbase + ns*16 + l16] = f2b(acc[ms][ns][r]);
    }
  }
}

// ---------------- in_proj GEMM on MFMA: xz[v][m][n] = sum_k hb[v][m][k]*Wi[n][k] ---
// M=1024, N=1024, K=256. grid (16, 4, 4), block 256 (4 waves x 64 m-rows).
__global__ __launch_bounds__(256) void inproj_mfma_kernel(const bf16* __restrict__ hb,
    const bf16* __restrict__ Wif, const bf16* __restrict__ Wib2, float* __restrict__ xz)
{
  int v = blockIdx.z;
  int m0 = blockIdx.y*256, n0 = blockIdx.x*64;
  const bf16* A = hb + (long)v*262144;
  const bf16* W = (v >= 2) ? Wib2 : Wif;
  float* out = xz + (long)v*1048576;
  int tid = threadIdx.x;
  int wave = tid >> 6, lane = tid & 63;
  int quad = lane >> 4, l16 = lane & 15;
  f32x4v acc[4][4];
  #pragma unroll
  for (int i = 0; i < 4; i++)
    #pragma unroll
    for (int j = 0; j < 4; j++) acc[i][j] = (f32x4v){0.f, 0.f, 0.f, 0.f};
  for (int k0 = 0; k0 < 256; k0 += 32){
    int c = k0 + quad*8;
    bf16x8v a[4], bb[4];
    #pragma unroll
    for (int ms = 0; ms < 4; ms++)
      a[ms] = *(const bf16x8v*)&A[(long)(m0 + wave*64 + ms*16 + l16)*256 + c];
    #pragma unroll
    for (int ns = 0; ns < 4; ns++)
      bb[ns] = *(const bf16x8v*)&W[(long)(n0 + ns*16 + l16)*256 + c];
    #pragma unroll
    for (int ms = 0; ms < 4; ms++)
      #pragma unroll
      for (int ns = 0; ns < 4; ns++)
        acc[ms][ns] = __builtin_amdgcn_mfma_f32_16x16x32_bf16(a[ms], bb[ns], acc[ms][ns], 0, 0, 0);
  }
  #pragma unroll
  for (int ms = 0; ms < 4; ms++){
    int m = m0 + wave*64 + ms*16 + quad*4;
    #pragma unroll
    for (int r = 0; r < 4; r++){
      long rowbase = (long)(m + r)*1024 + n0;
      #pragma unroll
      for (int ns = 0; ns < 4; ns++)
        out[rowbase + ns*16 + l16] = acc[ms][ns][r];
    }
  }
}

// ---------------- per-channel stats of bf16 tensor (B,C,16384) ---------------------
// grid (C, B), block 256
__global__ __launch_bounds__(256) void chstats_kernel(const bf16* __restrict__ t,
                                                      float* __restrict__ sum, float* __restrict__ sq)
{
  int c = blockIdx.x, b = blockIdx.y, tid = threadIdx.x;
  const bf16* p = t + ((long)(b*C_ + c))*16384;
  float s = 0.f, s2 = 0.f;
  for (int it = 0; it < 64; it++){ float v = b2f(p[it*256 + tid]); s += v; s2 += v*v; }
  __shared__ float red[512];
  bred2(s, s2, red);
  if (tid == 0){ atomicAdd(&sum[c], s); atomicAdd(&sq[c], s2); }
}

// ---------------- generic GEMM: C[m,n] = act(sum_k A[m,k] W[n,k] + bias[n]) --------
// A fp32 (lda, batch stride sA), W fp32 (N,K) row-major, batched over grid.z.
// grid ((N+63)/64, (M+63)/64, nbatch), block 256
__global__ __launch_bounds__(256) void gemm_kernel(
  const float* __restrict__ Abase, long sA, int lda,
  const float* __restrict__ W0, const float* __restrict__ W1,
  const float* __restrict__ bias0, const float* __restrict__ bias1, int wsplit,
  float* __restrict__ Cbase, long sC, int ldc,
  int M, int N, int K, int act)
{
  int z = blockIdx.z;
  const float* A = Abase + (long)z*sA;
  float* Cp = Cbase + (long)z*sC;
  const float* W = (z >= wsplit) ? W1 : W0;
  const float* bias = (z >= wsplit) ? bias1 : bias0;
  int m0 = blockIdx.y*64, n0 = blockIdx.x*64;
  __shared__ __align__(16) float As[16][68];
  __shared__ __align__(16) float Ws[16][68];
  int tid = threadIdx.x, tx = tid & 15, ty = tid >> 4;
  float acc[4][4] = {};
  for (int k0 = 0; k0 < K; k0 += 16){
    #pragma unroll
    for (int q = 0; q < 4; q++){
      int e = tid + q*256; int r = e >> 4, kk = e & 15;
      int mi = m0 + r, ki = k0 + kk;
      As[kk][r] = (mi < M && ki < K) ? A[(long)mi*lda + ki] : 0.f;
    }
    #pragma unroll
    for (int q = 0; q < 4; q++){
      int e = tid + q*256; int n = e >> 4, kk = e & 15;
      int ni = n0 + n, ki = k0 + kk;
      Ws[kk][n] = (ni < N && ki < K) ? W[(long)ni*K + ki] : 0.f;
    }
    __syncthreads();
    #pragma unroll
    for (int kk = 0; kk < 16; kk++){
      float4 a4 = *(const float4*)&As[kk][ty*4];
      float4 b4 = *(const float4*)&Ws[kk][tx*4];
      float av[4] = {a4.x, a4.y, a4.z, a4.w};
      float bv[4] = {b4.x, b4.y, b4.z, b4.w};
      #pragma unroll
      for (int mm = 0; mm < 4; mm++)
        #pragma unroll
        for (int nn = 0; nn < 4; nn++) acc[mm][nn] += av[mm]*bv[nn];
    }
    __syncthreads();
  }
  #pragma unroll
  for (int mm = 0; mm < 4; mm++){
    int mi = m0 + ty*4 + mm;
    if (mi >= M) continue;
    #pragma unroll
    for (int nn = 0; nn < 4; nn++){
      int ni = n0 + tx*4 + nn;
      if (ni >= N) continue;
      float v = acc[mm][nn];
      if (bias) v += bias[ni];
      if (act == 2) v = softplusf(v);
      Cp[(long)mi*ldc + ni] = v;
    }
  }
}

// ---------------- depthwise causal conv1d (k=4) + silu -----------------------------
// grid (L, B, 4), block 512
__global__ __launch_bounds__(512) void conv1d_kernel(const float* __restrict__ xzb,
    const float* __restrict__ fw, const float* __restrict__ fb,
    const float* __restrict__ bw, const float* __restrict__ bb,
    float* __restrict__ ub)
{
  int l = blockIdx.x, b = blockIdx.y, v = blockIdx.z, d = threadIdx.x;
  const float* xm = xzb + (long)v*1024*1024;
  const float* w  = (v < 2) ? fw : bw;
  const float* cb = (v < 2) ? fb : bb;
  float acc = cb[d];
  #pragma unroll
  for (int k = 0; k < 4; k++){
    int ll = l - 3 + k;
    if (ll >= 0) acc += xm[(long)(b*L_ + ll)*1024 + d] * w[d*4 + k];
  }
  ub[(long)v*1024*512 + (long)(b*L_ + l)*512 + d] = siluf(acc);
}

// ---------------- selective scan (ALL inputs staged to LDS; no in-loop globals) ----
// One wave per block, 256 blocks. Bulk-stage dt/u/zg (bf16) + B/C (bf16) to LDS
// with a throughput-pipelined coalesced loop, then run the 128-step recurrence
// entirely out of LDS (lane-contiguous, conflict-free).
// grid (8, B, 4), block 64 : thread = one (b,d), d = bx*64 + lane
__global__ __launch_bounds__(64) void scan_kernel(const float* __restrict__ dtb, const float* __restrict__ ub,
    const float* __restrict__ dblb, const float* __restrict__ xzb,
    const float* __restrict__ fAlog, const float* __restrict__ fD,
    const float* __restrict__ bAlog, const float* __restrict__ bD,
    float* __restrict__ yb)
{
  int v = blockIdx.z, b = blockIdx.y;
  int tid = threadIdx.x;
  int d = blockIdx.x*64 + tid;
  const float* dt  = dtb  + (long)v*1024*512;
  const float* u   = ub   + (long)v*1024*512;
  const float* dbl = dblb + (long)v*1024*48;
  const float* zg  = xzb  + (long)v*1024*1024 + 512;
  const float* Alog = (v < 2) ? fAlog : bAlog;
  const float* Dp   = (v < 2) ? fD : bD;
  __shared__ bf16 sdt[8192], su[8192], szg[8192];  // [l][lane]
  __shared__ bf16 sbc[4096];                        // [l][0..15]=B, [16..31]=C
  long row = (long)b*L_;
  #pragma unroll 8
  for (int l = 0; l < 128; l++){
    sdt[l*64 + tid] = f2b(dt[(row + l)*512 + d]);
    su [l*64 + tid] = f2b(u [(row + l)*512 + d]);
    szg[l*64 + tid] = f2b(zg[(row + l)*1024 + d]);
  }
  #pragma unroll 8
  for (int idx = tid; idx < 4096; idx += 64){
    int l = idx >> 5, i = idx & 31;
    sbc[idx] = f2b(dbl[(row + l)*48 + 16 + i]);
  }
  float a2[16];
  #pragma unroll
  for (int n = 0; n < 16; n++) a2[n] = -expf(Alog[d*16 + n]) * 1.44269504f;
  float Dv = Dp[d];
  float h[16];
  #pragma unroll
  for (int n = 0; n < 16; n++) h[n] = 0.f;
  __syncthreads();
  float* yo = yb + (long)v*1024*512;
  for (int l = 0; l < 128; l++){
    float dtv = b2f(sdt[l*64 + tid]);
    float uv  = b2f(su [l*64 + tid]);
    float zgv = b2f(szg[l*64 + tid]);
    float dtu = dtv*uv;
    float acc = 0.f;
    const bf16* Bm = &sbc[l*32];
    #pragma unroll
    for (int n = 0; n < 16; n++){
      float dA = exp2f(dtv*a2[n]);
      h[n] = dA*h[n] + dtu*b2f(Bm[n]);
      acc += h[n]*b2f(Bm[16 + n]);
    }
    yo[(row + l)*512 + d] = (acc + Dv*uv) * siluf(zgv);
  }
}

// ---------------- LayerNorm over C, two output modes -------------------------------
// grid (128, B, NV), block 256
__global__ __launch_bounds__(256) void ln_kernel(const float* __restrict__ inb, float* __restrict__ out0,
    float* __restrict__ out1, const float* __restrict__ lnw, const float* __restrict__ lnb, int mode)
{
  int r = blockIdx.x, b = blockIdx.y, v = blockIdx.z, c = threadIdx.x;
  long row = (long)b*L_ + r;
  float val = inb[((long)v*1024 + row)*C_ + c];
  __shared__ float red[512];
  float s = val, s2 = val*val;
  bred2(s, s2, red);
  float m = s*(1.f/256.f), var = s2*(1.f/256.f) - m*m;
  float o = (val - m)*rsqrtf(vclamp(var))*lnw[c] + lnb[c];
  if (mode == 1){
    long frow = (long)b*L_ + (127 - r);
    if (v == 0)      out0[row*512 + c] = o;
    else if (v == 1) out1[row*512 + c] = o;
    else if (v == 2) out0[frow*512 + 256 + c] = o;
    else             out1[frow*512 + 256 + c] = o;
  } else {
    out0[((long)v*1024 + row)*C_ + c] = o;
  }
}

// ---------------- hsig(rm+rn)*clip(bn2(z2)) + gn stats; resq IN-PLACE in z2 --------
// grid (C, B), block 256
__global__ __launch_bounds__(256) void hsig_kernel(bf16* __restrict__ z2, const float* __restrict__ rm,
    const float* __restrict__ rn, const float* __restrict__ a2, const float* __restrict__ d2,
    float* __restrict__ gnsum, float* __restrict__ gnsq)
{
  int c = blockIdx.x, b = blockIdx.y, tid = threadIdx.x;
  __shared__ float rms[128], rns[128];
  if (tid < 128){
    rms[tid] = rm[(long)(b*L_ + tid)*C_ + c];
    rns[tid] = rn[(long)(b*L_ + tid)*C_ + c];
  }
  __syncthreads();
  float aa = a2[c], dd = d2[c];
  bf16* zp = z2 + ((long)(b*C_ + c))*16384;
  float s = 0.f, s2 = 0.f;
  for (int g = 0; g < 16; g++){
    float tv[4]; int wq[4];
    #pragma unroll
    for (int q = 0; q < 4; q++){
      int p = g*1024 + q*256 + tid; int i = p >> 7, j = p & 127;
      float zv = b2f(zp[p])*aa + dd;
      zv = fminf(fmaxf(zv, 0.f), 6.f);
      float gate = rms[i] + rns[j];
      gate = fminf(fmaxf(gate + 3.f, 0.f), 6.f) * (1.f/6.f);
      float t = gate*zv;
      s += t; s2 += t*t;
      tv[q] = t;
      wq[q] = (((i | j) & 1) == 0) ? ((i >> 1)*64 + (j >> 1)) : -1;
    }
    __syncthreads();
    #pragma unroll
    for (int q = 0; q < 4; q++)
      if (wq[q] >= 0) zp[wq[q]] = f2b(tv[q]);
  }
  __shared__ float red[512];
  bred2(s, s2, red);
  if (tid == 0){ atomicAdd(&gnsum[b*32 + (c >> 3)], s); atomicAdd(&gnsq[b*32 + (c >> 3)], s2); }
}

// ---------------- gn finalize to per-(b,c) affine ----------------------------------
// grid (B), block 256
__global__ void fin_gn_kernel(const float* __restrict__ gnsum, const float* __restrict__ gnsq,
                              const float* __restrict__ g, const float* __restrict__ bb,
                              float* __restrict__ gnA, float* __restrict__ gnD)
{
  int b = blockIdx.x, c = threadIdx.x, gr = c >> 3;
  float inv_cnt = 1.f/131072.f;
  float m = gnsum[b*32 + gr]*inv_cnt;
  float v = gnsq[b*32 + gr]*inv_cnt - m*m;
  float inv = rsqrtf(vclamp(v));
  float A = inv*g[c];
  gnA[b*C_ + c] = A;
  gnD[b*C_ + c] = bb[c] - m*A;
}

// ---------------- trd: rqt[b][s][c] = bf16(gnA*resq[b,c,s]+gnD) --------------------
// resq rows strided 16384 (in-place inside z2); 64x64 LDS transpose.
// grid (64, 4, B), block 256.
__global__ __launch_bounds__(256) void trd_kernel(const bf16* __restrict__ z2,
    const float* __restrict__ gnA, const float* __restrict__ gnD, bf16* __restrict__ rqt)
{
  int p0 = blockIdx.x*64, c0 = blockIdx.y*64, b = blockIdx.z;
  int tid = threadIdx.x;
  __shared__ float t[64][65];
  #pragma unroll
  for (int q = 0; q < 2; q++){
    int cl = (tid >> 3) + q*32;
    int p8 = (tid & 7)*8;
    int c = c0 + cl;
    const bf16* src = &z2[((long)(b*C_ + c))*16384 + p0 + p8];
    float a = gnA[b*C_ + c], dd = gnD[b*C_ + c];
    bf16 v[8];
    *(uint4*)v = *(const uint4*)src;
    #pragma unroll
    for (int i = 0; i < 8; i++) t[p8 + i][cl] = b2f(v[i])*a + dd;
  }
  __syncthreads();
  #pragma unroll
  for (int q = 0; q < 2; q++){
    int pl = (tid >> 3) + q*32;
    int c8 = (tid & 7)*8;
    bf16 v[8];
    #pragma unroll
    for (int i = 0; i < 8; i++) v[i] = f2b(t[pl][c8 + i]);
    *(uint4*)&rqt[((long)b*4096 + p0 + pl)*256 + c0 + c8] = *(const uint4*)v;
  }
}

// ---------------- down-pw GEMM on MFMA: d[b,o,s] = sum_c Wb[o,c]*rqt[b,s,c] --------
// Same structure as pwz_mfma; fp32 output to d_out (stride 4096). grid (64, B).
__global__ __launch_bounds__(256) void pwdown_mfma_kernel(const bf16* __restrict__ rqt,
    const bf16* __restrict__ Wb, float* __restrict__ out)
{
  int b = blockIdx.y;
  int p0 = blockIdx.x*64;
  int tid = threadIdx.x;
  int wave = tid >> 6, lane = tid & 63;
  int quad = lane >> 4, l16 = lane & 15;
  const bf16* zb = rqt + (long)b*4096*256;
  f32x4v acc[4][4];
  #pragma unroll
  for (int i = 0; i < 4; i++)
    #pragma unroll
    for (int j = 0; j < 4; j++) acc[i][j] = (f32x4v){0.f, 0.f, 0.f, 0.f};
  for (int k0 = 0; k0 < 256; k0 += 32){
    int c = k0 + quad*8;
    bf16x8v a[4], bb[4];
    #pragma unroll
    for (int ms = 0; ms < 4; ms++)
      a[ms] = *(const bf16x8v*)&Wb[(wave*64 + ms*16 + l16)*C_ + c];
    #pragma unroll
    for (int ns = 0; ns < 4; ns++)
      bb[ns] = *(const bf16x8v*)&zb[((long)(p0 + ns*16 + l16))*C_ + c];
    #pragma unroll
    for (int ms = 0; ms < 4; ms++)
      #pragma unroll
      for (int ns = 0; ns < 4; ns++)
        acc[ms][ns] = __builtin_amdgcn_mfma_f32_16x16x32_bf16(a[ms], bb[ns], acc[ms][ns], 0, 0, 0);
  }
  #pragma unroll
  for (int ms = 0; ms < 4; ms++){
    int o = wave*64 + ms*16 + quad*4;
    #pragma unroll
    for (int r = 0; r < 4; r++){
      long rowbase = ((long)(b*C_ + o + r))*4096 + p0;
      #pragma unroll
      for (int ns = 0; ns < 4; ns++)
        out[rowbase + ns*16 + l16] = acc[ms][ns][r];
    }
  }
}

// ---------------- 5 moments per (b,c): sum d, d^2, x, x^2, dx ----------------------
// grid (C, B), block 256
__global__ __launch_bounds__(256) void stat5_kernel(const float* __restrict__ dbuf, const float* __restrict__ x,
                                                    float* __restrict__ s5)
{
  int c = blockIdx.x, b = blockIdx.y, tid = threadIdx.x;
  const float* dp = dbuf + ((long)(b*C_ + c))*4096;
  const float* xp = x + ((long)(b*C_ + c))*4096;
  float sd = 0, sd2 = 0, sx = 0, sx2 = 0, sdx = 0;
  for (int it = 0; it < 16; it++){
    float d = dp[it*256 + tid];
    float xv = xp[it*256 + tid];
    sd += d; sd2 += d*d; sx += xv; sx2 += xv*xv; sdx += d*xv;
  }
  __shared__ float red[256];
  float r0 = bred1(sd, red); float r1 = bred1(sd2, red); float r2 = bred1(sx, red);
  float r3 = bred1(sx2, red); float r4 = bred1(sdx, red);
  if (tid == 0){
    float* o = s5 + (long)(b*C_ + c)*5;
    o[0] = r0; o[1] = r1; o[2] = r2; o[3] = r3; o[4] = r4;
  }
}

// ---------------- collapse bn -> gn -> (+x) -> gn into out = P*d + Q*x + R ---------
// grid (B), block 256
__global__ void coeff_kernel(const float* __restrict__ s5, const float* __restrict__ dbn_g, const float* __restrict__ dbn_b,
                             const float* __restrict__ gn_g, const float* __restrict__ gn_b, float* __restrict__ pqr)
{
  int b = blockIdx.x, c = threadIdx.x, g = c >> 3;
  float sd = 0, sd2 = 0;
  for (int bb = 0; bb < 8; bb++){ sd += s5[(long)(bb*C_ + c)*5 + 0]; sd2 += s5[(long)(bb*C_ + c)*5 + 1]; }
  float inv_cnt = 1.f/32768.f;
  float mB = sd*inv_cnt;
  float vB = sd2*inv_cnt - mB*mB;
  float ab = dbn_g[c] * rsqrtf(vclamp(vB));
  float db = dbn_b[c] - mB*ab;
  const float* s = s5 + (long)(b*C_ + c)*5;
  float inv_n = 1.f/4096.f;
  float m = s[0]*inv_n, Ed2 = s[1]*inv_n, mx = s[2]*inv_n, Ex2 = s[3]*inv_n, Edx = s[4]*inv_n;
  float Ev = ab*m + db;
  float Ev2 = ab*ab*Ed2 + 2.f*ab*db*m + db*db;
  __shared__ float e1[256], e2[256];
  e1[c] = Ev; e2[c] = Ev2;
  __syncthreads();
  float m1 = 0, q1 = 0;
  for (int k = 0; k < 8; k++){ m1 += e1[(g << 3) + k]; q1 += e2[(g << 3) + k]; }
  m1 *= 0.125f; q1 *= 0.125f;
  float inv1 = rsqrtf(vclamp(q1 - m1*m1));
  float gg = gn_g[c];
  float A1 = inv1*gg;
  float D1 = gn_b[c] - m1*A1;
  float al = A1*ab;
  float be = A1*db + D1;
  float Et = al*m + be + mx;
  float Et2 = al*al*Ed2 + 2.f*al*be*m + be*be + 2.f*al*Edx + 2.f*be*mx + Ex2;
  __syncthreads();
  e1[c] = Et; e2[c] = Et2;
  __syncthreads();
  float m2 = 0, q2 = 0;
  for (int k = 0; k < 8; k++){ m2 += e1[(g << 3) + k]; q2 += e2[(g << 3) + k]; }
  m2 *= 0.125f; q2 *= 0.125f;
  float inv2 = rsqrtf(vclamp(q2 - m2*m2));
  float G = inv2*gg;
  float* o = pqr + (long)(b*C_ + c)*3;
  o[0] = G*al;
  o[1] = G;
  o[2] = G*(be - m2) + gn_b[c];
}

// ---------------- final elementwise: out = P*out + Q*x + R (in-place on d_out) -----
// grid (C, B), block 256
__global__ __launch_bounds__(256) void final_kernel(const float* __restrict__ x,
    const float* __restrict__ pqr, float* __restrict__ out)
{
  int c = blockIdx.x, b = blockIdx.y, tid = threadIdx.x;
  const float* o = pqr + (long)(b*C_ + c)*3;
  float P = o[0], Q = o[1], R = o[2];
  long base = ((long)(b*C_ + c))*4096;
  for (int it = 0; it < 16; it++){
    long idx = base + it*256 + tid;
    out[idx] = P*out[idx] + Q*x[idx] + R;
  }
}

extern "C" void kernel_launch(void* const* d_in, const int* in_sizes, int n_in,
                              void* d_out, int out_size, void* d_ws, size_t ws_size,
                              hipStream_t stream)
{
  (void)in_sizes; (void)n_in; (void)out_size; (void)ws_size;
  // ALL inputs/outputs are float32.
  const float* x         = (const float*)d_in[0];
  const float* pos       = (const float*)d_in[1];
  const float* ln_w      = (const float*)d_in[2];
  const float* ln_b      = (const float*)d_in[3];
  const float* proj_w    = (const float*)d_in[4];
  const float* proj_b    = (const float*)d_in[5];
  const float* up_dw_w   = (const float*)d_in[6];
  const float* up_bn1_g  = (const float*)d_in[7];
  const float* up_bn1_b  = (const float*)d_in[8];
  const float* up_pw_w   = (const float*)d_in[9];
  const float* up_bn2_g  = (const float*)d_in[10];
  const float* up_bn2_b  = (const float*)d_in[11];
  const float* down_pw_w = (const float*)d_in[12];
  const float* down_bn_g = (const float*)d_in[13];
  const float* down_bn_b = (const float*)d_in[14];
  const float* gn_g      = (const float*)d_in[15];
  const float* gn_b      = (const float*)d_in[16];
  const float* f_in_w    = (const float*)d_in[17];
  const float* f_conv_w  = (const float*)d_in[18];
  const float* f_conv_b  = (const float*)d_in[19];
  const float* f_xproj_w = (const float*)d_in[20];
  const float* f_dt_w    = (const float*)d_in[21];
  const float* f_dt_b    = (const float*)d_in[22];
  const float* f_Alog    = (const float*)d_in[23];
  const float* f_D       = (const float*)d_in[24];
  const float* f_out_w   = (const float*)d_in[25];
  const float* b_in_w    = (const float*)d_in[26];
  const float* b_conv_w  = (const float*)d_in[27];
  const float* b_conv_b  = (const float*)d_in[28];
  const float* b_xproj_w = (const float*)d_in[29];
  const float* b_dt_w    = (const float*)d_in[30];
  const float* b_dt_b    = (const float*)d_in[31];
  const float* b_Alog    = (const float*)d_in[32];
  const float* b_D       = (const float*)d_in[33];
  const float* b_out_w   = (const float*)d_in[34];

  // ======== workspace layout, PEAK = 132MB ========
  char* sb = (char*)d_ws;
  float* statz = (float*)(sb);               // 1536 f (zeroed each launch)
  float* abn   = (float*)(sb + 8192);        // 1024 f
  float* gnAD  = (float*)(sb + 16384);       // 4096 f
  float* stat5 = (float*)(sb + 65536);       // 10240 f
  float* pqr   = (float*)(sb + 131072);      // 6144 f
  float* rmrn  = (float*)(sb + 1*MB);        // 2MB: 2 x (1024,256)
  bf16*  Wbbuf = (bf16*)(sb + 3*MB);         // 128KB: up_pw_w bf16
  bf16*  Wb2buf= (bf16*)(sb + 3*MB + 262144);// 128KB: down_pw_w bf16
  char* big = sb + 4*MB;
  float* pool4  = (float*)(big + 0*MB);      // 2 MB
  bf16*  hbufb  = (bf16*)(big + 2*MB);       // 2 MB: 4 x (B*L,C) bf16
  bf16*  Wif    = (bf16*)(big + 4*MB);       // 512KB: f_in_w bf16
  bf16*  Wib2   = (bf16*)(big + 4*MB + 524288); // 512KB: b_in_w bf16
  float* xzbuf  = (float*)(big + 6*MB);      // 16 MB
  float* ubuf   = (float*)(big + 22*MB);     // 8 MB
  float* dblbuf = (float*)(big + 30*MB);     // 768 KB
  float* dtbuf  = (float*)(big + 31*MB);     // 8 MB
  float* ybuf   = (float*)(big + 39*MB);     // 8 MB
  float* mout   = (float*)(big + 47*MB);     // 4 MB
  float* cbuf   = (float*)(big + 51*MB);     // 4 MB
  float* respre = (float*)(big + 55*MB);     // 2 MB  (ends at 57MB < 64MB)
  bf16*  z1buf  = (bf16*)(big);              // 64 MiB bf16, c-major (phase 2a)
  bf16*  z2buf  = (bf16*)(big);              // 64 MiB bf16 (phase 2b/3; z1 dead)
  bf16*  z1tbuf = (bf16*)(sb + 68*MB);       // 64 MiB bf16, p-major (phase 2)
  bf16*  rqtbuf = (bf16*)(sb + 68*MB);       // 16 MiB bf16, p-major (phase 3; z1t dead)
  float* dbuf   = (float*)d_out;             // 32 MB fp32 (phase 3)

  float* bn1sum = statz;        float* bn1sq = statz + 256;
  float* bn2sum = statz + 512;  float* bn2sq = statz + 768;
  float* gnsum  = statz + 1024; float* gnsq  = statz + 1280;
  float* abn1 = abn;       float* dbn1 = abn + 256;
  float* abn2 = abn + 512; float* dbn2 = abn + 768;
  float* gnA = gnAD;       float* gnD = gnAD + 2048;
  float* pcolmax = pool4;
  float* pcolmin = pool4 + 131072;
  float* prowmax = pool4 + 262144;
  float* prowmin = pool4 + 393216;

  hipMemsetAsync(statz, 0, 1536*sizeof(float), stream);

  // ---- phase 1: pooling + LN + mamba x4 (f/b x max/min) -> rmrn ----
  pool1_kernel<<<dim3(256, 8), 64, 0, stream>>>(x, pos, pcolmax, pcolmin, prowmax, prowmin);
  pool2_kernel<<<dim3(128, 8), 256, 0, stream>>>(pcolmax, pcolmin, prowmax, prowmin, ln_w, ln_b, hbufb);
  wcvt_kernel<<<1024, 256, 0, stream>>>(f_in_w, Wif, 262144);
  wcvt_kernel<<<1024, 256, 0, stream>>>(b_in_w, Wib2, 262144);
  inproj_mfma_kernel<<<dim3(16, 4, 4), 256, 0, stream>>>(hbufb, Wif, Wib2, xzbuf);
  conv1d_kernel<<<dim3(128, 8, 4), 512, 0, stream>>>(xzbuf, f_conv_w, f_conv_b, b_conv_w, b_conv_b, ubuf);
  gemm_kernel<<<dim3(1, 16, 4), 256, 0, stream>>>(ubuf, 524288, 512, f_xproj_w, b_xproj_w, nullptr, nullptr, 2,
                                                  dblbuf, 49152, 48, 1024, 48, 512, 0);
  gemm_kernel<<<dim3(8, 16, 4), 256, 0, stream>>>(dblbuf, 49152, 48, f_dt_w, b_dt_w, f_dt_b, b_dt_b, 2,
                                                  dtbuf, 524288, 512, 1024, 512, 16, 2);
  scan_kernel<<<dim3(8, 8, 4), 64, 0, stream>>>(dtbuf, ubuf, dblbuf, xzbuf, f_Alog, f_D, b_Alog, b_D, ybuf);
  gemm_kernel<<<dim3(4, 16, 4), 256, 0, stream>>>(ybuf, 524288, 512, f_out_w, b_out_w, nullptr, nullptr, 2,
                                                  mout, 262144, 256, 1024, 256, 512, 0);
  ln_kernel<<<dim3(128, 8, 4), 256, 0, stream>>>(mout, cbuf, cbuf + 524288, ln_w, ln_b, 1);
  gemm_kernel<<<dim3(4, 16, 2), 256, 0, stream>>>(cbuf, 524288, 512, proj_w, proj_w, proj_b, proj_b, 2,
                                                  respre, 262144, 256, 1024, 256, 512, 0);
  ln_kernel<<<dim3(128, 8, 2), 256, 0, stream>>>(respre, rmrn, nullptr, ln_w, ln_b, 0);

  // ---- phase 2: z path ----
  dwz1_kernel<<<2048, 256, 0, stream>>>(x, up_dw_w, z1buf, bn1sum, bn1sq);
  fin_bn_kernel<<<1, 256, 0, stream>>>(bn1sum, bn1sq, up_bn1_g, up_bn1_b, 1.f/131072.f, abn1, dbn1);
  wcvt_kernel<<<256, 256, 0, stream>>>(up_pw_w, Wbbuf, 65536);
  wcvt_kernel<<<256, 256, 0, stream>>>(down_pw_w, Wb2buf, 65536);
  actz1_kernel<<<dim3(256, 4, 8), 256, 0, stream>>>(z1buf, abn1, dbn1, z1tbuf);
  pwz_mfma_kernel<<<dim3(256, 8), 256, 0, stream>>>(z1tbuf, Wbbuf, z2buf);
  chstats_kernel<<<dim3(256, 8), 256, 0, stream>>>(z2buf, bn2sum, bn2sq);
  fin_bn_kernel<<<1, 256, 0, stream>>>(bn2sum, bn2sq, up_bn2_g, up_bn2_b, 1.f/131072.f, abn2, dbn2);

  // ---- phase 3: merge + tail ----
  hsig_kernel<<<dim3(256, 8), 256, 0, stream>>>(z2buf, rmrn, rmrn + 262144, abn2, dbn2, gnsum, gnsq);
  fin_gn_kernel<<<8, 256, 0, stream>>>(gnsum, gnsq, gn_g, gn_b, gnA, gnD);
  trd_kernel<<<dim3(64, 4, 8), 256, 0, stream>>>(z2buf, gnA, gnD, rqtbuf);
  pwdown_mfma_kernel<<<dim3(64, 8), 256, 0, stream>>>(rqtbuf, Wb2buf, dbuf);
  stat5_kernel<<<dim3(256, 8), 256, 0, stream>>>(dbuf, x, stat5);
  coeff_kernel<<<8, 256, 0, stream>>>(stat5, down_bn_g, down_bn_b, gn_g, gn_b, pqr);
  final_kernel<<<dim3(256, 8), 256, 0, stream>>>(x, pqr, (float*)d_out);
}

// Round 11
// 620.051 us; speedup vs baseline: 3.1525x; 1.1575x over previous
//
#include <hip/hip_runtime.h>
#include <hip/hip_bf16.h>

typedef __hip_bfloat16 bf16;
typedef __attribute__((ext_vector_type(8))) short bf16x8v;
typedef __attribute__((ext_vector_type(4))) float f32x4v;

#define B_ 8
#define C_ 256
#define L_ 128
#define MB 1048576UL

__device__ inline float b2f(bf16 v){ return __bfloat162float(v); }
__device__ inline bf16 f2b(float v){ return __float2bfloat16(v); }
__device__ inline float siluf(float x){ return x / (1.f + expf(-x)); }
__device__ inline float softplusf(float x){ return (x > 20.f) ? x : log1pf(expf(x)); }
__device__ inline float vclamp(float v){ return fmaxf(v, 0.f) + 1e-5f; }

// block = 256 threads. red must hold 512 floats.
__device__ inline void bred2(float& a, float& b, float* red){
  int t = threadIdx.x;
  __syncthreads();
  red[t] = a; red[256 + t] = b;
  __syncthreads();
  for (int off = 128; off > 0; off >>= 1){
    if (t < off){ red[t] += red[t + off]; red[256 + t] += red[256 + t + off]; }
    __syncthreads();
  }
  a = red[0]; b = red[256];
}
__device__ inline float bred1(float a, float* red){
  int t = threadIdx.x;
  __syncthreads();
  red[t] = a; __syncthreads();
  for (int off = 128; off > 0; off >>= 1){
    if (t < off) red[t] += red[t + off];
    __syncthreads();
  }
  return red[0];
}

// ---------------- pooling step 1: row/col max/min + argmax + pos-embed -------------
// grid (C, B), block 64
__global__ __launch_bounds__(64) void pool1_kernel(const float* __restrict__ x, const float* __restrict__ pos,
    float* __restrict__ pcolmax, float* __restrict__ pcolmin,
    float* __restrict__ prowmax, float* __restrict__ prowmin)
{
  int c = blockIdx.x, b = blockIdx.y, t = threadIdx.x;
  __shared__ float xs[64][65];
  const float* xp = x + ((long)(b*C_ + c))*4096;
  for (int i = 0; i < 64; i++) xs[i][t] = xp[i*64 + t];
  __syncthreads();
  // jax.image.resize 'linear' 16->64: half-pixel coords, edge clamp
  float tt = 0.25f*(float)t - 0.375f;
  const float* pp = pos + c*16;
  float pe;
  if (tt <= 0.f) pe = pp[0];
  else if (tt >= 15.f) pe = pp[15];
  else { int f = (int)floorf(tt); float w = tt - (float)f; pe = pp[f]*(1.f - w) + pp[f+1]*w; }
  float vmax = -1e30f, vmin = 1e30f; int amax = 0, amin = 0;
  for (int j = 0; j < 64; j++){
    float v = xs[t][j];
    if (v > vmax){ vmax = v; amax = j; }
    if (v < vmin){ vmin = v; amin = j; }
  }
  long o = (long)(b*64 + t)*C_ + c;
  prowmax[o] = vmax + pe + (float)amax;
  prowmin[o] = vmin + pe + (float)amin;
  vmax = -1e30f; vmin = 1e30f; amax = 0; amin = 0;
  for (int i = 0; i < 64; i++){
    float v = xs[i][t];
    if (v > vmax){ vmax = v; amax = i; }
    if (v < vmin){ vmin = v; amin = i; }
  }
  pcolmax[o] = vmax + pe + (float)amax;
  pcolmin[o] = vmin + pe + (float)amin;
}

// ---------------- pooling step 2: LN over channels, write 4 mamba inputs (bf16) ----
// grid (128, B), block 256
__global__ __launch_bounds__(256) void pool2_kernel(const float* __restrict__ pcolmax, const float* __restrict__ pcolmin,
    const float* __restrict__ prowmax, const float* __restrict__ prowmin,
    const float* __restrict__ lnw, const float* __restrict__ lnb, bf16* __restrict__ hbuf)
{
  int r = blockIdx.x, b = blockIdx.y, c = threadIdx.x;
  __shared__ float red[512];
  int p = r & 63;
  long src = (long)(b*64 + p)*C_ + c;
  float vmax = (r < 64) ? pcolmax[src] : prowmax[src];
  float vmin = (r < 64) ? pcolmin[src] : prowmin[src];
  float gw = lnw[c], gb = lnb[c];
  long row = (long)b*L_ + r, frow = (long)b*L_ + (127 - r);
  float s = vmax, s2 = vmax*vmax;
  bred2(s, s2, red);
  float m = s*(1.f/256.f), var = s2*(1.f/256.f) - m*m;
  float o = (vmax - m)*rsqrtf(vclamp(var))*gw + gb;
  hbuf[0*262144 + row*C_ + c]  = f2b(o);
  hbuf[2*262144 + frow*C_ + c] = f2b(o);
  s = vmin; s2 = vmin*vmin;
  bred2(s, s2, red);
  m = s*(1.f/256.f); var = s2*(1.f/256.f) - m*m;
  o = (vmin - m)*rsqrtf(vclamp(var))*gw + gb;
  hbuf[1*262144 + row*C_ + c]  = f2b(o);
  hbuf[3*262144 + frow*C_ + c] = f2b(o);
}

// ---------------- dwconvT on-the-fly helper ----------------------------------------
__device__ inline float dwconvT_at(const float* __restrict__ xp, const float* __restrict__ w, int i, int j)
{
  float acc = 0.f;
  #pragma unroll
  for (int ki = 0; ki < 3; ki++){
    int pi = i + ki - 1;
    if (pi < 0 || (pi & 1)) continue;
    int xi = pi >> 1;
    if (xi >= 64) continue;
    #pragma unroll
    for (int kj = 0; kj < 3; kj++){
      int pj = j + kj - 1;
      if (pj < 0 || (pj & 1)) continue;
      int xj = pj >> 1;
      if (xj >= 64) continue;
      acc += w[(2-ki)*3 + (2-kj)] * xp[xi*64 + xj];
    }
  }
  return acc;
}

// ---------------- z1raw = dwconvT(x) as bf16 + bn1 stats (one pass) ----------------
// x plane staged in LDS; coalesced bf16 stores. grid (B*C), block 256.
__global__ __launch_bounds__(256) void dwz1_kernel(const float* __restrict__ x, const float* __restrict__ dw,
    bf16* __restrict__ z1, float* __restrict__ bn1sum, float* __restrict__ bn1sq)
{
  int bc = blockIdx.x; int c = bc & 255;
  int tid = threadIdx.x;
  __shared__ float xs[4096];
  const float* xp = x + (long)bc*4096;
  for (int it = 0; it < 16; it++) xs[it*256 + tid] = xp[it*256 + tid];
  float w[9];
  #pragma unroll
  for (int q = 0; q < 9; q++) w[q] = dw[c*9 + q];
  __syncthreads();
  bf16* zp = z1 + (long)bc*16384;
  float s = 0.f, s2 = 0.f;
  for (int it = 0; it < 64; it++){
    int p = it*256 + tid; int i = p >> 7, j = p & 127;
    float acc = dwconvT_at(xs, w, i, j);
    zp[p] = f2b(acc);
    s += acc; s2 += acc*acc;
  }
  __shared__ float red[512];
  bred2(s, s2, red);
  if (tid == 0){ atomicAdd(&bn1sum[c], s); atomicAdd(&bn1sq[c], s2); }
}

// ---------------- bn finalize: per-channel affine ----------------------------------
__global__ void fin_bn_kernel(const float* __restrict__ sum, const float* __restrict__ sq,
                              const float* __restrict__ g, const float* __restrict__ b,
                              float cnt_inv, float* __restrict__ a, float* __restrict__ d)
{
  int c = threadIdx.x;
  float m = sum[c]*cnt_inv;
  float v = sq[c]*cnt_inv - m*m;
  float aa = g[c] * rsqrtf(vclamp(v));
  a[c] = aa;
  d[c] = b[c] - m*aa;
}

// ---------------- fp32 -> bf16 weight convert --------------------------------------
__global__ void wcvt_kernel(const float* __restrict__ W, bf16* __restrict__ Wb, int n)
{
  int i = blockIdx.x*256 + threadIdx.x;
  if (i < n) Wb[i] = f2b(W[i]);
}

// ---------------- actz1: z1t[b][p][c] = bf16(relu(fa[c]*z1[b,c,p]+fd[c])) ----------
// 64x64 transpose via LDS fp32 tile (bank-clean). grid (256, 4, B), block 256.
__global__ __launch_bounds__(256) void actz1_kernel(const bf16* __restrict__ z1,
    const float* __restrict__ fa, const float* __restrict__ fd, bf16* __restrict__ z1t)
{
  int p0 = blockIdx.x*64, c0 = blockIdx.y*64, b = blockIdx.z;
  int tid = threadIdx.x;
  __shared__ float t[64][65];
  #pragma unroll
  for (int q = 0; q < 2; q++){
    int cl = (tid >> 3) + q*32;
    int p8 = (tid & 7)*8;
    const bf16* src = &z1[((long)(b*C_ + c0 + cl))*16384 + p0 + p8];
    float a = fa[c0 + cl], d = fd[c0 + cl];
    bf16 v[8];
    *(uint4*)v = *(const uint4*)src;
    #pragma unroll
    for (int i = 0; i < 8; i++) t[p8 + i][cl] = fmaxf(b2f(v[i])*a + d, 0.f);
  }
  __syncthreads();
  #pragma unroll
  for (int q = 0; q < 2; q++){
    int pl = (tid >> 3) + q*32;
    int c8 = (tid & 7)*8;
    bf16 v[8];
    #pragma unroll
    for (int i = 0; i < 8; i++) v[i] = f2b(t[pl][c8 + i]);
    *(uint4*)&z1t[((long)b*16384 + p0 + pl)*256 + c0 + c8] = *(const uint4*)v;
  }
}

// ---------------- up-pw GEMM on MFMA: z2[b,o,p] = sum_c Wb[o,c]*z1t[b,p,c] ---------
// grid (256, B), block 256.
__global__ __launch_bounds__(256) void pwz_mfma_kernel(const bf16* __restrict__ z1t,
    const bf16* __restrict__ Wb, bf16* __restrict__ z2)
{
  int b = blockIdx.y;
  int p0 = blockIdx.x*64;
  int tid = threadIdx.x;
  int wave = tid >> 6, lane = tid & 63;
  int quad = lane >> 4, l16 = lane & 15;
  const bf16* zb = z1t + (long)b*16384*256;
  f32x4v acc[4][4];
  #pragma unroll
  for (int i = 0; i < 4; i++)
    #pragma unroll
    for (int j = 0; j < 4; j++) acc[i][j] = (f32x4v){0.f, 0.f, 0.f, 0.f};
  for (int k0 = 0; k0 < 256; k0 += 32){
    int c = k0 + quad*8;
    bf16x8v a[4], bb[4];
    #pragma unroll
    for (int ms = 0; ms < 4; ms++)
      a[ms] = *(const bf16x8v*)&Wb[(wave*64 + ms*16 + l16)*C_ + c];
    #pragma unroll
    for (int ns = 0; ns < 4; ns++)
      bb[ns] = *(const bf16x8v*)&zb[((long)(p0 + ns*16 + l16))*C_ + c];
    #pragma unroll
    for (int ms = 0; ms < 4; ms++)
      #pragma unroll
      for (int ns = 0; ns < 4; ns++)
        acc[ms][ns] = __builtin_amdgcn_mfma_f32_16x16x32_bf16(a[ms], bb[ns], acc[ms][ns], 0, 0, 0);
  }
  #pragma unroll
  for (int ms = 0; ms < 4; ms++){
    int o = wave*64 + ms*16 + quad*4;
    #pragma unroll
    for (int r = 0; r < 4; r++){
      long rowbase = ((long)(b*C_ + o + r))*16384 + p0;
      #pragma unroll
      for (int ns = 0; ns < 4; ns++)
        z2[rowbase + ns*16 + l16] = f2b(acc[ms][ns][r]);
    }
  }
}

// ---------------- in_proj GEMM on MFMA: xz[v][m][n] = sum_k hb[v][m][k]*Wi[n][k] ---
// M=1024, N=1024, K=256. grid (16, 4, 4), block 256 (4 waves x 64 m-rows).
__global__ __launch_bounds__(256) void inproj_mfma_kernel(const bf16* __restrict__ hb,
    const bf16* __restrict__ Wif, const bf16* __restrict__ Wib2, float* __restrict__ xz)
{
  int v = blockIdx.z;
  int m0 = blockIdx.y*256, n0 = blockIdx.x*64;
  const bf16* A = hb + (long)v*262144;
  const bf16* W = (v >= 2) ? Wib2 : Wif;
  float* out = xz + (long)v*1048576;
  int tid = threadIdx.x;
  int wave = tid >> 6, lane = tid & 63;
  int quad = lane >> 4, l16 = lane & 15;
  f32x4v acc[4][4];
  #pragma unroll
  for (int i = 0; i < 4; i++)
    #pragma unroll
    for (int j = 0; j < 4; j++) acc[i][j] = (f32x4v){0.f, 0.f, 0.f, 0.f};
  for (int k0 = 0; k0 < 256; k0 += 32){
    int c = k0 + quad*8;
    bf16x8v a[4], bb[4];
    #pragma unroll
    for (int ms = 0; ms < 4; ms++)
      a[ms] = *(const bf16x8v*)&A[(long)(m0 + wave*64 + ms*16 + l16)*256 + c];
    #pragma unroll
    for (int ns = 0; ns < 4; ns++)
      bb[ns] = *(const bf16x8v*)&W[(long)(n0 + ns*16 + l16)*256 + c];
    #pragma unroll
    for (int ms = 0; ms < 4; ms++)
      #pragma unroll
      for (int ns = 0; ns < 4; ns++)
        acc[ms][ns] = __builtin_amdgcn_mfma_f32_16x16x32_bf16(a[ms], bb[ns], acc[ms][ns], 0, 0, 0);
  }
  #pragma unroll
  for (int ms = 0; ms < 4; ms++){
    int m = m0 + wave*64 + ms*16 + quad*4;
    #pragma unroll
    for (int r = 0; r < 4; r++){
      long rowbase = (long)(m + r)*1024 + n0;
      #pragma unroll
      for (int ns = 0; ns < 4; ns++)
        out[rowbase + ns*16 + l16] = acc[ms][ns][r];
    }
  }
}

// ---------------- x_proj GEMM on MFMA: dbl[v][m][n] = sum_k u[v][m][k]*Wx[n][k] ----
// M=1024, N=48, K=512. grid (4 mtile, 4 v), block 256 (4 waves x 64 m-rows).
__global__ __launch_bounds__(256) void xproj_mfma_kernel(const bf16* __restrict__ ub,
    const bf16* __restrict__ Wxf, const bf16* __restrict__ Wxb, float* __restrict__ dblb)
{
  int v = blockIdx.y;
  int m0 = blockIdx.x*256;
  const bf16* A = ub + (long)v*524288;
  const bf16* W = (v >= 2) ? Wxb : Wxf;
  float* out = dblb + (long)v*49152;
  int tid = threadIdx.x;
  int wave = tid >> 6, lane = tid & 63;
  int quad = lane >> 4, l16 = lane & 15;
  f32x4v acc[4][3];
  #pragma unroll
  for (int i = 0; i < 4; i++)
    #pragma unroll
    for (int j = 0; j < 3; j++) acc[i][j] = (f32x4v){0.f, 0.f, 0.f, 0.f};
  for (int k0 = 0; k0 < 512; k0 += 32){
    int c = k0 + quad*8;
    bf16x8v a[4], bb[3];
    #pragma unroll
    for (int ms = 0; ms < 4; ms++)
      a[ms] = *(const bf16x8v*)&A[(long)(m0 + wave*64 + ms*16 + l16)*512 + c];
    #pragma unroll
    for (int ns = 0; ns < 3; ns++)
      bb[ns] = *(const bf16x8v*)&W[(long)(ns*16 + l16)*512 + c];
    #pragma unroll
    for (int ms = 0; ms < 4; ms++)
      #pragma unroll
      for (int ns = 0; ns < 3; ns++)
        acc[ms][ns] = __builtin_amdgcn_mfma_f32_16x16x32_bf16(a[ms], bb[ns], acc[ms][ns], 0, 0, 0);
  }
  #pragma unroll
  for (int ms = 0; ms < 4; ms++){
    int m = m0 + wave*64 + ms*16 + quad*4;
    #pragma unroll
    for (int r = 0; r < 4; r++){
      long rowbase = (long)(m + r)*48;
      #pragma unroll
      for (int ns = 0; ns < 3; ns++)
        out[rowbase + ns*16 + l16] = acc[ms][ns][r];
    }
  }
}

// ---------------- out_proj GEMM on MFMA: mout[v][m][n] = sum_k y[v][m][k]*Wo[n][k] -
// M=1024, N=256, K=512. grid (4 ntile, 4 mtile, 4 v), block 256.
__global__ __launch_bounds__(256) void outproj_mfma_kernel(const bf16* __restrict__ yb,
    const bf16* __restrict__ Wof, const bf16* __restrict__ Wob, float* __restrict__ mo)
{
  int v = blockIdx.z;
  int m0 = blockIdx.y*256, n0 = blockIdx.x*64;
  const bf16* A = yb + (long)v*524288;
  const bf16* W = (v >= 2) ? Wob : Wof;
  float* out = mo + (long)v*262144;
  int tid = threadIdx.x;
  int wave = tid >> 6, lane = tid & 63;
  int quad = lane >> 4, l16 = lane & 15;
  f32x4v acc[4][4];
  #pragma unroll
  for (int i = 0; i < 4; i++)
    #pragma unroll
    for (int j = 0; j < 4; j++) acc[i][j] = (f32x4v){0.f, 0.f, 0.f, 0.f};
  for (int k0 = 0; k0 < 512; k0 += 32){
    int c = k0 + quad*8;
    bf16x8v a[4], bb[4];
    #pragma unroll
    for (int ms = 0; ms < 4; ms++)
      a[ms] = *(const bf16x8v*)&A[(long)(m0 + wave*64 + ms*16 + l16)*512 + c];
    #pragma unroll
    for (int ns = 0; ns < 4; ns++)
      bb[ns] = *(const bf16x8v*)&W[(long)(n0 + ns*16 + l16)*512 + c];
    #pragma unroll
    for (int ms = 0; ms < 4; ms++)
      #pragma unroll
      for (int ns = 0; ns < 4; ns++)
        acc[ms][ns] = __builtin_amdgcn_mfma_f32_16x16x32_bf16(a[ms], bb[ns], acc[ms][ns], 0, 0, 0);
  }
  #pragma unroll
  for (int ms = 0; ms < 4; ms++){
    int m = m0 + wave*64 + ms*16 + quad*4;
    #pragma unroll
    for (int r = 0; r < 4; r++){
      long rowbase = (long)(m + r)*256 + n0;
      #pragma unroll
      for (int ns = 0; ns < 4; ns++)
        out[rowbase + ns*16 + l16] = acc[ms][ns][r];
    }
  }
}

// ---------------- per-channel stats of bf16 tensor (B,C,16384) ---------------------
// grid (C, B), block 256
__global__ __launch_bounds__(256) void chstats_kernel(const bf16* __restrict__ t,
                                                      float* __restrict__ sum, float* __restrict__ sq)
{
  int c = blockIdx.x, b = blockIdx.y, tid = threadIdx.x;
  const bf16* p = t + ((long)(b*C_ + c))*16384;
  float s = 0.f, s2 = 0.f;
  for (int it = 0; it < 64; it++){ float v = b2f(p[it*256 + tid]); s += v; s2 += v*v; }
  __shared__ float red[512];
  bred2(s, s2, red);
  if (tid == 0){ atomicAdd(&sum[c], s); atomicAdd(&sq[c], s2); }
}

// ---------------- generic GEMM: C[m,n] = act(sum_k A[m,k] W[n,k] + bias[n]) --------
// grid ((N+63)/64, (M+63)/64, nbatch), block 256
__global__ __launch_bounds__(256) void gemm_kernel(
  const float* __restrict__ Abase, long sA, int lda,
  const float* __restrict__ W0, const float* __restrict__ W1,
  const float* __restrict__ bias0, const float* __restrict__ bias1, int wsplit,
  float* __restrict__ Cbase, long sC, int ldc,
  int M, int N, int K, int act)
{
  int z = blockIdx.z;
  const float* A = Abase + (long)z*sA;
  float* Cp = Cbase + (long)z*sC;
  const float* W = (z >= wsplit) ? W1 : W0;
  const float* bias = (z >= wsplit) ? bias1 : bias0;
  int m0 = blockIdx.y*64, n0 = blockIdx.x*64;
  __shared__ __align__(16) float As[16][68];
  __shared__ __align__(16) float Ws[16][68];
  int tid = threadIdx.x, tx = tid & 15, ty = tid >> 4;
  float acc[4][4] = {};
  for (int k0 = 0; k0 < K; k0 += 16){
    #pragma unroll
    for (int q = 0; q < 4; q++){
      int e = tid + q*256; int r = e >> 4, kk = e & 15;
      int mi = m0 + r, ki = k0 + kk;
      As[kk][r] = (mi < M && ki < K) ? A[(long)mi*lda + ki] : 0.f;
    }
    #pragma unroll
    for (int q = 0; q < 4; q++){
      int e = tid + q*256; int n = e >> 4, kk = e & 15;
      int ni = n0 + n, ki = k0 + kk;
      Ws[kk][n] = (ni < N && ki < K) ? W[(long)ni*K + ki] : 0.f;
    }
    __syncthreads();
    #pragma unroll
    for (int kk = 0; kk < 16; kk++){
      float4 a4 = *(const float4*)&As[kk][ty*4];
      float4 b4 = *(const float4*)&Ws[kk][tx*4];
      float av[4] = {a4.x, a4.y, a4.z, a4.w};
      float bv[4] = {b4.x, b4.y, b4.z, b4.w};
      #pragma unroll
      for (int mm = 0; mm < 4; mm++)
        #pragma unroll
        for (int nn = 0; nn < 4; nn++) acc[mm][nn] += av[mm]*bv[nn];
    }
    __syncthreads();
  }
  #pragma unroll
  for (int mm = 0; mm < 4; mm++){
    int mi = m0 + ty*4 + mm;
    if (mi >= M) continue;
    #pragma unroll
    for (int nn = 0; nn < 4; nn++){
      int ni = n0 + tx*4 + nn;
      if (ni >= N) continue;
      float v = acc[mm][nn];
      if (bias) v += bias[ni];
      if (act == 2) v = softplusf(v);
      Cp[(long)mi*ldc + ni] = v;
    }
  }
}

// ---------------- depthwise causal conv1d (k=4) + silu, bf16 out -------------------
// grid (L, B, 4), block 512
__global__ __launch_bounds__(512) void conv1d_kernel(const float* __restrict__ xzb,
    const float* __restrict__ fw, const float* __restrict__ fb,
    const float* __restrict__ bw, const float* __restrict__ bb,
    bf16* __restrict__ ub)
{
  int l = blockIdx.x, b = blockIdx.y, v = blockIdx.z, d = threadIdx.x;
  const float* xm = xzb + (long)v*1024*1024;
  const float* w  = (v < 2) ? fw : bw;
  const float* cb = (v < 2) ? fb : bb;
  float acc = cb[d];
  #pragma unroll
  for (int k = 0; k < 4; k++){
    int ll = l - 3 + k;
    if (ll >= 0) acc += xm[(long)(b*L_ + ll)*1024 + d] * w[d*4 + k];
  }
  ub[(long)v*1024*512 + (long)(b*L_ + l)*512 + d] = f2b(siluf(acc));
}

// ---------------- selective scan (split-state, all-LDS, 512 waves) -----------------
// Lanes 0-31 carry states 0-7, lanes 32-63 carry states 8-15 for the same 32 d's;
// dt/u/zg LDS reads broadcast across halves; B/C read as bf16x8 (1 ds_read_b128);
// per-step cross-half merge via one shfl_xor(32). grid (16, B, 4), block 64.
__global__ __launch_bounds__(64) void scan_kernel(const float* __restrict__ dtb, const bf16* __restrict__ ub,
    const float* __restrict__ dblb, const float* __restrict__ xzb,
    const float* __restrict__ fAlog, const float* __restrict__ fD,
    const float* __restrict__ bAlog, const float* __restrict__ bD,
    bf16* __restrict__ yb)
{
  int v = blockIdx.z, b = blockIdx.y;
  int tid = threadIdx.x;
  int dd = tid & 31, half = tid >> 5;
  int d0 = blockIdx.x*32;
  int d = d0 + dd;
  const float* dt  = dtb  + (long)v*1024*512;
  const bf16*  u   = ub   + (long)v*1024*512;
  const float* dbl = dblb + (long)v*1024*48;
  const float* zg  = xzb  + (long)v*1024*1024 + 512;
  const float* Alog = (v < 2) ? fAlog : bAlog;
  const float* Dp   = (v < 2) ? fD : bD;
  __shared__ bf16 sdt[4096], su[4096], szg[4096];          // [l][32]
  __shared__ __align__(16) bf16 sbc[4096];                 // [l][0..15]=B,[16..31]=C
  long row = (long)b*L_;
  for (int idx = tid; idx < 4096; idx += 64){
    int l = idx >> 5, j = idx & 31;
    sdt[idx] = f2b(dt[(row + l)*512 + d0 + j]);
    su [idx] = u[(row + l)*512 + d0 + j];
    szg[idx] = f2b(zg[(row + l)*1024 + d0 + j]);
    sbc[idx] = f2b(dbl[(row + l)*48 + 16 + j]);
  }
  float a2[8];
  #pragma unroll
  for (int n = 0; n < 8; n++) a2[n] = -expf(Alog[d*16 + half*8 + n]) * 1.44269504f;
  float Dv = Dp[d];
  float h[8];
  #pragma unroll
  for (int n = 0; n < 8; n++) h[n] = 0.f;
  __syncthreads();
  bf16* yo = yb + (long)v*1024*512;
  for (int l = 0; l < 128; l++){
    float dtv = b2f(sdt[l*32 + dd]);
    float uv  = b2f(su [l*32 + dd]);
    float zgv = b2f(szg[l*32 + dd]);
    bf16x8v Bv = *(const bf16x8v*)&sbc[l*32 + half*8];
    bf16x8v Cv = *(const bf16x8v*)&sbc[l*32 + 16 + half*8];
    float dtu = dtv*uv;
    float acc = 0.f;
    #pragma unroll
    for (int n = 0; n < 8; n++){
      float dA = exp2f(dtv*a2[n]);
      bf16 tb; *(short*)&tb = Bv[n];
      bf16 tc; *(short*)&tc = Cv[n];
      h[n] = dA*h[n] + dtu*b2f(tb);
      acc += h[n]*b2f(tc);
    }
    acc += __shfl_xor(acc, 32);
    if (half == 0)
      yo[(row + l)*512 + d] = f2b((acc + Dv*uv) * siluf(zgv));
  }
}

// ---------------- LayerNorm over C, two output modes -------------------------------
// grid (128, B, NV), block 256
__global__ __launch_bounds__(256) void ln_kernel(const float* __restrict__ inb, float* __restrict__ out0,
    float* __restrict__ out1, const float* __restrict__ lnw, const float* __restrict__ lnb, int mode)
{
  int r = blockIdx.x, b = blockIdx.y, v = blockIdx.z, c = threadIdx.x;
  long row = (long)b*L_ + r;
  float val = inb[((long)v*1024 + row)*C_ + c];
  __shared__ float red[512];
  float s = val, s2 = val*val;
  bred2(s, s2, red);
  float m = s*(1.f/256.f), var = s2*(1.f/256.f) - m*m;
  float o = (val - m)*rsqrtf(vclamp(var))*lnw[c] + lnb[c];
  if (mode == 1){
    long frow = (long)b*L_ + (127 - r);
    if (v == 0)      out0[row*512 + c] = o;
    else if (v == 1) out1[row*512 + c] = o;
    else if (v == 2) out0[frow*512 + 256 + c] = o;
    else             out1[frow*512 + 256 + c] = o;
  } else {
    out0[((long)v*1024 + row)*C_ + c] = o;
  }
}

// ---------------- hsig(rm+rn)*clip(bn2(z2)) + gn stats; resq IN-PLACE in z2 --------
// grid (C, B), block 256
__global__ __launch_bounds__(256) void hsig_kernel(bf16* __restrict__ z2, const float* __restrict__ rm,
    const float* __restrict__ rn, const float* __restrict__ a2, const float* __restrict__ d2,
    float* __restrict__ gnsum, float* __restrict__ gnsq)
{
  int c = blockIdx.x, b = blockIdx.y, tid = threadIdx.x;
  __shared__ float rms[128], rns[128];
  if (tid < 128){
    rms[tid] = rm[(long)(b*L_ + tid)*C_ + c];
    rns[tid] = rn[(long)(b*L_ + tid)*C_ + c];
  }
  __syncthreads();
  float aa = a2[c], dd = d2[c];
  bf16* zp = z2 + ((long)(b*C_ + c))*16384;
  float s = 0.f, s2 = 0.f;
  for (int g = 0; g < 16; g++){
    float tv[4]; int wq[4];
    #pragma unroll
    for (int q = 0; q < 4; q++){
      int p = g*1024 + q*256 + tid; int i = p >> 7, j = p & 127;
      float zv = b2f(zp[p])*aa + dd;
      zv = fminf(fmaxf(zv, 0.f), 6.f);
      float gate = rms[i] + rns[j];
      gate = fminf(fmaxf(gate + 3.f, 0.f), 6.f) * (1.f/6.f);
      float t = gate*zv;
      s += t; s2 += t*t;
      tv[q] = t;
      wq[q] = (((i | j) & 1) == 0) ? ((i >> 1)*64 + (j >> 1)) : -1;
    }
    __syncthreads();
    #pragma unroll
    for (int q = 0; q < 4; q++)
      if (wq[q] >= 0) zp[wq[q]] = f2b(tv[q]);
  }
  __shared__ float red[512];
  bred2(s, s2, red);
  if (tid == 0){ atomicAdd(&gnsum[b*32 + (c >> 3)], s); atomicAdd(&gnsq[b*32 + (c >> 3)], s2); }
}

// ---------------- gn finalize to per-(b,c) affine ----------------------------------
// grid (B), block 256
__global__ void fin_gn_kernel(const float* __restrict__ gnsum, const float* __restrict__ gnsq,
                              const float* __restrict__ g, const float* __restrict__ bb,
                              float* __restrict__ gnA, float* __restrict__ gnD)
{
  int b = blockIdx.x, c = threadIdx.x, gr = c >> 3;
  float inv_cnt = 1.f/131072.f;
  float m = gnsum[b*32 + gr]*inv_cnt;
  float v = gnsq[b*32 + gr]*inv_cnt - m*m;
  float inv = rsqrtf(vclamp(v));
  float A = inv*g[c];
  gnA[b*C_ + c] = A;
  gnD[b*C_ + c] = bb[c] - m*A;
}

// ---------------- trd: rqt[b][s][c] = bf16(gnA*resq[b,c,s]+gnD) --------------------
// grid (64, 4, B), block 256.
__global__ __launch_bounds__(256) void trd_kernel(const bf16* __restrict__ z2,
    const float* __restrict__ gnA, const float* __restrict__ gnD, bf16* __restrict__ rqt)
{
  int p0 = blockIdx.x*64, c0 = blockIdx.y*64, b = blockIdx.z;
  int tid = threadIdx.x;
  __shared__ float t[64][65];
  #pragma unroll
  for (int q = 0; q < 2; q++){
    int cl = (tid >> 3) + q*32;
    int p8 = (tid & 7)*8;
    int c = c0 + cl;
    const bf16* src = &z2[((long)(b*C_ + c))*16384 + p0 + p8];
    float a = gnA[b*C_ + c], dd = gnD[b*C_ + c];
    bf16 v[8];
    *(uint4*)v = *(const uint4*)src;
    #pragma unroll
    for (int i = 0; i < 8; i++) t[p8 + i][cl] = b2f(v[i])*a + dd;
  }
  __syncthreads();
  #pragma unroll
  for (int q = 0; q < 2; q++){
    int pl = (tid >> 3) + q*32;
    int c8 = (tid & 7)*8;
    bf16 v[8];
    #pragma unroll
    for (int i = 0; i < 8; i++) v[i] = f2b(t[pl][c8 + i]);
    *(uint4*)&rqt[((long)b*4096 + p0 + pl)*256 + c0 + c8] = *(const uint4*)v;
  }
}

// ---------------- down-pw GEMM on MFMA: d[b,o,s] = sum_c Wb[o,c]*rqt[b,s,c] --------
// fp32 output to d_out (stride 4096). grid (64, B), block 256.
__global__ __launch_bounds__(256) void pwdown_mfma_kernel(const bf16* __restrict__ rqt,
    const bf16* __restrict__ Wb, float* __restrict__ out)
{
  int b = blockIdx.y;
  int p0 = blockIdx.x*64;
  int tid = threadIdx.x;
  int wave = tid >> 6, lane = tid & 63;
  int quad = lane >> 4, l16 = lane & 15;
  const bf16* zb = rqt + (long)b*4096*256;
  f32x4v acc[4][4];
  #pragma unroll
  for (int i = 0; i < 4; i++)
    #pragma unroll
    for (int j = 0; j < 4; j++) acc[i][j] = (f32x4v){0.f, 0.f, 0.f, 0.f};
  for (int k0 = 0; k0 < 256; k0 += 32){
    int c = k0 + quad*8;
    bf16x8v a[4], bb[4];
    #pragma unroll
    for (int ms = 0; ms < 4; ms++)
      a[ms] = *(const bf16x8v*)&Wb[(wave*64 + ms*16 + l16)*C_ + c];
    #pragma unroll
    for (int ns = 0; ns < 4; ns++)
      bb[ns] = *(const bf16x8v*)&zb[((long)(p0 + ns*16 + l16))*C_ + c];
    #pragma unroll
    for (int ms = 0; ms < 4; ms++)
      #pragma unroll
      for (int ns = 0; ns < 4; ns++)
        acc[ms][ns] = __builtin_amdgcn_mfma_f32_16x16x32_bf16(a[ms], bb[ns], acc[ms][ns], 0, 0, 0);
  }
  #pragma unroll
  for (int ms = 0; ms < 4; ms++){
    int o = wave*64 + ms*16 + quad*4;
    #pragma unroll
    for (int r = 0; r < 4; r++){
      long rowbase = ((long)(b*C_ + o + r))*4096 + p0;
      #pragma unroll
      for (int ns = 0; ns < 4; ns++)
        out[rowbase + ns*16 + l16] = acc[ms][ns][r];
    }
  }
}

// ---------------- 5 moments per (b,c): sum d, d^2, x, x^2, dx ----------------------
// grid (C, B), block 256
__global__ __launch_bounds__(256) void stat5_kernel(const float* __restrict__ dbuf, const float* __restrict__ x,
                                                    float* __restrict__ s5)
{
  int c = blockIdx.x, b = blockIdx.y, tid = threadIdx.x;
  const float* dp = dbuf + ((long)(b*C_ + c))*4096;
  const float* xp = x + ((long)(b*C_ + c))*4096;
  float sd = 0, sd2 = 0, sx = 0, sx2 = 0, sdx = 0;
  for (int it = 0; it < 16; it++){
    float d = dp[it*256 + tid];
    float xv = xp[it*256 + tid];
    sd += d; sd2 += d*d; sx += xv; sx2 += xv*xv; sdx += d*xv;
  }
  __shared__ float red[256];
  float r0 = bred1(sd, red); float r1 = bred1(sd2, red); float r2 = bred1(sx, red);
  float r3 = bred1(sx2, red); float r4 = bred1(sdx, red);
  if (tid == 0){
    float* o = s5 + (long)(b*C_ + c)*5;
    o[0] = r0; o[1] = r1; o[2] = r2; o[3] = r3; o[4] = r4;
  }
}

// ---------------- collapse bn -> gn -> (+x) -> gn into out = P*d + Q*x + R ---------
// grid (B), block 256
__global__ void coeff_kernel(const float* __restrict__ s5, const float* __restrict__ dbn_g, const float* __restrict__ dbn_b,
                             const float* __restrict__ gn_g, const float* __restrict__ gn_b, float* __restrict__ pqr)
{
  int b = blockIdx.x, c = threadIdx.x, g = c >> 3;
  float sd = 0, sd2 = 0;
  for (int bb = 0; bb < 8; bb++){ sd += s5[(long)(bb*C_ + c)*5 + 0]; sd2 += s5[(long)(bb*C_ + c)*5 + 1]; }
  float inv_cnt = 1.f/32768.f;
  float mB = sd*inv_cnt;
  float vB = sd2*inv_cnt - mB*mB;
  float ab = dbn_g[c] * rsqrtf(vclamp(vB));
  float db = dbn_b[c] - mB*ab;
  const float* s = s5 + (long)(b*C_ + c)*5;
  float inv_n = 1.f/4096.f;
  float m = s[0]*inv_n, Ed2 = s[1]*inv_n, mx = s[2]*inv_n, Ex2 = s[3]*inv_n, Edx = s[4]*inv_n;
  float Ev = ab*m + db;
  float Ev2 = ab*ab*Ed2 + 2.f*ab*db*m + db*db;
  __shared__ float e1[256], e2[256];
  e1[c] = Ev; e2[c] = Ev2;
  __syncthreads();
  float m1 = 0, q1 = 0;
  for (int k = 0; k < 8; k++){ m1 += e1[(g << 3) + k]; q1 += e2[(g << 3) + k]; }
  m1 *= 0.125f; q1 *= 0.125f;
  float inv1 = rsqrtf(vclamp(q1 - m1*m1));
  float gg = gn_g[c];
  float A1 = inv1*gg;
  float D1 = gn_b[c] - m1*A1;
  float al = A1*ab;
  float be = A1*db + D1;
  float Et = al*m + be + mx;
  float Et2 = al*al*Ed2 + 2.f*al*be*m + be*be + 2.f*al*Edx + 2.f*be*mx + Ex2;
  __syncthreads();
  e1[c] = Et; e2[c] = Et2;
  __syncthreads();
  float m2 = 0, q2 = 0;
  for (int k = 0; k < 8; k++){ m2 += e1[(g << 3) + k]; q2 += e2[(g << 3) + k]; }
  m2 *= 0.125f; q2 *= 0.125f;
  float inv2 = rsqrtf(vclamp(q2 - m2*m2));
  float G = inv2*gg;
  float* o = pqr + (long)(b*C_ + c)*3;
  o[0] = G*al;
  o[1] = G;
  o[2] = G*(be - m2) + gn_b[c];
}

// ---------------- final elementwise: out = P*out + Q*x + R (in-place on d_out) -----
// grid (C, B), block 256
__global__ __launch_bounds__(256) void final_kernel(const float* __restrict__ x,
    const float* __restrict__ pqr, float* __restrict__ out)
{
  int c = blockIdx.x, b = blockIdx.y, tid = threadIdx.x;
  const float* o = pqr + (long)(b*C_ + c)*3;
  float P = o[0], Q = o[1], R = o[2];
  long base = ((long)(b*C_ + c))*4096;
  for (int it = 0; it < 16; it++){
    long idx = base + it*256 + tid;
    out[idx] = P*out[idx] + Q*x[idx] + R;
  }
}

extern "C" void kernel_launch(void* const* d_in, const int* in_sizes, int n_in,
                              void* d_out, int out_size, void* d_ws, size_t ws_size,
                              hipStream_t stream)
{
  (void)in_sizes; (void)n_in; (void)out_size; (void)ws_size;
  // ALL inputs/outputs are float32.
  const float* x         = (const float*)d_in[0];
  const float* pos       = (const float*)d_in[1];
  const float* ln_w      = (const float*)d_in[2];
  const float* ln_b      = (const float*)d_in[3];
  const float* proj_w    = (const float*)d_in[4];
  const float* proj_b    = (const float*)d_in[5];
  const float* up_dw_w   = (const float*)d_in[6];
  const float* up_bn1_g  = (const float*)d_in[7];
  const float* up_bn1_b  = (const float*)d_in[8];
  const float* up_pw_w   = (const float*)d_in[9];
  const float* up_bn2_g  = (const float*)d_in[10];
  const float* up_bn2_b  = (const float*)d_in[11];
  const float* down_pw_w = (const float*)d_in[12];
  const float* down_bn_g = (const float*)d_in[13];
  const float* down_bn_b = (const float*)d_in[14];
  const float* gn_g      = (const float*)d_in[15];
  const float* gn_b      = (const float*)d_in[16];
  const float* f_in_w    = (const float*)d_in[17];
  const float* f_conv_w  = (const float*)d_in[18];
  const float* f_conv_b  = (const float*)d_in[19];
  const float* f_xproj_w = (const float*)d_in[20];
  const float* f_dt_w    = (const float*)d_in[21];
  const float* f_dt_b    = (const float*)d_in[22];
  const float* f_Alog    = (const float*)d_in[23];
  const float* f_D       = (const float*)d_in[24];
  const float* f_out_w   = (const float*)d_in[25];
  const float* b_in_w    = (const float*)d_in[26];
  const float* b_conv_w  = (const float*)d_in[27];
  const float* b_conv_b  = (const float*)d_in[28];
  const float* b_xproj_w = (const float*)d_in[29];
  const float* b_dt_w    = (const float*)d_in[30];
  const float* b_dt_b    = (const float*)d_in[31];
  const float* b_Alog    = (const float*)d_in[32];
  const float* b_D       = (const float*)d_in[33];
  const float* b_out_w   = (const float*)d_in[34];

  // ======== workspace layout, PEAK = 132MB ========
  char* sb = (char*)d_ws;
  float* statz = (float*)(sb);               // 1536 f (zeroed each launch)
  float* abn   = (float*)(sb + 8192);        // 1024 f
  float* gnAD  = (float*)(sb + 16384);       // 4096 f
  float* stat5 = (float*)(sb + 65536);       // 10240 f
  float* pqr   = (float*)(sb + 131072);      // 6144 f
  float* rmrn  = (float*)(sb + 1*MB);        // 2MB: 2 x (1024,256)
  bf16*  Wbbuf = (bf16*)(sb + 3*MB);         // 128KB: up_pw_w bf16
  bf16*  Wb2buf= (bf16*)(sb + 3*MB + 262144);// 128KB: down_pw_w bf16
  char* big = sb + 4*MB;
  float* pool4  = (float*)(big + 0*MB);      // 2 MB
  bf16*  hbufb  = (bf16*)(big + 2*MB);       // 2 MB: 4 x (B*L,C) bf16
  bf16*  Wif    = (bf16*)(big + 4*MB);       // 512KB: f_in_w bf16
  bf16*  Wib2   = (bf16*)(big + 4*MB + 524288); // 512KB: b_in_w bf16
  bf16*  Wxf    = (bf16*)(big + 5*MB);           // 48KB: f_xproj_w bf16
  bf16*  Wxb    = (bf16*)(big + 5*MB + 65536);   // 48KB: b_xproj_w bf16
  bf16*  Wof    = (bf16*)(big + 5*MB + 131072);  // 256KB: f_out_w bf16
  bf16*  Wob    = (bf16*)(big + 5*MB + 393216);  // 256KB: b_out_w bf16
  float* xzbuf  = (float*)(big + 6*MB);      // 16 MB
  bf16*  ubuf   = (bf16*)(big + 22*MB);      // 4 MB: 4 x (1024,512) bf16
  float* dblbuf = (float*)(big + 30*MB);     // 768 KB
  float* dtbuf  = (float*)(big + 31*MB);     // 8 MB
  bf16*  ybuf   = (bf16*)(big + 39*MB);      // 4 MB: 4 x (1024,512) bf16
  float* mout   = (float*)(big + 47*MB);     // 4 MB
  float* cbuf   = (float*)(big + 51*MB);     // 4 MB
  float* respre = (float*)(big + 55*MB);     // 2 MB  (ends at 57MB < 64MB)
  bf16*  z1buf  = (bf16*)(big);              // 64 MiB bf16, c-major (phase 2a)
  bf16*  z2buf  = (bf16*)(big);              // 64 MiB bf16 (phase 2b/3; z1 dead)
  bf16*  z1tbuf = (bf16*)(sb + 68*MB);       // 64 MiB bf16, p-major (phase 2)
  bf16*  rqtbuf = (bf16*)(sb + 68*MB);       // 16 MiB bf16, p-major (phase 3)
  float* dbuf   = (float*)d_out;             // 32 MB fp32 (phase 3)

  float* bn1sum = statz;        float* bn1sq = statz + 256;
  float* bn2sum = statz + 512;  float* bn2sq = statz + 768;
  float* gnsum  = statz + 1024; float* gnsq  = statz + 1280;
  float* abn1 = abn;       float* dbn1 = abn + 256;
  float* abn2 = abn + 512; float* dbn2 = abn + 768;
  float* gnA = gnAD;       float* gnD = gnAD + 2048;
  float* pcolmax = pool4;
  float* pcolmin = pool4 + 131072;
  float* prowmax = pool4 + 262144;
  float* prowmin = pool4 + 393216;

  hipMemsetAsync(statz, 0, 1536*sizeof(float), stream);

  // ---- phase 1: pooling + LN + mamba x4 (f/b x max/min) -> rmrn ----
  pool1_kernel<<<dim3(256, 8), 64, 0, stream>>>(x, pos, pcolmax, pcolmin, prowmax, prowmin);
  pool2_kernel<<<dim3(128, 8), 256, 0, stream>>>(pcolmax, pcolmin, prowmax, prowmin, ln_w, ln_b, hbufb);
  wcvt_kernel<<<1024, 256, 0, stream>>>(f_in_w, Wif, 262144);
  wcvt_kernel<<<1024, 256, 0, stream>>>(b_in_w, Wib2, 262144);
  wcvt_kernel<<<96, 256, 0, stream>>>(f_xproj_w, Wxf, 24576);
  wcvt_kernel<<<96, 256, 0, stream>>>(b_xproj_w, Wxb, 24576);
  wcvt_kernel<<<512, 256, 0, stream>>>(f_out_w, Wof, 131072);
  wcvt_kernel<<<512, 256, 0, stream>>>(b_out_w, Wob, 131072);
  inproj_mfma_kernel<<<dim3(16, 4, 4), 256, 0, stream>>>(hbufb, Wif, Wib2, xzbuf);
  conv1d_kernel<<<dim3(128, 8, 4), 512, 0, stream>>>(xzbuf, f_conv_w, f_conv_b, b_conv_w, b_conv_b, ubuf);
  xproj_mfma_kernel<<<dim3(4, 4), 256, 0, stream>>>(ubuf, Wxf, Wxb, dblbuf);
  gemm_kernel<<<dim3(8, 16, 4), 256, 0, stream>>>(dblbuf, 49152, 48, f_dt_w, b_dt_w, f_dt_b, b_dt_b, 2,
                                                  dtbuf, 524288, 512, 1024, 512, 16, 2);
  scan_kernel<<<dim3(16, 8, 4), 64, 0, stream>>>(dtbuf, ubuf, dblbuf, xzbuf, f_Alog, f_D, b_Alog, b_D, ybuf);
  outproj_mfma_kernel<<<dim3(4, 4, 4), 256, 0, stream>>>(ybuf, Wof, Wob, mout);
  ln_kernel<<<dim3(128, 8, 4), 256, 0, stream>>>(mout, cbuf, cbuf + 524288, ln_w, ln_b, 1);
  gemm_kernel<<<dim3(4, 16, 2), 256, 0, stream>>>(cbuf, 524288, 512, proj_w, proj_w, proj_b, proj_b, 2,
                                                  respre, 262144, 256, 1024, 256, 512, 0);
  ln_kernel<<<dim3(128, 8, 2), 256, 0, stream>>>(respre, rmrn, nullptr, ln_w, ln_b, 0);

  // ---- phase 2: z path ----
  dwz1_kernel<<<2048, 256, 0, stream>>>(x, up_dw_w, z1buf, bn1sum, bn1sq);
  fin_bn_kernel<<<1, 256, 0, stream>>>(bn1sum, bn1sq, up_bn1_g, up_bn1_b, 1.f/131072.f, abn1, dbn1);
  wcvt_kernel<<<256, 256, 0, stream>>>(up_pw_w, Wbbuf, 65536);
  wcvt_kernel<<<256, 256, 0, stream>>>(down_pw_w, Wb2buf, 65536);
  actz1_kernel<<<dim3(256, 4, 8), 256, 0, stream>>>(z1buf, abn1, dbn1, z1tbuf);
  pwz_mfma_kernel<<<dim3(256, 8), 256, 0, stream>>>(z1tbuf, Wbbuf, z2buf);
  chstats_kernel<<<dim3(256, 8), 256, 0, stream>>>(z2buf, bn2sum, bn2sq);
  fin_bn_kernel<<<1, 256, 0, stream>>>(bn2sum, bn2sq, up_bn2_g, up_bn2_b, 1.f/131072.f, abn2, dbn2);

  // ---- phase 3: merge + tail ----
  hsig_kernel<<<dim3(256, 8), 256, 0, stream>>>(z2buf, rmrn, rmrn + 262144, abn2, dbn2, gnsum, gnsq);
  fin_gn_kernel<<<8, 256, 0, stream>>>(gnsum, gnsq, gn_g, gn_b, gnA, gnD);
  trd_kernel<<<dim3(64, 4, 8), 256, 0, stream>>>(z2buf, gnA, gnD, rqtbuf);
  pwdown_mfma_kernel<<<dim3(64, 8), 256, 0, stream>>>(rqtbuf, Wb2buf, dbuf);
  stat5_kernel<<<dim3(256, 8), 256, 0, stream>>>(dbuf, x, stat5);
  coeff_kernel<<<8, 256, 0, stream>>>(stat5, down_bn_g, down_bn_b, gn_g, gn_b, pqr);
  final_kernel<<<dim3(256, 8), 256, 0, stream>>>(x, pqr, (float*)d_out);
}

// Round 12
// 561.083 us; speedup vs baseline: 3.4838x; 1.1051x over previous
//
#include <hip/hip_runtime.h>
#include <hip/hip_bf16.h>

typedef __hip_bfloat16 bf16;
typedef __attribute__((ext_vector_type(8))) short bf16x8v;
typedef __attribute__((ext_vector_type(4))) short bf16x4v;
typedef __attribute__((ext_vector_type(4))) float f32x4v;

#define B_ 8
#define C_ 256
#define L_ 128
#define MB 1048576UL

__device__ inline float b2f(bf16 v){ return __bfloat162float(v); }
__device__ inline bf16 f2b(float v){ return __float2bfloat16(v); }
__device__ inline float siluf(float x){ return x / (1.f + expf(-x)); }
__device__ inline float softplusf(float x){ return (x > 20.f) ? x : log1pf(expf(x)); }
__device__ inline float vclamp(float v){ return fmaxf(v, 0.f) + 1e-5f; }

// block = 256 threads. red must hold 512 floats.
__device__ inline void bred2(float& a, float& b, float* red){
  int t = threadIdx.x;
  __syncthreads();
  red[t] = a; red[256 + t] = b;
  __syncthreads();
  for (int off = 128; off > 0; off >>= 1){
    if (t < off){ red[t] += red[t + off]; red[256 + t] += red[256 + t + off]; }
    __syncthreads();
  }
  a = red[0]; b = red[256];
}
__device__ inline float bred1(float a, float* red){
  int t = threadIdx.x;
  __syncthreads();
  red[t] = a; __syncthreads();
  for (int off = 128; off > 0; off >>= 1){
    if (t < off) red[t] += red[t + off];
    __syncthreads();
  }
  return red[0];
}

// ---------------- pooling step 1: row/col max/min + argmax + pos-embed -------------
// grid (C, B), block 64
__global__ __launch_bounds__(64) void pool1_kernel(const float* __restrict__ x, const float* __restrict__ pos,
    float* __restrict__ pcolmax, float* __restrict__ pcolmin,
    float* __restrict__ prowmax, float* __restrict__ prowmin)
{
  int c = blockIdx.x, b = blockIdx.y, t = threadIdx.x;
  __shared__ float xs[64][65];
  const float* xp = x + ((long)(b*C_ + c))*4096;
  for (int i = 0; i < 64; i++) xs[i][t] = xp[i*64 + t];
  __syncthreads();
  // jax.image.resize 'linear' 16->64: half-pixel coords, edge clamp
  float tt = 0.25f*(float)t - 0.375f;
  const float* pp = pos + c*16;
  float pe;
  if (tt <= 0.f) pe = pp[0];
  else if (tt >= 15.f) pe = pp[15];
  else { int f = (int)floorf(tt); float w = tt - (float)f; pe = pp[f]*(1.f - w) + pp[f+1]*w; }
  float vmax = -1e30f, vmin = 1e30f; int amax = 0, amin = 0;
  for (int j = 0; j < 64; j++){
    float v = xs[t][j];
    if (v > vmax){ vmax = v; amax = j; }
    if (v < vmin){ vmin = v; amin = j; }
  }
  long o = (long)(b*64 + t)*C_ + c;
  prowmax[o] = vmax + pe + (float)amax;
  prowmin[o] = vmin + pe + (float)amin;
  vmax = -1e30f; vmin = 1e30f; amax = 0; amin = 0;
  for (int i = 0; i < 64; i++){
    float v = xs[i][t];
    if (v > vmax){ vmax = v; amax = i; }
    if (v < vmin){ vmin = v; amin = i; }
  }
  pcolmax[o] = vmax + pe + (float)amax;
  pcolmin[o] = vmin + pe + (float)amin;
}

// ---------------- pooling step 2: LN over channels, write 4 mamba inputs (bf16) ----
// grid (128, B), block 256
__global__ __launch_bounds__(256) void pool2_kernel(const float* __restrict__ pcolmax, const float* __restrict__ pcolmin,
    const float* __restrict__ prowmax, const float* __restrict__ prowmin,
    const float* __restrict__ lnw, const float* __restrict__ lnb, bf16* __restrict__ hbuf)
{
  int r = blockIdx.x, b = blockIdx.y, c = threadIdx.x;
  __shared__ float red[512];
  int p = r & 63;
  long src = (long)(b*64 + p)*C_ + c;
  float vmax = (r < 64) ? pcolmax[src] : prowmax[src];
  float vmin = (r < 64) ? pcolmin[src] : prowmin[src];
  float gw = lnw[c], gb = lnb[c];
  long row = (long)b*L_ + r, frow = (long)b*L_ + (127 - r);
  float s = vmax, s2 = vmax*vmax;
  bred2(s, s2, red);
  float m = s*(1.f/256.f), var = s2*(1.f/256.f) - m*m;
  float o = (vmax - m)*rsqrtf(vclamp(var))*gw + gb;
  hbuf[0*262144 + row*C_ + c]  = f2b(o);
  hbuf[2*262144 + frow*C_ + c] = f2b(o);
  s = vmin; s2 = vmin*vmin;
  bred2(s, s2, red);
  m = s*(1.f/256.f); var = s2*(1.f/256.f) - m*m;
  o = (vmin - m)*rsqrtf(vclamp(var))*gw + gb;
  hbuf[1*262144 + row*C_ + c]  = f2b(o);
  hbuf[3*262144 + frow*C_ + c] = f2b(o);
}

// ---------------- dwconvT on-the-fly helper ----------------------------------------
__device__ inline float dwconvT_at(const float* __restrict__ xp, const float* __restrict__ w, int i, int j)
{
  float acc = 0.f;
  #pragma unroll
  for (int ki = 0; ki < 3; ki++){
    int pi = i + ki - 1;
    if (pi < 0 || (pi & 1)) continue;
    int xi = pi >> 1;
    if (xi >= 64) continue;
    #pragma unroll
    for (int kj = 0; kj < 3; kj++){
      int pj = j + kj - 1;
      if (pj < 0 || (pj & 1)) continue;
      int xj = pj >> 1;
      if (xj >= 64) continue;
      acc += w[(2-ki)*3 + (2-kj)] * xp[xi*64 + xj];
    }
  }
  return acc;
}

// ---------------- z1raw = dwconvT(x) as bf16 + bn1 stats (one pass) ----------------
// grid (B*C), block 256.
__global__ __launch_bounds__(256) void dwz1_kernel(const float* __restrict__ x, const float* __restrict__ dw,
    bf16* __restrict__ z1, float* __restrict__ bn1sum, float* __restrict__ bn1sq)
{
  int bc = blockIdx.x; int c = bc & 255;
  int tid = threadIdx.x;
  __shared__ float xs[4096];
  const float* xp = x + (long)bc*4096;
  for (int it = 0; it < 16; it++) xs[it*256 + tid] = xp[it*256 + tid];
  float w[9];
  #pragma unroll
  for (int q = 0; q < 9; q++) w[q] = dw[c*9 + q];
  __syncthreads();
  bf16* zp = z1 + (long)bc*16384;
  float s = 0.f, s2 = 0.f;
  for (int it = 0; it < 64; it++){
    int p = it*256 + tid; int i = p >> 7, j = p & 127;
    float acc = dwconvT_at(xs, w, i, j);
    zp[p] = f2b(acc);
    s += acc; s2 += acc*acc;
  }
  __shared__ float red[512];
  bred2(s, s2, red);
  if (tid == 0){ atomicAdd(&bn1sum[c], s); atomicAdd(&bn1sq[c], s2); }
}

// ---------------- bn finalize: per-channel affine ----------------------------------
__global__ void fin_bn_kernel(const float* __restrict__ sum, const float* __restrict__ sq,
                              const float* __restrict__ g, const float* __restrict__ b,
                              float cnt_inv, float* __restrict__ a, float* __restrict__ d)
{
  int c = threadIdx.x;
  float m = sum[c]*cnt_inv;
  float v = sq[c]*cnt_inv - m*m;
  float aa = g[c] * rsqrtf(vclamp(v));
  a[c] = aa;
  d[c] = b[c] - m*aa;
}

// ---------------- fp32 -> bf16 weight convert --------------------------------------
__global__ void wcvt_kernel(const float* __restrict__ W, bf16* __restrict__ Wb, int n)
{
  int i = blockIdx.x*256 + threadIdx.x;
  if (i < n) Wb[i] = f2b(W[i]);
}

// ---------------- actz1: z1t[b][p][c] = bf16(relu(fa[c]*z1[b,c,p]+fd[c])) ----------
// grid (256, 4, B), block 256.
__global__ __launch_bounds__(256) void actz1_kernel(const bf16* __restrict__ z1,
    const float* __restrict__ fa, const float* __restrict__ fd, bf16* __restrict__ z1t)
{
  int p0 = blockIdx.x*64, c0 = blockIdx.y*64, b = blockIdx.z;
  int tid = threadIdx.x;
  __shared__ float t[64][65];
  #pragma unroll
  for (int q = 0; q < 2; q++){
    int cl = (tid >> 3) + q*32;
    int p8 = (tid & 7)*8;
    const bf16* src = &z1[((long)(b*C_ + c0 + cl))*16384 + p0 + p8];
    float a = fa[c0 + cl], d = fd[c0 + cl];
    bf16 v[8];
    *(uint4*)v = *(const uint4*)src;
    #pragma unroll
    for (int i = 0; i < 8; i++) t[p8 + i][cl] = fmaxf(b2f(v[i])*a + d, 0.f);
  }
  __syncthreads();
  #pragma unroll
  for (int q = 0; q < 2; q++){
    int pl = (tid >> 3) + q*32;
    int c8 = (tid & 7)*8;
    bf16 v[8];
    #pragma unroll
    for (int i = 0; i < 8; i++) v[i] = f2b(t[pl][c8 + i]);
    *(uint4*)&z1t[((long)b*16384 + p0 + pl)*256 + c0 + c8] = *(const uint4*)v;
  }
}

// ---------------- up-pw GEMM on MFMA: z2[b,o,p] = sum_c Wb[o,c]*z1t[b,p,c] ---------
// grid (256, B), block 256.
__global__ __launch_bounds__(256) void pwz_mfma_kernel(const bf16* __restrict__ z1t,
    const bf16* __restrict__ Wb, bf16* __restrict__ z2)
{
  int b = blockIdx.y;
  int p0 = blockIdx.x*64;
  int tid = threadIdx.x;
  int wave = tid >> 6, lane = tid & 63;
  int quad = lane >> 4, l16 = lane & 15;
  const bf16* zb = z1t + (long)b*16384*256;
  f32x4v acc[4][4];
  #pragma unroll
  for (int i = 0; i < 4; i++)
    #pragma unroll
    for (int j = 0; j < 4; j++) acc[i][j] = (f32x4v){0.f, 0.f, 0.f, 0.f};
  for (int k0 = 0; k0 < 256; k0 += 32){
    int c = k0 + quad*8;
    bf16x8v a[4], bb[4];
    #pragma unroll
    for (int ms = 0; ms < 4; ms++)
      a[ms] = *(const bf16x8v*)&Wb[(wave*64 + ms*16 + l16)*C_ + c];
    #pragma unroll
    for (int ns = 0; ns < 4; ns++)
      bb[ns] = *(const bf16x8v*)&zb[((long)(p0 + ns*16 + l16))*C_ + c];
    #pragma unroll
    for (int ms = 0; ms < 4; ms++)
      #pragma unroll
      for (int ns = 0; ns < 4; ns++)
        acc[ms][ns] = __builtin_amdgcn_mfma_f32_16x16x32_bf16(a[ms], bb[ns], acc[ms][ns], 0, 0, 0);
  }
  #pragma unroll
  for (int ms = 0; ms < 4; ms++){
    int o = wave*64 + ms*16 + quad*4;
    #pragma unroll
    for (int r = 0; r < 4; r++){
      long rowbase = ((long)(b*C_ + o + r))*16384 + p0;
      #pragma unroll
      for (int ns = 0; ns < 4; ns++)
        z2[rowbase + ns*16 + l16] = f2b(acc[ms][ns][r]);
    }
  }
}

// ---------------- in_proj GEMM on MFMA: xz[v][m][n] = sum_k hb[v][m][k]*Wi[n][k] ---
// M=1024, N=1024, K=256, bf16 out. grid (16, 4, 4), block 256.
__global__ __launch_bounds__(256) void inproj_mfma_kernel(const bf16* __restrict__ hb,
    const bf16* __restrict__ Wif, const bf16* __restrict__ Wib2, bf16* __restrict__ xz)
{
  int v = blockIdx.z;
  int m0 = blockIdx.y*256, n0 = blockIdx.x*64;
  const bf16* A = hb + (long)v*262144;
  const bf16* W = (v >= 2) ? Wib2 : Wif;
  bf16* out = xz + (long)v*1048576;
  int tid = threadIdx.x;
  int wave = tid >> 6, lane = tid & 63;
  int quad = lane >> 4, l16 = lane & 15;
  f32x4v acc[4][4];
  #pragma unroll
  for (int i = 0; i < 4; i++)
    #pragma unroll
    for (int j = 0; j < 4; j++) acc[i][j] = (f32x4v){0.f, 0.f, 0.f, 0.f};
  for (int k0 = 0; k0 < 256; k0 += 32){
    int c = k0 + quad*8;
    bf16x8v a[4], bb[4];
    #pragma unroll
    for (int ms = 0; ms < 4; ms++)
      a[ms] = *(const bf16x8v*)&A[(long)(m0 + wave*64 + ms*16 + l16)*256 + c];
    #pragma unroll
    for (int ns = 0; ns < 4; ns++)
      bb[ns] = *(const bf16x8v*)&W[(long)(n0 + ns*16 + l16)*256 + c];
    #pragma unroll
    for (int ms = 0; ms < 4; ms++)
      #pragma unroll
      for (int ns = 0; ns < 4; ns++)
        acc[ms][ns] = __builtin_amdgcn_mfma_f32_16x16x32_bf16(a[ms], bb[ns], acc[ms][ns], 0, 0, 0);
  }
  #pragma unroll
  for (int ms = 0; ms < 4; ms++){
    int m = m0 + wave*64 + ms*16 + quad*4;
    #pragma unroll
    for (int r = 0; r < 4; r++){
      long rowbase = (long)(m + r)*1024 + n0;
      #pragma unroll
      for (int ns = 0; ns < 4; ns++)
        out[rowbase + ns*16 + l16] = f2b(acc[ms][ns][r]);
    }
  }
}

// ---------------- x_proj GEMM on MFMA: dbl[v][m][n] = sum_k u[v][m][k]*Wx[n][k] ----
// M=1024, N=48, K=512. grid (4 mtile, 4 v), block 256.
__global__ __launch_bounds__(256) void xproj_mfma_kernel(const bf16* __restrict__ ub,
    const bf16* __restrict__ Wxf, const bf16* __restrict__ Wxb, float* __restrict__ dblb)
{
  int v = blockIdx.y;
  int m0 = blockIdx.x*256;
  const bf16* A = ub + (long)v*524288;
  const bf16* W = (v >= 2) ? Wxb : Wxf;
  float* out = dblb + (long)v*49152;
  int tid = threadIdx.x;
  int wave = tid >> 6, lane = tid & 63;
  int quad = lane >> 4, l16 = lane & 15;
  f32x4v acc[4][3];
  #pragma unroll
  for (int i = 0; i < 4; i++)
    #pragma unroll
    for (int j = 0; j < 3; j++) acc[i][j] = (f32x4v){0.f, 0.f, 0.f, 0.f};
  for (int k0 = 0; k0 < 512; k0 += 32){
    int c = k0 + quad*8;
    bf16x8v a[4], bb[3];
    #pragma unroll
    for (int ms = 0; ms < 4; ms++)
      a[ms] = *(const bf16x8v*)&A[(long)(m0 + wave*64 + ms*16 + l16)*512 + c];
    #pragma unroll
    for (int ns = 0; ns < 3; ns++)
      bb[ns] = *(const bf16x8v*)&W[(long)(ns*16 + l16)*512 + c];
    #pragma unroll
    for (int ms = 0; ms < 4; ms++)
      #pragma unroll
      for (int ns = 0; ns < 3; ns++)
        acc[ms][ns] = __builtin_amdgcn_mfma_f32_16x16x32_bf16(a[ms], bb[ns], acc[ms][ns], 0, 0, 0);
  }
  #pragma unroll
  for (int ms = 0; ms < 4; ms++){
    int m = m0 + wave*64 + ms*16 + quad*4;
    #pragma unroll
    for (int r = 0; r < 4; r++){
      long rowbase = (long)(m + r)*48;
      #pragma unroll
      for (int ns = 0; ns < 3; ns++)
        out[rowbase + ns*16 + l16] = acc[ms][ns][r];
    }
  }
}

// ---------------- out_proj GEMM on MFMA: mout[v][m][n] = sum_k y[v][m][k]*Wo[n][k] -
// M=1024, N=256, K=512. grid (4 ntile, 4 mtile, 4 v), block 256.
__global__ __launch_bounds__(256) void outproj_mfma_kernel(const bf16* __restrict__ yb,
    const bf16* __restrict__ Wof, const bf16* __restrict__ Wob, float* __restrict__ mo)
{
  int v = blockIdx.z;
  int m0 = blockIdx.y*256, n0 = blockIdx.x*64;
  const bf16* A = yb + (long)v*524288;
  const bf16* W = (v >= 2) ? Wob : Wof;
  float* out = mo + (long)v*262144;
  int tid = threadIdx.x;
  int wave = tid >> 6, lane = tid & 63;
  int quad = lane >> 4, l16 = lane & 15;
  f32x4v acc[4][4];
  #pragma unroll
  for (int i = 0; i < 4; i++)
    #pragma unroll
    for (int j = 0; j < 4; j++) acc[i][j] = (f32x4v){0.f, 0.f, 0.f, 0.f};
  for (int k0 = 0; k0 < 512; k0 += 32){
    int c = k0 + quad*8;
    bf16x8v a[4], bb[4];
    #pragma unroll
    for (int ms = 0; ms < 4; ms++)
      a[ms] = *(const bf16x8v*)&A[(long)(m0 + wave*64 + ms*16 + l16)*512 + c];
    #pragma unroll
    for (int ns = 0; ns < 4; ns++)
      bb[ns] = *(const bf16x8v*)&W[(long)(n0 + ns*16 + l16)*512 + c];
    #pragma unroll
    for (int ms = 0; ms < 4; ms++)
      #pragma unroll
      for (int ns = 0; ns < 4; ns++)
        acc[ms][ns] = __builtin_amdgcn_mfma_f32_16x16x32_bf16(a[ms], bb[ns], acc[ms][ns], 0, 0, 0);
  }
  #pragma unroll
  for (int ms = 0; ms < 4; ms++){
    int m = m0 + wave*64 + ms*16 + quad*4;
    #pragma unroll
    for (int r = 0; r < 4; r++){
      long rowbase = (long)(m + r)*256 + n0;
      #pragma unroll
      for (int ns = 0; ns < 4; ns++)
        out[rowbase + ns*16 + l16] = acc[ms][ns][r];
    }
  }
}

// ---------------- proj GEMM on MFMA: respre[z][m][n] = sum_k cb[z][m][k]*Wp[n][k]+b -
// M=1024, N=256, K=512, z=2. grid (4 ntile, 4 mtile, 2), block 256.
__global__ __launch_bounds__(256) void pj_mfma_kernel(const bf16* __restrict__ cb,
    const bf16* __restrict__ Wp, const float* __restrict__ pb, float* __restrict__ rp)
{
  int z = blockIdx.z;
  int m0 = blockIdx.y*256, n0 = blockIdx.x*64;
  const bf16* A = cb + (long)z*524288;
  float* out = rp + (long)z*262144;
  int tid = threadIdx.x;
  int wave = tid >> 6, lane = tid & 63;
  int quad = lane >> 4, l16 = lane & 15;
  f32x4v acc[4][4];
  #pragma unroll
  for (int i = 0; i < 4; i++)
    #pragma unroll
    for (int j = 0; j < 4; j++) acc[i][j] = (f32x4v){0.f, 0.f, 0.f, 0.f};
  for (int k0 = 0; k0 < 512; k0 += 32){
    int c = k0 + quad*8;
    bf16x8v a[4], bb[4];
    #pragma unroll
    for (int ms = 0; ms < 4; ms++)
      a[ms] = *(const bf16x8v*)&A[(long)(m0 + wave*64 + ms*16 + l16)*512 + c];
    #pragma unroll
    for (int ns = 0; ns < 4; ns++)
      bb[ns] = *(const bf16x8v*)&Wp[(long)(n0 + ns*16 + l16)*512 + c];
    #pragma unroll
    for (int ms = 0; ms < 4; ms++)
      #pragma unroll
      for (int ns = 0; ns < 4; ns++)
        acc[ms][ns] = __builtin_amdgcn_mfma_f32_16x16x32_bf16(a[ms], bb[ns], acc[ms][ns], 0, 0, 0);
  }
  #pragma unroll
  for (int ms = 0; ms < 4; ms++){
    int m = m0 + wave*64 + ms*16 + quad*4;
    #pragma unroll
    for (int r = 0; r < 4; r++){
      long rowbase = (long)(m + r)*256 + n0;
      #pragma unroll
      for (int ns = 0; ns < 4; ns++)
        out[rowbase + ns*16 + l16] = acc[ms][ns][r] + pb[n0 + ns*16 + l16];
    }
  }
}

// ---------------- per-channel stats of bf16 tensor (B,C,16384) ---------------------
// grid (C, B), block 256
__global__ __launch_bounds__(256) void chstats_kernel(const bf16* __restrict__ t,
                                                      float* __restrict__ sum, float* __restrict__ sq)
{
  int c = blockIdx.x, b = blockIdx.y, tid = threadIdx.x;
  const bf16* p = t + ((long)(b*C_ + c))*16384;
  float s = 0.f, s2 = 0.f;
  for (int it = 0; it < 64; it++){ float v = b2f(p[it*256 + tid]); s += v; s2 += v*v; }
  __shared__ float red[512];
  bred2(s, s2, red);
  if (tid == 0){ atomicAdd(&sum[c], s); atomicAdd(&sq[c], s2); }
}

// ---------------- generic GEMM (kept for dt-proj only) -----------------------------
// grid ((N+63)/64, (M+63)/64, nbatch), block 256
__global__ __launch_bounds__(256) void gemm_kernel(
  const float* __restrict__ Abase, long sA, int lda,
  const float* __restrict__ W0, const float* __restrict__ W1,
  const float* __restrict__ bias0, const float* __restrict__ bias1, int wsplit,
  float* __restrict__ Cbase, long sC, int ldc,
  int M, int N, int K, int act)
{
  int z = blockIdx.z;
  const float* A = Abase + (long)z*sA;
  float* Cp = Cbase + (long)z*sC;
  const float* W = (z >= wsplit) ? W1 : W0;
  const float* bias = (z >= wsplit) ? bias1 : bias0;
  int m0 = blockIdx.y*64, n0 = blockIdx.x*64;
  __shared__ __align__(16) float As[16][68];
  __shared__ __align__(16) float Ws[16][68];
  int tid = threadIdx.x, tx = tid & 15, ty = tid >> 4;
  float acc[4][4] = {};
  for (int k0 = 0; k0 < K; k0 += 16){
    #pragma unroll
    for (int q = 0; q < 4; q++){
      int e = tid + q*256; int r = e >> 4, kk = e & 15;
      int mi = m0 + r, ki = k0 + kk;
      As[kk][r] = (mi < M && ki < K) ? A[(long)mi*lda + ki] : 0.f;
    }
    #pragma unroll
    for (int q = 0; q < 4; q++){
      int e = tid + q*256; int n = e >> 4, kk = e & 15;
      int ni = n0 + n, ki = k0 + kk;
      Ws[kk][n] = (ni < N && ki < K) ? W[(long)ni*K + ki] : 0.f;
    }
    __syncthreads();
    #pragma unroll
    for (int kk = 0; kk < 16; kk++){
      float4 a4 = *(const float4*)&As[kk][ty*4];
      float4 b4 = *(const float4*)&Ws[kk][tx*4];
      float av[4] = {a4.x, a4.y, a4.z, a4.w};
      float bv[4] = {b4.x, b4.y, b4.z, b4.w};
      #pragma unroll
      for (int mm = 0; mm < 4; mm++)
        #pragma unroll
        for (int nn = 0; nn < 4; nn++) acc[mm][nn] += av[mm]*bv[nn];
    }
    __syncthreads();
  }
  #pragma unroll
  for (int mm = 0; mm < 4; mm++){
    int mi = m0 + ty*4 + mm;
    if (mi >= M) continue;
    #pragma unroll
    for (int nn = 0; nn < 4; nn++){
      int ni = n0 + tx*4 + nn;
      if (ni >= N) continue;
      float v = acc[mm][nn];
      if (bias) v += bias[ni];
      if (act == 2) v = softplusf(v);
      Cp[(long)mi*ldc + ni] = v;
    }
  }
}

// ---------------- depthwise causal conv1d (k=4) + silu, bf16 in/out ----------------
// grid (L, B, 4), block 512
__global__ __launch_bounds__(512) void conv1d_kernel(const bf16* __restrict__ xzb,
    const float* __restrict__ fw, const float* __restrict__ fb,
    const float* __restrict__ bw, const float* __restrict__ bb,
    bf16* __restrict__ ub)
{
  int l = blockIdx.x, b = blockIdx.y, v = blockIdx.z, d = threadIdx.x;
  const bf16* xm = xzb + (long)v*1024*1024;
  const float* w  = (v < 2) ? fw : bw;
  const float* cb = (v < 2) ? fb : bb;
  float acc = cb[d];
  #pragma unroll
  for (int k = 0; k < 4; k++){
    int ll = l - 3 + k;
    if (ll >= 0) acc += b2f(xm[(long)(b*L_ + ll)*1024 + d]) * w[d*4 + k];
  }
  ub[(long)v*1024*512 + (long)(b*L_ + l)*512 + d] = f2b(siluf(acc));
}

// ---------------- selective scan (4-way state split, all-LDS, 1024 waves) ----------
// Lanes: dd = lane&15 selects d, qtr = lane>>4 selects 4-state group; dt/u/zg LDS
// reads broadcast; B/C read as bf16x4; merges via shfl_xor(16)+shfl_xor(32).
// grid (32, B, 4), block 64.
__global__ __launch_bounds__(64) void scan_kernel(const float* __restrict__ dtb, const bf16* __restrict__ ub,
    const float* __restrict__ dblb, const bf16* __restrict__ xzb,
    const float* __restrict__ fAlog, const float* __restrict__ fD,
    const float* __restrict__ bAlog, const float* __restrict__ bD,
    bf16* __restrict__ yb)
{
  int v = blockIdx.z, b = blockIdx.y;
  int tid = threadIdx.x;
  int dd = tid & 15, qtr = tid >> 4;
  int d0 = blockIdx.x*16;
  int d = d0 + dd;
  const float* dt  = dtb  + (long)v*1024*512;
  const bf16*  u   = ub   + (long)v*1024*512;
  const float* dbl = dblb + (long)v*1024*48;
  const bf16*  zg  = xzb  + (long)v*1024*1024 + 512;
  const float* Alog = (v < 2) ? fAlog : bAlog;
  const float* Dp   = (v < 2) ? fD : bD;
  __shared__ bf16 sdt[2048], su[2048], szg[2048];          // [l][16]
  __shared__ __align__(16) bf16 sbc[4096];                 // [l][0..15]=B,[16..31]=C
  long row = (long)b*L_;
  for (int idx = tid; idx < 2048; idx += 64){
    int l = idx >> 4, j = idx & 15;
    sdt[idx] = f2b(dt[(row + l)*512 + d0 + j]);
    su [idx] = u[(row + l)*512 + d0 + j];
    szg[idx] = zg[(row + l)*1024 + d0 + j];
  }
  for (int idx = tid; idx < 4096; idx += 64){
    int l = idx >> 5, j = idx & 31;
    sbc[idx] = f2b(dbl[(row + l)*48 + 16 + j]);
  }
  float a2[4];
  #pragma unroll
  for (int n = 0; n < 4; n++) a2[n] = -expf(Alog[d*16 + qtr*4 + n]) * 1.44269504f;
  float Dv = Dp[d];
  float h[4];
  #pragma unroll
  for (int n = 0; n < 4; n++) h[n] = 0.f;
  __syncthreads();
  bf16* yo = yb + (long)v*1024*512;
  for (int l = 0; l < 128; l++){
    float dtv = b2f(sdt[l*16 + dd]);
    float uv  = b2f(su [l*16 + dd]);
    float zgv = b2f(szg[l*16 + dd]);
    bf16x4v Bv = *(const bf16x4v*)&sbc[l*32 + qtr*4];
    bf16x4v Cv = *(const bf16x4v*)&sbc[l*32 + 16 + qtr*4];
    float dtu = dtv*uv;
    float acc = 0.f;
    #pragma unroll
    for (int n = 0; n < 4; n++){
      float dA = exp2f(dtv*a2[n]);
      bf16 tb; *(short*)&tb = Bv[n];
      bf16 tc; *(short*)&tc = Cv[n];
      h[n] = dA*h[n] + dtu*b2f(tb);
      acc += h[n]*b2f(tc);
    }
    acc += __shfl_xor(acc, 16);
    acc += __shfl_xor(acc, 32);
    if (qtr == 0)
      yo[(row + l)*512 + d] = f2b((acc + Dv*uv) * siluf(zgv));
  }
}

// ---------------- LayerNorm over C: mode 1 -> bf16 concat; mode 0 -> fp32 copy -----
// grid (128, B, NV), block 256
__global__ __launch_bounds__(256) void ln_kernel(const float* __restrict__ inb, bf16* __restrict__ outb0,
    bf16* __restrict__ outb1, float* __restrict__ outf,
    const float* __restrict__ lnw, const float* __restrict__ lnb, int mode)
{
  int r = blockIdx.x, b = blockIdx.y, v = blockIdx.z, c = threadIdx.x;
  long row = (long)b*L_ + r;
  float val = inb[((long)v*1024 + row)*C_ + c];
  __shared__ float red[512];
  float s = val, s2 = val*val;
  bred2(s, s2, red);
  float m = s*(1.f/256.f), var = s2*(1.f/256.f) - m*m;
  float o = (val - m)*rsqrtf(vclamp(var))*lnw[c] + lnb[c];
  if (mode == 1){
    long frow = (long)b*L_ + (127 - r);
    if (v == 0)      outb0[row*512 + c] = f2b(o);
    else if (v == 1) outb1[row*512 + c] = f2b(o);
    else if (v == 2) outb0[frow*512 + 256 + c] = f2b(o);
    else             outb1[frow*512 + 256 + c] = f2b(o);
  } else {
    outf[((long)v*1024 + row)*C_ + c] = o;
  }
}

// ---------------- hsig(rm+rn)*clip(bn2(z2)) + gn stats; resq IN-PLACE in z2 --------
// grid (C, B), block 256
__global__ __launch_bounds__(256) void hsig_kernel(bf16* __restrict__ z2, const float* __restrict__ rm,
    const float* __restrict__ rn, const float* __restrict__ a2, const float* __restrict__ d2,
    float* __restrict__ gnsum, float* __restrict__ gnsq)
{
  int c = blockIdx.x, b = blockIdx.y, tid = threadIdx.x;
  __shared__ float rms[128], rns[128];
  if (tid < 128){
    rms[tid] = rm[(long)(b*L_ + tid)*C_ + c];
    rns[tid] = rn[(long)(b*L_ + tid)*C_ + c];
  }
  __syncthreads();
  float aa = a2[c], dd = d2[c];
  bf16* zp = z2 + ((long)(b*C_ + c))*16384;
  float s = 0.f, s2 = 0.f;
  for (int g = 0; g < 16; g++){
    float tv[4]; int wq[4];
    #pragma unroll
    for (int q = 0; q < 4; q++){
      int p = g*1024 + q*256 + tid; int i = p >> 7, j = p & 127;
      float zv = b2f(zp[p])*aa + dd;
      zv = fminf(fmaxf(zv, 0.f), 6.f);
      float gate = rms[i] + rns[j];
      gate = fminf(fmaxf(gate + 3.f, 0.f), 6.f) * (1.f/6.f);
      float t = gate*zv;
      s += t; s2 += t*t;
      tv[q] = t;
      wq[q] = (((i | j) & 1) == 0) ? ((i >> 1)*64 + (j >> 1)) : -1;
    }
    __syncthreads();
    #pragma unroll
    for (int q = 0; q < 4; q++)
      if (wq[q] >= 0) zp[wq[q]] = f2b(tv[q]);
  }
  __shared__ float red[512];
  bred2(s, s2, red);
  if (tid == 0){ atomicAdd(&gnsum[b*32 + (c >> 3)], s); atomicAdd(&gnsq[b*32 + (c >> 3)], s2); }
}

// ---------------- gn finalize to per-(b,c) affine ----------------------------------
// grid (B), block 256
__global__ void fin_gn_kernel(const float* __restrict__ gnsum, const float* __restrict__ gnsq,
                              const float* __restrict__ g, const float* __restrict__ bb,
                              float* __restrict__ gnA, float* __restrict__ gnD)
{
  int b = blockIdx.x, c = threadIdx.x, gr = c >> 3;
  float inv_cnt = 1.f/131072.f;
  float m = gnsum[b*32 + gr]*inv_cnt;
  float v = gnsq[b*32 + gr]*inv_cnt - m*m;
  float inv = rsqrtf(vclamp(v));
  float A = inv*g[c];
  gnA[b*C_ + c] = A;
  gnD[b*C_ + c] = bb[c] - m*A;
}

// ---------------- trd: rqt[b][s][c] = bf16(gnA*resq[b,c,s]+gnD) --------------------
// grid (64, 4, B), block 256.
__global__ __launch_bounds__(256) void trd_kernel(const bf16* __restrict__ z2,
    const float* __restrict__ gnA, const float* __restrict__ gnD, bf16* __restrict__ rqt)
{
  int p0 = blockIdx.x*64, c0 = blockIdx.y*64, b = blockIdx.z;
  int tid = threadIdx.x;
  __shared__ float t[64][65];
  #pragma unroll
  for (int q = 0; q < 2; q++){
    int cl = (tid >> 3) + q*32;
    int p8 = (tid & 7)*8;
    int c = c0 + cl;
    const bf16* src = &z2[((long)(b*C_ + c))*16384 + p0 + p8];
    float a = gnA[b*C_ + c], dd = gnD[b*C_ + c];
    bf16 v[8];
    *(uint4*)v = *(const uint4*)src;
    #pragma unroll
    for (int i = 0; i < 8; i++) t[p8 + i][cl] = b2f(v[i])*a + dd;
  }
  __syncthreads();
  #pragma unroll
  for (int q = 0; q < 2; q++){
    int pl = (tid >> 3) + q*32;
    int c8 = (tid & 7)*8;
    bf16 v[8];
    #pragma unroll
    for (int i = 0; i < 8; i++) v[i] = f2b(t[pl][c8 + i]);
    *(uint4*)&rqt[((long)b*4096 + p0 + pl)*256 + c0 + c8] = *(const uint4*)v;
  }
}

// ---------------- down-pw GEMM on MFMA -> fp32 d_out -------------------------------
// grid (64, B), block 256.
__global__ __launch_bounds__(256) void pwdown_mfma_kernel(const bf16* __restrict__ rqt,
    const bf16* __restrict__ Wb, float* __restrict__ out)
{
  int b = blockIdx.y;
  int p0 = blockIdx.x*64;
  int tid = threadIdx.x;
  int wave = tid >> 6, lane = tid & 63;
  int quad = lane >> 4, l16 = lane & 15;
  const bf16* zb = rqt + (long)b*4096*256;
  f32x4v acc[4][4];
  #pragma unroll
  for (int i = 0; i < 4; i++)
    #pragma unroll
    for (int j = 0; j < 4; j++) acc[i][j] = (f32x4v){0.f, 0.f, 0.f, 0.f};
  for (int k0 = 0; k0 < 256; k0 += 32){
    int c = k0 + quad*8;
    bf16x8v a[4], bb[4];
    #pragma unroll
    for (int ms = 0; ms < 4; ms++)
      a[ms] = *(const bf16x8v*)&Wb[(wave*64 + ms*16 + l16)*C_ + c];
    #pragma unroll
    for (int ns = 0; ns < 4; ns++)
      bb[ns] = *(const bf16x8v*)&zb[((long)(p0 + ns*16 + l16))*C_ + c];
    #pragma unroll
    for (int ms = 0; ms < 4; ms++)
      #pragma unroll
      for (int ns = 0; ns < 4; ns++)
        acc[ms][ns] = __builtin_amdgcn_mfma_f32_16x16x32_bf16(a[ms], bb[ns], acc[ms][ns], 0, 0, 0);
  }
  #pragma unroll
  for (int ms = 0; ms < 4; ms++){
    int o = wave*64 + ms*16 + quad*4;
    #pragma unroll
    for (int r = 0; r < 4; r++){
      long rowbase = ((long)(b*C_ + o + r))*4096 + p0;
      #pragma unroll
      for (int ns = 0; ns < 4; ns++)
        out[rowbase + ns*16 + l16] = acc[ms][ns][r];
    }
  }
}

// ---------------- 5 moments per (b,c): sum d, d^2, x, x^2, dx ----------------------
// grid (C, B), block 256
__global__ __launch_bounds__(256) void stat5_kernel(const float* __restrict__ dbuf, const float* __restrict__ x,
                                                    float* __restrict__ s5)
{
  int c = blockIdx.x, b = blockIdx.y, tid = threadIdx.x;
  const float* dp = dbuf + ((long)(b*C_ + c))*4096;
  const float* xp = x + ((long)(b*C_ + c))*4096;
  float sd = 0, sd2 = 0, sx = 0, sx2 = 0, sdx = 0;
  for (int it = 0; it < 16; it++){
    float d = dp[it*256 + tid];
    float xv = xp[it*256 + tid];
    sd += d; sd2 += d*d; sx += xv; sx2 += xv*xv; sdx += d*xv;
  }
  __shared__ float red[256];
  float r0 = bred1(sd, red); float r1 = bred1(sd2, red); float r2 = bred1(sx, red);
  float r3 = bred1(sx2, red); float r4 = bred1(sdx, red);
  if (tid == 0){
    float* o = s5 + (long)(b*C_ + c)*5;
    o[0] = r0; o[1] = r1; o[2] = r2; o[3] = r3; o[4] = r4;
  }
}

// ---------------- collapse bn -> gn -> (+x) -> gn into out = P*d + Q*x + R ---------
// grid (B), block 256
__global__ void coeff_kernel(const float* __restrict__ s5, const float* __restrict__ dbn_g, const float* __restrict__ dbn_b,
                             const float* __restrict__ gn_g, const float* __restrict__ gn_b, float* __restrict__ pqr)
{
  int b = blockIdx.x, c = threadIdx.x, g = c >> 3;
  float sd = 0, sd2 = 0;
  for (int bb = 0; bb < 8; bb++){ sd += s5[(long)(bb*C_ + c)*5 + 0]; sd2 += s5[(long)(bb*C_ + c)*5 + 1]; }
  float inv_cnt = 1.f/32768.f;
  float mB = sd*inv_cnt;
  float vB = sd2*inv_cnt - mB*mB;
  float ab = dbn_g[c] * rsqrtf(vclamp(vB));
  float db = dbn_b[c] - mB*ab;
  const float* s = s5 + (long)(b*C_ + c)*5;
  float inv_n = 1.f/4096.f;
  float m = s[0]*inv_n, Ed2 = s[1]*inv_n, mx = s[2]*inv_n, Ex2 = s[3]*inv_n, Edx = s[4]*inv_n;
  float Ev = ab*m + db;
  float Ev2 = ab*ab*Ed2 + 2.f*ab*db*m + db*db;
  __shared__ float e1[256], e2[256];
  e1[c] = Ev; e2[c] = Ev2;
  __syncthreads();
  float m1 = 0, q1 = 0;
  for (int k = 0; k < 8; k++){ m1 += e1[(g << 3) + k]; q1 += e2[(g << 3) + k]; }
  m1 *= 0.125f; q1 *= 0.125f;
  float inv1 = rsqrtf(vclamp(q1 - m1*m1));
  float gg = gn_g[c];
  float A1 = inv1*gg;
  float D1 = gn_b[c] - m1*A1;
  float al = A1*ab;
  float be = A1*db + D1;
  float Et = al*m + be + mx;
  float Et2 = al*al*Ed2 + 2.f*al*be*m + be*be + 2.f*al*Edx + 2.f*be*mx + Ex2;
  __syncthreads();
  e1[c] = Et; e2[c] = Et2;
  __syncthreads();
  float m2 = 0, q2 = 0;
  for (int k = 0; k < 8; k++){ m2 += e1[(g << 3) + k]; q2 += e2[(g << 3) + k]; }
  m2 *= 0.125f; q2 *= 0.125f;
  float inv2 = rsqrtf(vclamp(q2 - m2*m2));
  float G = inv2*gg;
  float* o = pqr + (long)(b*C_ + c)*3;
  o[0] = G*al;
  o[1] = G;
  o[2] = G*(be - m2) + gn_b[c];
}

// ---------------- final elementwise: out = P*out + Q*x + R (in-place on d_out) -----
// grid (C, B), block 256
__global__ __launch_bounds__(256) void final_kernel(const float* __restrict__ x,
    const float* __restrict__ pqr, float* __restrict__ out)
{
  int c = blockIdx.x, b = blockIdx.y, tid = threadIdx.x;
  const float* o = pqr + (long)(b*C_ + c)*3;
  float P = o[0], Q = o[1], R = o[2];
  long base = ((long)(b*C_ + c))*4096;
  for (int it = 0; it < 16; it++){
    long idx = base + it*256 + tid;
    out[idx] = P*out[idx] + Q*x[idx] + R;
  }
}

extern "C" void kernel_launch(void* const* d_in, const int* in_sizes, int n_in,
                              void* d_out, int out_size, void* d_ws, size_t ws_size,
                              hipStream_t stream)
{
  (void)in_sizes; (void)n_in; (void)out_size; (void)ws_size;
  // ALL inputs/outputs are float32.
  const float* x         = (const float*)d_in[0];
  const float* pos       = (const float*)d_in[1];
  const float* ln_w      = (const float*)d_in[2];
  const float* ln_b      = (const float*)d_in[3];
  const float* proj_w    = (const float*)d_in[4];
  const float* proj_b    = (const float*)d_in[5];
  const float* up_dw_w   = (const float*)d_in[6];
  const float* up_bn1_g  = (const float*)d_in[7];
  const float* up_bn1_b  = (const float*)d_in[8];
  const float* up_pw_w   = (const float*)d_in[9];
  const float* up_bn2_g  = (const float*)d_in[10];
  const float* up_bn2_b  = (const float*)d_in[11];
  const float* down_pw_w = (const float*)d_in[12];
  const float* down_bn_g = (const float*)d_in[13];
  const float* down_bn_b = (const float*)d_in[14];
  const float* gn_g      = (const float*)d_in[15];
  const float* gn_b      = (const float*)d_in[16];
  const float* f_in_w    = (const float*)d_in[17];
  const float* f_conv_w  = (const float*)d_in[18];
  const float* f_conv_b  = (const float*)d_in[19];
  const float* f_xproj_w = (const float*)d_in[20];
  const float* f_dt_w    = (const float*)d_in[21];
  const float* f_dt_b    = (const float*)d_in[22];
  const float* f_Alog    = (const float*)d_in[23];
  const float* f_D       = (const float*)d_in[24];
  const float* f_out_w   = (const float*)d_in[25];
  const float* b_in_w    = (const float*)d_in[26];
  const float* b_conv_w  = (const float*)d_in[27];
  const float* b_conv_b  = (const float*)d_in[28];
  const float* b_xproj_w = (const float*)d_in[29];
  const float* b_dt_w    = (const float*)d_in[30];
  const float* b_dt_b    = (const float*)d_in[31];
  const float* b_Alog    = (const float*)d_in[32];
  const float* b_D       = (const float*)d_in[33];
  const float* b_out_w   = (const float*)d_in[34];

  // ======== workspace layout, PEAK = 132MB ========
  char* sb = (char*)d_ws;
  float* statz = (float*)(sb);               // 1536 f (zeroed each launch)
  float* abn   = (float*)(sb + 8192);        // 1024 f
  float* gnAD  = (float*)(sb + 16384);       // 4096 f
  float* stat5 = (float*)(sb + 65536);       // 10240 f
  float* pqr   = (float*)(sb + 131072);      // 6144 f
  float* rmrn  = (float*)(sb + 1*MB);        // 2MB: 2 x (1024,256)
  bf16*  Wbbuf = (bf16*)(sb + 3*MB);         // 128KB: up_pw_w bf16
  bf16*  Wb2buf= (bf16*)(sb + 3*MB + 262144);// 128KB: down_pw_w bf16
  bf16*  Wpb   = (bf16*)(sb + 3*MB + 524288);// 256KB: proj_w bf16
  char* big = sb + 4*MB;
  float* pool4  = (float*)(big + 0*MB);      // 2 MB
  bf16*  hbufb  = (bf16*)(big + 2*MB);       // 2 MB: 4 x (B*L,C) bf16
  bf16*  Wif    = (bf16*)(big + 4*MB);       // 512KB: f_in_w bf16
  bf16*  Wib2   = (bf16*)(big + 4*MB + 524288); // 512KB: b_in_w bf16
  bf16*  Wxf    = (bf16*)(big + 5*MB);           // 48KB: f_xproj_w bf16
  bf16*  Wxb    = (bf16*)(big + 5*MB + 65536);   // 48KB: b_xproj_w bf16
  bf16*  Wof    = (bf16*)(big + 5*MB + 131072);  // 256KB: f_out_w bf16
  bf16*  Wob    = (bf16*)(big + 5*MB + 393216);  // 256KB: b_out_w bf16
  bf16*  xzbuf  = (bf16*)(big + 6*MB);       // 8 MB: 4 x (1024,1024) bf16
  bf16*  ubuf   = (bf16*)(big + 22*MB);      // 4 MB: 4 x (1024,512) bf16
  float* dblbuf = (float*)(big + 30*MB);     // 768 KB
  float* dtbuf  = (float*)(big + 31*MB);     // 8 MB
  bf16*  ybuf   = (bf16*)(big + 39*MB);      // 4 MB: 4 x (1024,512) bf16
  float* mout   = (float*)(big + 47*MB);     // 4 MB
  bf16*  cbufb  = (bf16*)(big + 51*MB);      // 2 MB: 2 x (1024,512) bf16
  float* respre = (float*)(big + 55*MB);     // 2 MB  (ends at 57MB < 64MB)
  bf16*  z1buf  = (bf16*)(big);              // 64 MiB bf16, c-major (phase 2a)
  bf16*  z2buf  = (bf16*)(big);              // 64 MiB bf16 (phase 2b/3; z1 dead)
  bf16*  z1tbuf = (bf16*)(sb + 68*MB);       // 64 MiB bf16, p-major (phase 2)
  bf16*  rqtbuf = (bf16*)(sb + 68*MB);       // 16 MiB bf16, p-major (phase 3)
  float* dbuf   = (float*)d_out;             // 32 MB fp32 (phase 3)

  float* bn1sum = statz;        float* bn1sq = statz + 256;
  float* bn2sum = statz + 512;  float* bn2sq = statz + 768;
  float* gnsum  = statz + 1024; float* gnsq  = statz + 1280;
  float* abn1 = abn;       float* dbn1 = abn + 256;
  float* abn2 = abn + 512; float* dbn2 = abn + 768;
  float* gnA = gnAD;       float* gnD = gnAD + 2048;
  float* pcolmax = pool4;
  float* pcolmin = pool4 + 131072;
  float* prowmax = pool4 + 262144;
  float* prowmin = pool4 + 393216;

  hipMemsetAsync(statz, 0, 1536*sizeof(float), stream);

  // ---- phase 1: pooling + LN + mamba x4 (f/b x max/min) -> rmrn ----
  pool1_kernel<<<dim3(256, 8), 64, 0, stream>>>(x, pos, pcolmax, pcolmin, prowmax, prowmin);
  pool2_kernel<<<dim3(128, 8), 256, 0, stream>>>(pcolmax, pcolmin, prowmax, prowmin, ln_w, ln_b, hbufb);
  wcvt_kernel<<<1024, 256, 0, stream>>>(f_in_w, Wif, 262144);
  wcvt_kernel<<<1024, 256, 0, stream>>>(b_in_w, Wib2, 262144);
  wcvt_kernel<<<96, 256, 0, stream>>>(f_xproj_w, Wxf, 24576);
  wcvt_kernel<<<96, 256, 0, stream>>>(b_xproj_w, Wxb, 24576);
  wcvt_kernel<<<512, 256, 0, stream>>>(f_out_w, Wof, 131072);
  wcvt_kernel<<<512, 256, 0, stream>>>(b_out_w, Wob, 131072);
  wcvt_kernel<<<512, 256, 0, stream>>>(proj_w, Wpb, 131072);
  inproj_mfma_kernel<<<dim3(16, 4, 4), 256, 0, stream>>>(hbufb, Wif, Wib2, xzbuf);
  conv1d_kernel<<<dim3(128, 8, 4), 512, 0, stream>>>(xzbuf, f_conv_w, f_conv_b, b_conv_w, b_conv_b, ubuf);
  xproj_mfma_kernel<<<dim3(4, 4), 256, 0, stream>>>(ubuf, Wxf, Wxb, dblbuf);
  gemm_kernel<<<dim3(8, 16, 4), 256, 0, stream>>>(dblbuf, 49152, 48, f_dt_w, b_dt_w, f_dt_b, b_dt_b, 2,
                                                  dtbuf, 524288, 512, 1024, 512, 16, 2);
  scan_kernel<<<dim3(32, 8, 4), 64, 0, stream>>>(dtbuf, ubuf, dblbuf, xzbuf, f_Alog, f_D, b_Alog, b_D, ybuf);
  outproj_mfma_kernel<<<dim3(4, 4, 4), 256, 0, stream>>>(ybuf, Wof, Wob, mout);
  ln_kernel<<<dim3(128, 8, 4), 256, 0, stream>>>(mout, cbufb, cbufb + 524288, nullptr, ln_w, ln_b, 1);
  pj_mfma_kernel<<<dim3(4, 4, 2), 256, 0, stream>>>(cbufb, Wpb, proj_b, respre);
  ln_kernel<<<dim3(128, 8, 2), 256, 0, stream>>>(respre, nullptr, nullptr, rmrn, ln_w, ln_b, 0);

  // ---- phase 2: z path ----
  dwz1_kernel<<<2048, 256, 0, stream>>>(x, up_dw_w, z1buf, bn1sum, bn1sq);
  fin_bn_kernel<<<1, 256, 0, stream>>>(bn1sum, bn1sq, up_bn1_g, up_bn1_b, 1.f/131072.f, abn1, dbn1);
  wcvt_kernel<<<256, 256, 0, stream>>>(up_pw_w, Wbbuf, 65536);
  wcvt_kernel<<<256, 256, 0, stream>>>(down_pw_w, Wb2buf, 65536);
  actz1_kernel<<<dim3(256, 4, 8), 256, 0, stream>>>(z1buf, abn1, dbn1, z1tbuf);
  pwz_mfma_kernel<<<dim3(256, 8), 256, 0, stream>>>(z1tbuf, Wbbuf, z2buf);
  chstats_kernel<<<dim3(256, 8), 256, 0, stream>>>(z2buf, bn2sum, bn2sq);
  fin_bn_kernel<<<1, 256, 0, stream>>>(bn2sum, bn2sq, up_bn2_g, up_bn2_b, 1.f/131072.f, abn2, dbn2);

  // ---- phase 3: merge + tail ----
  hsig_kernel<<<dim3(256, 8), 256, 0, stream>>>(z2buf, rmrn, rmrn + 262144, abn2, dbn2, gnsum, gnsq);
  fin_gn_kernel<<<8, 256, 0, stream>>>(gnsum, gnsq, gn_g, gn_b, gnA, gnD);
  trd_kernel<<<dim3(64, 4, 8), 256, 0, stream>>>(z2buf, gnA, gnD, rqtbuf);
  pwdown_mfma_kernel<<<dim3(64, 8), 256, 0, stream>>>(rqtbuf, Wb2buf, dbuf);
  stat5_kernel<<<dim3(256, 8), 256, 0, stream>>>(dbuf, x, stat5);
  coeff_kernel<<<8, 256, 0, stream>>>(stat5, down_bn_g, down_bn_b, gn_g, gn_b, pqr);
  final_kernel<<<dim3(256, 8), 256, 0, stream>>>(x, pqr, (float*)d_out);
}